// Round 5
// baseline (286.844 us; speedup 1.0000x reference)
//
#include <hip/hip_runtime.h>
#include <math.h>

#define NN 100000
#define NE 500000

typedef short bf16x8 __attribute__((ext_vector_type(8)));
typedef float f32x4 __attribute__((ext_vector_type(4)));

// fast tanh-approx gelu (exp2-based): |err| <= ~3e-3 vs exact erf-gelu.
// exp2(2.3022084*q), q = x*(1+0.044715x^2)  ==>  exp2(x*(2.3022084 + 0.10294325x^2))
__device__ __forceinline__ float gelu_f(float x) {
  const float t = x * x;
  const float p = fmaf(t, 0.10294325f, 2.3022084f);
  const float E = __builtin_amdgcn_exp2f(x * p);
  const float r = __builtin_amdgcn_rcpf(E + 1.0f);
  return fmaf(-x, r, x);
}
// HW packed f32->bf16 (RNE), gfx950: v_cvt_pk_bf16_f32
__device__ __forceinline__ unsigned cvtpk(float lo, float hi) {
  unsigned r;
  asm("v_cvt_pk_bf16_f32 %0, %1, %2" : "=v"(r) : "v"(lo), "v"(hi));
  return r;
}
__device__ __forceinline__ short f2bf(float x) {
  return (short)cvtpk(x, x);
}
__device__ __forceinline__ unsigned pack2(float a, float b) {
  return cvtpk(a, b);
}
__device__ __forceinline__ float bf2f(short s) {
  unsigned u = ((unsigned)(unsigned short)s) << 16;
  return __builtin_bit_cast(float, u);
}
__device__ __forceinline__ float bf2f_lo(unsigned w) {
  return __builtin_bit_cast(float, w << 16);
}
__device__ __forceinline__ float bf2f_hi(unsigned w) {
  return __builtin_bit_cast(float, w & 0xFFFF0000u);
}

// ---------------- Kernel 1: per-node h = mlp(u,pn) + u@ipW + ipb -> bf16 ----------------
__global__ __launch_bounds__(256) void node_h_kernel(
    const float* __restrict__ node_u,
    const float* __restrict__ W1, const float* __restrict__ b1,
    const float* __restrict__ W2, const float* __restrict__ b2,
    const float* __restrict__ ipW, const float* __restrict__ ipb,
    unsigned short* __restrict__ h) {
  const int lane = threadIdx.x & 63;
  const int node = blockIdx.x * 4 + (threadIdx.x >> 6);
  if (node >= NN) return;
  const float* u = node_u + (size_t)node * 5;
  const float u0 = u[0], u1 = u[1], u2 = u[2], u3 = u[3], u4 = u[4];
  float a = b1[lane];
  a = fmaf(u0, W1[0 * 64 + lane], a);
  a = fmaf(u1, W1[1 * 64 + lane], a);
  a = fmaf(u2, W1[2 * 64 + lane], a);
  a = fmaf(u3, W1[3 * 64 + lane], a);
  a = fmaf(u4, W1[4 * 64 + lane], a);
  const float g = gelu_f(a);
  float acc = b2[lane] + ipb[lane];
  acc = fmaf(u0, ipW[0 * 64 + lane], acc);
  acc = fmaf(u1, ipW[1 * 64 + lane], acc);
  acc = fmaf(u2, ipW[2 * 64 + lane], acc);
  acc = fmaf(u3, ipW[3 * 64 + lane], acc);
  acc = fmaf(u4, ipW[4 * 64 + lane], acc);
  for (int k = 0; k < 64; ++k) {
    acc = fmaf(__shfl(g, k, 64), W2[k * 64 + lane], acc);
  }
  h[(size_t)node * 64 + lane] = (unsigned short)f2bf(acc);
}

// ---------------- Kernel 0: repack GEMM weights to bf16 fragment order ----------------
// Fragment block = 512 bf16: lane l (0..63) x elem e (0..7); value = W[k][n],
// k = ks*32 + 8*(l>>4) + e, n = nt*16 + (l&15).  (A-side uses the same k map.)
__global__ __launch_bounds__(256) void prep_kernel(
    const float* __restrict__ pm_W1, const float* __restrict__ pm_W2,
    const float* __restrict__ prho_W1, const float* __restrict__ pen_W1,
    const float* __restrict__ pmu_W1, const float* __restrict__ pv_W1,
    const float* __restrict__ prho_b1, const float* __restrict__ pen_b1,
    const float* __restrict__ pmu_b1, const float* __restrict__ pv_b1,
    const float* __restrict__ pe_W2,
    const float* __restrict__ prho_W2, const float* __restrict__ pen_W2,
    const float* __restrict__ pmu_W2, const float* __restrict__ pv_W2,
    const float* __restrict__ prho_b2, const float* __restrict__ pen_b2,
    const float* __restrict__ pmu_b2, const float* __restrict__ pv_b2,
    short* __restrict__ W1P, short* __restrict__ W2P, short* __restrict__ WHP,
    float* __restrict__ HB, short* __restrict__ WEP, short* __restrict__ WOP,
    float* __restrict__ HB2) {
  int t = blockIdx.x * 256 + threadIdx.x;
  if (t < 40960) {  // pm_W1: 292(->320)x128, [nt=8][ks=10][512]
    const int nt = t / 5120, rem = t % 5120;
    const int ks = rem / 512, li = rem % 512;
    const int l = li >> 3, e = li & 7;
    const int k = ks * 32 + ((l >> 4) << 3) + e;
    const int n = nt * 16 + (l & 15);
    W1P[t] = (k < 292) ? f2bf(pm_W1[k * 128 + n]) : (short)0;
    return;
  }
  t -= 40960;
  if (t < 8192) {  // pm_W2: 128x64, [nt=4][ks=4][512]
    const int nt = t / 2048, rem = t % 2048;
    const int ks = rem / 512, li = rem % 512;
    const int l = li >> 3, e = li & 7;
    const int k = ks * 32 + ((l >> 4) << 3) + e;
    const int n = nt * 16 + (l & 15);
    W2P[t] = f2bf(pm_W2[k * 64 + n]);
    return;
  }
  t -= 8192;
  if (t < 14336) {  // heads W1 concat: 64x224, [nt=14][ks=2][512]
    const int nt = t / 1024, rem = t % 1024;
    const int ks = rem / 512, li = rem % 512;
    const int l = li >> 3, e = li & 7;
    const int k = ks * 32 + ((l >> 4) << 3) + e;
    const int col = nt * 16 + (l & 15);
    float v;
    if (col < 64) v = prho_W1[k * 64 + col];
    else if (col < 128) v = pen_W1[k * 64 + (col - 64)];
    else if (col < 192) v = pmu_W1[k * 64 + (col - 128)];
    else v = pv_W1[k * 32 + (col - 192)];
    WHP[t] = f2bf(v);
    return;
  }
  t -= 14336;
  if (t < 224) {  // head hidden biases concat (f32)
    HB[t] = (t < 64) ? prho_b1[t]
          : (t < 128) ? pen_b1[t - 64]
          : (t < 192) ? pmu_b1[t - 128]
          : pv_b1[t - 192];
    return;
  }
  t -= 224;
  if (t < 1024) {  // pe_W2: 32x32, [nt=2][512]
    const int nt = t / 512, li = t % 512;
    const int l = li >> 3, e = li & 7;
    const int k = ((l >> 4) << 3) + e;
    const int n = nt * 16 + (l & 15);
    WEP[t] = f2bf(pe_W2[k * 32 + n]);
    return;
  }
  t -= 1024;
  if (t < 3584) {  // stacked head W2: 224x16, [ks=7][512]
    const int ks = t / 512, li = t % 512;
    const int l = li >> 3, e = li & 7;
    const int k = ks * 32 + ((l >> 4) << 3) + e;
    const int j = l & 15;
    float v = 0.0f;
    if (j == 0 && k < 64) v = prho_W2[k];
    else if (j == 1 && k >= 64 && k < 128) v = pen_W2[k - 64];
    else if (j == 2 && k >= 128 && k < 192) v = pmu_W2[(k - 128) * 2 + 0];
    else if (j == 3 && k >= 128 && k < 192) v = pmu_W2[(k - 128) * 2 + 1];
    else if (j == 4 && k >= 192 && k < 224) v = pv_W2[k - 192];
    WOP[t] = f2bf(v);
    return;
  }
  t -= 3584;
  if (t < 16) {  // head output biases
    HB2[t] = (t == 0) ? prho_b2[0]
           : (t == 1) ? pen_b2[0]
           : (t == 2) ? pmu_b2[0]
           : (t == 3) ? pmu_b2[1]
           : (t == 4) ? pv_b2[0] : 0.0f;
  }
}

// ---------------- Kernel 2: per-edge fused MFMA pipeline, 32 edges / block ----------------
struct EdgeArgs {
  const float *node_u, *edge_attr, *mean_mom, *std_mom, *edge_mem;
  const int* eidx;
  const float *pe_W1, *pe_b1, *pe_b2;
  const float *pm_b1, *pm_b2;
  const float *ln_g, *ln_b;
  const unsigned short* h;   // bf16
  const short *W1P, *W2P, *WHP, *WEP, *WOP;
  const float *HB, *HB2;
  float* out;
};

#define SMS 328   // msg bf16 row stride (656 B)
#define H1S 136   // h1 bf16 row stride (272 B)
#define MSR 72    // m bf16 row stride (144 B)
#define ZST 240   // z bf16 row stride (480 B, 16B-aligned)
#define EPS 40    // eps-hidden bf16 row stride (80 B)

// LDS map (32000 B -> 5 blocks/CU):
//  [0, 20992): msg bf16 [32][328]              (S0*..E2)
//      overlay: aMq bf16 [32][72] @ +8704      (E3 -> LNsums)
//      overlay: aZ  bf16 [32][240] @ +0        (E4 -> E5), ends 15360
//  [15360, 19968): aMp/aM bf16 [32][72]        (E3 -> E4; in-place LN)
//  [20992, 29696): h1 bf16 [32][136]           (E2 -> E3); early: epsB bf16 [32][40]
//  [29696, 30720): sSc  f32 [32][8]
//  [30720, 31744): sSc2 f32 [32][8]
//  [31744, 32000): sIdx int[64] (early) / sSums f32[64] (LN)
#define OFF_A   0
#define OFF_MQ  8704
#define OFF_AM  15360
#define OFF_H1  20992
#define OFF_SC  29696
#define OFF_SC2 30720
#define OFF_IDX 31744
#define SMEM_BYTES 32000

#define MFMA16(a, b, c) __builtin_amdgcn_mfma_f32_16x16x32_bf16((a), (b), (c), 0, 0, 0)

__global__ __launch_bounds__(256, 5) void edge_kernel(EdgeArgs A) {
  __shared__ __align__(16) char smem[SMEM_BYTES];
  short* aA = (short*)(smem + OFF_A);
  short* aMq = (short*)(smem + OFF_MQ);
  short* aM = (short*)(smem + OFF_AM);
  short* aZ = (short*)(smem + OFF_A);
  short* aH1 = (short*)(smem + OFF_H1);
  short* epsB = (short*)(smem + OFF_H1);
  float* sSc = (float*)(smem + OFF_SC);
  float* sSc2 = (float*)(smem + OFF_SC2);
  int* sIdx = (int*)(smem + OFF_IDX);
  float* sSums = (float*)(smem + OFF_IDX);

  const int tid = threadIdx.x;
  const int e0 = blockIdx.x * 32;
  const int lane = tid & 63;
  const int wv = tid >> 6;
  const int l15 = lane & 15, g = lane >> 4;
  const int mt = wv & 1, nh = wv >> 1;

  // ---- S0a: per-edge scalars (vel_proj, n, t, du, indices) + zero K-pad
  if (tid < 32) {
    const int e = e0 + tid;
    const int s = A.eidx[e];
    const int d = A.eidx[NE + e];
    sIdx[tid] = s;
    sIdx[32 + tid] = d;
    const float dx = A.edge_attr[e * 3 + 0];
    const float dy = A.edge_attr[e * 3 + 1];
    const float r = A.edge_attr[e * 3 + 2];
    const float inv = 1.0f / (r + 1e-12f);
    const float n0 = dx * inv, n1 = dy * inv;  // t = (-n1, n0)
    const float* us = A.node_u + (size_t)s * 5;
    const float* ud = A.node_u + (size_t)d * 5;
    const float sm0 = A.std_mom[0], sm1 = A.std_mom[1];
    const float mm0 = A.mean_mom[0], mm1 = A.mean_mom[1];
    const float rs0 = fmaf(us[3], sm0, mm0), rs1 = fmaf(us[4], sm1, mm1);
    const float rd0 = fmaf(ud[3], sm0, mm0), rd1 = fmaf(ud[4], sm1, mm1);
    const float isc = 1.0f / (sqrtf(sm0 * sm0 + sm1 * sm1) + 1e-8f);
    unsigned* vp = (unsigned*)(aA + tid * SMS + 288);
    vp[0] = pack2((rs0 * n0 + rs1 * n1) * isc, (-rs0 * n1 + rs1 * n0) * isc);
    vp[1] = pack2((rd0 * n0 + rd1 * n1) * isc, (-rd0 * n1 + rd1 * n0) * isc);
    unsigned* zp = (unsigned*)(aA + tid * SMS + 292);
#pragma unroll
    for (int z = 0; z < 14; ++z) zp[z] = 0u;  // zero K-pad cols 292..319
    float* st = &sSc[tid * 8];
    st[0] = n0; st[1] = n1; st[2] = r;
    st[3] = ud[0] - us[0];
    st[4] = ud[1] - us[1];
    st[5] = ud[3] - us[3];
    st[6] = ud[4] - us[4];
  }
  __syncthreads();

  // ---- S0b: eps hidden (1 -> 32, gelu) -> epsB bf16 [32][40]
  {
    const int i = tid & 31, eg = tid >> 5;
    const float w1 = A.pe_W1[i], b1 = A.pe_b1[i];
#pragma unroll
    for (int p = 0; p < 4; ++p) {
      const int el = eg * 4 + p;
      epsB[el * EPS + i] = f2bf(gelu_f(fmaf(sSc[el * 8 + 2], w1, b1)));
    }
  }
  __syncthreads();

  // ---- S0c: eps out via MFMA (M=32,K=32,N=32) -> msg cols [256..288)
  {
    const bf16x8 a = *(const bf16x8*)((const char*)epsB + (mt * 16 + l15) * (EPS * 2) + g * 16);
    const bf16x8 b = *(const bf16x8*)(A.WEP + nh * 512 + lane * 8);
    f32x4 acc = {0.f, 0.f, 0.f, 0.f};
    acc = MFMA16(a, b, acc);
    const int col = 256 + nh * 16 + l15;
    const float bb = A.pe_b2[nh * 16 + l15];
#pragma unroll
    for (int rg = 0; rg < 4; ++rg)
      aA[(mt * 16 + g * 4 + rg) * SMS + col] = f2bf(acc[rg] + bb);
  }
  // ---- S0d: h gathers (bf16) -> msg cols [0..256)
  {
    const int c = tid & 31, eg = tid >> 5;
#pragma unroll
    for (int p = 0; p < 4; ++p) {
      const int el = eg * 4 + p;
      const unsigned us_raw = ((const unsigned*)(A.h + (size_t)sIdx[el] * 64))[c];
      const unsigned ud_raw = ((const unsigned*)(A.h + (size_t)sIdx[32 + el] * 64))[c];
      unsigned* rp = (unsigned*)((char*)aA + el * (SMS * 2));
      rp[c] = us_raw;
      rp[32 + c] = ud_raw;
      const float s0 = bf2f_lo(us_raw), s1 = bf2f_hi(us_raw);
      const float d0 = bf2f_lo(ud_raw), d1 = bf2f_hi(ud_raw);
      rp[64 + c] = pack2(s0 + d0, s1 + d1);
      const float q0 = s0 - d0, q1 = s1 - d1;
      rp[96 + c] = pack2(q0 * q0, q1 * q1);
    }
  }
  __syncthreads();

  // ---- E2: layer1 MFMA (K=320 incl pad, N=128)
  {
    const char* arow = (const char*)aA + (mt * 16 + l15) * (SMS * 2) + g * 16;
    const short* BW = A.W1P + nh * 4 * 10 * 512 + lane * 8;
    f32x4 ac0 = {0.f, 0.f, 0.f, 0.f}, ac1 = ac0, ac2 = ac0, ac3 = ac0;
    for (int ks = 0; ks < 10; ++ks) {
      const bf16x8 a = *(const bf16x8*)(arow + ks * 64);
      const bf16x8 b0 = *(const bf16x8*)(BW + (0 * 10 + ks) * 512);
      const bf16x8 b1 = *(const bf16x8*)(BW + (1 * 10 + ks) * 512);
      const bf16x8 b2 = *(const bf16x8*)(BW + (2 * 10 + ks) * 512);
      const bf16x8 b3 = *(const bf16x8*)(BW + (3 * 10 + ks) * 512);
      ac0 = MFMA16(a, b0, ac0);
      ac1 = MFMA16(a, b1, ac1);
      ac2 = MFMA16(a, b2, ac2);
      ac3 = MFMA16(a, b3, ac3);
    }
    const int rb = mt * 16 + g * 4;
#define EPI1(j, accv) { \
    const int col = (nh * 4 + (j)) * 16 + l15; \
    const float bb = A.pm_b1[col]; \
    _Pragma("unroll") \
    for (int rg = 0; rg < 4; ++rg) \
      aH1[(rb + rg) * H1S + col] = f2bf(gelu_f(accv[rg] + bb)); \
  }
    EPI1(0, ac0) EPI1(1, ac1) EPI1(2, ac2) EPI1(3, ac3)
#undef EPI1
  }
  __syncthreads();

  // ---- E3: layer2 MFMA (K=128, N=64) + bias + edge_memory -> aM (x) + aMq (x^2) bf16
  {
    const char* arow = (const char*)aH1 + (mt * 16 + l15) * (H1S * 2) + g * 16;
    const short* BW = A.W2P + nh * 2 * 4 * 512 + lane * 8;
    f32x4 ac0 = {0.f, 0.f, 0.f, 0.f}, ac1 = ac0;
    for (int ks = 0; ks < 4; ++ks) {
      const bf16x8 a = *(const bf16x8*)(arow + ks * 64);
      const bf16x8 b0 = *(const bf16x8*)(BW + (0 * 4 + ks) * 512);
      const bf16x8 b1 = *(const bf16x8*)(BW + (1 * 4 + ks) * 512);
      ac0 = MFMA16(a, b0, ac0);
      ac1 = MFMA16(a, b1, ac1);
    }
    const int rb = mt * 16 + g * 4;
#define EPI2(j, accv) { \
    const int col = (nh * 2 + (j)) * 16 + l15; \
    const float bb = A.pm_b2[col]; \
    _Pragma("unroll") \
    for (int rg = 0; rg < 4; ++rg) { \
      const int row = rb + rg; \
      const float x = accv[rg] + bb + A.edge_mem[(size_t)(e0 + row) * 64 + col]; \
      const unsigned pk = pack2(x, x * x); \
      aM[row * MSR + col] = (short)pk; \
      aMq[row * MSR + col] = (short)(pk >> 16); \
    } \
  }
    EPI2(0, ac0) EPI2(1, ac1)
#undef EPI2
  }
  __syncthreads();

  // ---- LN sums via MFMA: wave (mt, q): C = A . ones, rows mt*16.., A = x or x^2
  {
    const int q = wv >> 1;
    const short* src = q ? aMq : aM;
    const short ONE = (short)0x3F80;
    const bf16x8 bones = {ONE, ONE, ONE, ONE, ONE, ONE, ONE, ONE};
    f32x4 acc = {0.f, 0.f, 0.f, 0.f};
#pragma unroll
    for (int ks = 0; ks < 2; ++ks) {
      const bf16x8 a = *(const bf16x8*)((const char*)src + (mt * 16 + l15) * (MSR * 2) + ks * 64 + g * 16);
      acc = MFMA16(a, bones, acc);
    }
    if (l15 == 0) {
#pragma unroll
      for (int rg = 0; rg < 4; ++rg)
        sSums[q * 32 + mt * 16 + g * 4 + rg] = acc[rg];
    }
  }
  __syncthreads();

  // ---- LN normalize (elementwise, in-place on aM) + m f32 output
  {
    const float lg = A.ln_g[lane], lb = A.ln_b[lane];
    float* out_m = A.out + (size_t)10 * NE;
#pragma unroll
    for (int p = 0; p < 8; ++p) {
      const int r = p * 4 + wv;
      const float x = bf2f(aM[r * MSR + lane]);
      const float mean = sSums[r] * (1.0f / 64.0f);
      const float var = fmaxf(sSums[32 + r] * (1.0f / 64.0f) - mean * mean, 0.0f);
      const float rstd = rsqrtf(var + 1e-5f);
      const float y = fmaf((x - mean) * rstd, lg, lb);
      aM[r * MSR + lane] = f2bf(y);
      out_m[(size_t)(e0 + r) * 64 + lane] = y;
    }
  }
  __syncthreads();

  // ---- E4: head hidden MFMA (K=64, N=224), gelu -> z bf16 (stride 240, overlay aA)
  {
    const char* arow = (const char*)aM + (mt * 16 + l15) * (MSR * 2) + g * 16;
    const bf16x8 a0 = *(const bf16x8*)(arow);
    const bf16x8 a1 = *(const bf16x8*)(arow + 64);
    const short* BW = A.WHP + nh * 7 * 2 * 512 + lane * 8;
    const int rb = mt * 16 + g * 4;
#define HEADJ(j) { \
    f32x4 acc = {0.f, 0.f, 0.f, 0.f}; \
    acc = MFMA16(a0, *(const bf16x8*)(BW + ((j) * 2 + 0) * 512), acc); \
    acc = MFMA16(a1, *(const bf16x8*)(BW + ((j) * 2 + 1) * 512), acc); \
    const int col = (nh * 7 + (j)) * 16 + l15; \
    const float bb = A.HB[col]; \
    _Pragma("unroll") \
    for (int rg = 0; rg < 4; ++rg) \
      aZ[(rb + rg) * ZST + col] = f2bf(gelu_f(acc[rg] + bb)); \
  }
    HEADJ(0) HEADJ(1) HEADJ(2) HEADJ(3) HEADJ(4) HEADJ(5) HEADJ(6)
#undef HEADJ
  }
  __syncthreads();

  // ---- E5: head outputs via MFMA (M=32, K=224, N=16; cols 0..4 valid)
  if (wv < 2) {
    f32x4 acc = {0.f, 0.f, 0.f, 0.f};
    for (int ks = 0; ks < 7; ++ks) {
      const bf16x8 a = *(const bf16x8*)((const char*)aZ + (wv * 16 + l15) * (ZST * 2) + ks * 64 + g * 16);
      const bf16x8 b = *(const bf16x8*)(A.WOP + ks * 512 + lane * 8);
      acc = MFMA16(a, b, acc);
    }
    if (l15 < 5) {
      const float bb = A.HB2[l15];
#pragma unroll
      for (int rg = 0; rg < 4; ++rg)
        sSc2[(wv * 16 + g * 4 + rg) * 8 + l15] = acc[rg] + bb;
    }
  }
  __syncthreads();

  // ---- E5b: flux epilogue
  if (tid < 32) {
    const int e = tid;
    const float* st = &sSc[e * 8];
    const float n0 = st[0], n1 = st[1], r = st[2];
    const float du0 = st[3], du1 = st[4], du3 = st[5], du4 = st[6];
    const float arho = sSc2[e * 8 + 0], aen = sSc2[e * 8 + 1];
    const float amu0 = sSc2[e * 8 + 2], amu1 = sSc2[e * 8 + 3];
    const float av = sSc2[e * 8 + 4];
    const float alpha = __builtin_amdgcn_rcpf(1.0f + __builtin_amdgcn_exp2f(-1.4426950408f * av));
    const size_t ge = (size_t)(e0 + e);
    float* out = A.out;
    const float c0 = arho - alpha * du0;
    out[ge * 2 + 0] = c0 * n0;
    out[ge * 2 + 1] = c0 * n1;
    const float c1 = aen - alpha * du1;
    out[(size_t)2 * NE + ge * 2 + 0] = c1 * n0;
    out[(size_t)2 * NE + ge * 2 + 1] = c1 * n1;
    out[(size_t)4 * NE + ge * 2 + 0] = amu0 * n0 - amu1 * n1 - alpha * du3;
    out[(size_t)4 * NE + ge * 2 + 1] = amu0 * n1 + amu1 * n0 - alpha * du4;
    out[(size_t)6 * NE + ge * 2 + 0] = n0;
    out[(size_t)6 * NE + ge * 2 + 1] = n1;
    out[(size_t)8 * NE + ge] = r;
    out[(size_t)9 * NE + ge] = alpha;
  }
}

extern "C" void kernel_launch(void* const* d_in, const int* in_sizes, int n_in,
                              void* d_out, int out_size, void* d_ws, size_t ws_size,
                              hipStream_t stream) {
  const float* node_u = (const float*)d_in[0];
  const float* pn_W1 = (const float*)d_in[6];
  const float* pn_b1 = (const float*)d_in[7];
  const float* pn_W2 = (const float*)d_in[8];
  const float* pn_b2 = (const float*)d_in[9];
  const float* ip_W = (const float*)d_in[10];
  const float* ip_b = (const float*)d_in[11];

  char* ws = (char*)d_ws;
  unsigned short* h = (unsigned short*)ws;        // 12,800,000 B
  short* W1P = (short*)(ws + 12800000);           // 81,920 B
  short* W2P = (short*)(ws + 12881920);           // 16,384 B
  short* WHP = (short*)(ws + 12898304);           // 28,672 B
  float* HB  = (float*)(ws + 12926976);           // 896 B
  short* WEP = (short*)(ws + 12927872);           // 2,048 B
  short* WOP = (short*)(ws + 12929920);           // 7,168 B
  float* HB2 = (float*)(ws + 12937088);           // 64 B

  EdgeArgs A;
  A.node_u = node_u;
  A.edge_attr = (const float*)d_in[1];
  A.mean_mom = (const float*)d_in[2];
  A.std_mom = (const float*)d_in[3];
  A.edge_mem = (const float*)d_in[4];
  A.eidx = (const int*)d_in[5];
  A.pe_W1 = (const float*)d_in[12];
  A.pe_b1 = (const float*)d_in[13];
  A.pe_b2 = (const float*)d_in[15];
  A.pm_b1 = (const float*)d_in[17];
  A.pm_b2 = (const float*)d_in[19];
  A.ln_g = (const float*)d_in[36];
  A.ln_b = (const float*)d_in[37];
  A.h = h;
  A.W1P = W1P;
  A.W2P = W2P;
  A.WHP = WHP;
  A.WEP = WEP;
  A.WOP = WOP;
  A.HB = HB;
  A.HB2 = HB2;
  A.out = (float*)d_out;

  prep_kernel<<<267, 256, 0, stream>>>(
      (const float*)d_in[16], (const float*)d_in[18],
      (const float*)d_in[20], (const float*)d_in[24],
      (const float*)d_in[28], (const float*)d_in[32],
      (const float*)d_in[21], (const float*)d_in[25],
      (const float*)d_in[29], (const float*)d_in[33],
      (const float*)d_in[14],
      (const float*)d_in[22], (const float*)d_in[26],
      (const float*)d_in[30], (const float*)d_in[34],
      (const float*)d_in[23], (const float*)d_in[27],
      (const float*)d_in[31], (const float*)d_in[35],
      W1P, W2P, WHP, HB, WEP, WOP, HB2);
  node_h_kernel<<<NN / 4, 256, 0, stream>>>(node_u, pn_W1, pn_b1, pn_W2, pn_b2,
                                            ip_W, ip_b, h);
  edge_kernel<<<NE / 32, 256, 0, stream>>>(A);
}

// Round 6
// 264.491 us; speedup vs baseline: 1.0845x; 1.0845x over previous
//
#include <hip/hip_runtime.h>
#include <math.h>

#define NN 100000
#define NE 500000

typedef short bf16x8 __attribute__((ext_vector_type(8)));
typedef float f32x4 __attribute__((ext_vector_type(4)));
typedef float f32x16 __attribute__((ext_vector_type(16)));

// fast tanh-approx gelu (exp2-based): |err| <= ~3e-3 vs exact erf-gelu.
__device__ __forceinline__ float gelu_f(float x) {
  const float t = x * x;
  const float p = fmaf(t, 0.10294325f, 2.3022084f);
  const float E = __builtin_amdgcn_exp2f(x * p);
  const float r = __builtin_amdgcn_rcpf(E + 1.0f);
  return fmaf(-x, r, x);
}
// HW packed f32->bf16 (RNE), gfx950: v_cvt_pk_bf16_f32
__device__ __forceinline__ unsigned cvtpk(float lo, float hi) {
  unsigned r;
  asm("v_cvt_pk_bf16_f32 %0, %1, %2" : "=v"(r) : "v"(lo), "v"(hi));
  return r;
}
__device__ __forceinline__ short f2bf(float x) {
  return (short)cvtpk(x, x);
}
__device__ __forceinline__ unsigned pack2(float a, float b) {
  return cvtpk(a, b);
}
__device__ __forceinline__ float bf2f(short s) {
  unsigned u = ((unsigned)(unsigned short)s) << 16;
  return __builtin_bit_cast(float, u);
}
__device__ __forceinline__ float bf2f_lo(unsigned w) {
  return __builtin_bit_cast(float, w << 16);
}
__device__ __forceinline__ float bf2f_hi(unsigned w) {
  return __builtin_bit_cast(float, w & 0xFFFF0000u);
}

// ---------------- Kernel 1: per-node h = mlp(u,pn) + u@ipW + ipb -> bf16 ----------------
__global__ __launch_bounds__(256) void node_h_kernel(
    const float* __restrict__ node_u,
    const float* __restrict__ W1, const float* __restrict__ b1,
    const float* __restrict__ W2, const float* __restrict__ b2,
    const float* __restrict__ ipW, const float* __restrict__ ipb,
    unsigned short* __restrict__ h) {
  const int lane = threadIdx.x & 63;
  const int node = blockIdx.x * 4 + (threadIdx.x >> 6);
  if (node >= NN) return;
  const float* u = node_u + (size_t)node * 5;
  const float u0 = u[0], u1 = u[1], u2 = u[2], u3 = u[3], u4 = u[4];
  float a = b1[lane];
  a = fmaf(u0, W1[0 * 64 + lane], a);
  a = fmaf(u1, W1[1 * 64 + lane], a);
  a = fmaf(u2, W1[2 * 64 + lane], a);
  a = fmaf(u3, W1[3 * 64 + lane], a);
  a = fmaf(u4, W1[4 * 64 + lane], a);
  const float g = gelu_f(a);
  float a0 = b2[lane] + ipb[lane];
  a0 = fmaf(u0, ipW[0 * 64 + lane], a0);
  a0 = fmaf(u1, ipW[1 * 64 + lane], a0);
  a0 = fmaf(u2, ipW[2 * 64 + lane], a0);
  a0 = fmaf(u3, ipW[3 * 64 + lane], a0);
  a0 = fmaf(u4, ipW[4 * 64 + lane], a0);
  float a1 = 0.f, a2 = 0.f, a3 = 0.f;
  for (int k = 0; k < 64; k += 4) {  // 4 independent chains for ILP
    a0 = fmaf(__shfl(g, k + 0, 64), W2[(k + 0) * 64 + lane], a0);
    a1 = fmaf(__shfl(g, k + 1, 64), W2[(k + 1) * 64 + lane], a1);
    a2 = fmaf(__shfl(g, k + 2, 64), W2[(k + 2) * 64 + lane], a2);
    a3 = fmaf(__shfl(g, k + 3, 64), W2[(k + 3) * 64 + lane], a3);
  }
  h[(size_t)node * 64 + lane] = (unsigned short)f2bf((a0 + a1) + (a2 + a3));
}

// ---------------- Kernel 0: repack GEMM weights to bf16 fragment order ----------------
// 16x16 frag block = 512 bf16: lane l x elem e; k = ks*32 + 8*(l>>4) + e, n = nt*16 + (l&15).
// 32x32 frag block = 512 bf16: lane l x elem e; k = ks*16 + 8*(l>>5) + e, n = nt*32 + (l&31).
__global__ __launch_bounds__(256) void prep_kernel(
    const float* __restrict__ pm_W1, const float* __restrict__ pm_W2,
    const float* __restrict__ prho_W1, const float* __restrict__ pen_W1,
    const float* __restrict__ pmu_W1, const float* __restrict__ pv_W1,
    const float* __restrict__ prho_b1, const float* __restrict__ pen_b1,
    const float* __restrict__ pmu_b1, const float* __restrict__ pv_b1,
    const float* __restrict__ pe_W2,
    const float* __restrict__ prho_W2, const float* __restrict__ pen_W2,
    const float* __restrict__ pmu_W2, const float* __restrict__ pv_W2,
    const float* __restrict__ prho_b2, const float* __restrict__ pen_b2,
    const float* __restrict__ pmu_b2, const float* __restrict__ pv_b2,
    short* __restrict__ W1P, short* __restrict__ W2P, short* __restrict__ WHP,
    float* __restrict__ HB, short* __restrict__ WEP, short* __restrict__ WOP,
    float* __restrict__ HB2) {
  int t = blockIdx.x * 256 + threadIdx.x;
  if (t < 40960) {  // pm_W1 32x32-frag: 292(->320)x128, [nt=4][ks=20][512]
    const int nt = t / 10240, rem = t % 10240;
    const int ks = rem / 512, li = rem % 512;
    const int l = li >> 3, e = li & 7;
    const int k = ks * 16 + ((l >> 5) << 3) + e;
    const int n = nt * 32 + (l & 31);
    W1P[t] = (k < 292) ? f2bf(pm_W1[k * 128 + n]) : (short)0;
    return;
  }
  t -= 40960;
  if (t < 8192) {  // pm_W2 16x16-frag: 128x64, [nt=4][ks=4][512]
    const int nt = t / 2048, rem = t % 2048;
    const int ks = rem / 512, li = rem % 512;
    const int l = li >> 3, e = li & 7;
    const int k = ks * 32 + ((l >> 4) << 3) + e;
    const int n = nt * 16 + (l & 15);
    W2P[t] = f2bf(pm_W2[k * 64 + n]);
    return;
  }
  t -= 8192;
  if (t < 14336) {  // heads W1 concat 32x32-frag: 64x224, [nt=7][ks=4][512]
    const int nt = t / 2048, rem = t % 2048;
    const int ks = rem / 512, li = rem % 512;
    const int l = li >> 3, e = li & 7;
    const int k = ks * 16 + ((l >> 5) << 3) + e;   // 0..63
    const int col = nt * 32 + (l & 31);            // 0..223
    float v;
    if (col < 64) v = prho_W1[k * 64 + col];
    else if (col < 128) v = pen_W1[k * 64 + (col - 64)];
    else if (col < 192) v = pmu_W1[k * 64 + (col - 128)];
    else v = pv_W1[k * 32 + (col - 192)];
    WHP[t] = f2bf(v);
    return;
  }
  t -= 14336;
  if (t < 224) {  // head hidden biases concat (f32)
    HB[t] = (t < 64) ? prho_b1[t]
          : (t < 128) ? pen_b1[t - 64]
          : (t < 192) ? pmu_b1[t - 128]
          : pv_b1[t - 192];
    return;
  }
  t -= 224;
  if (t < 1024) {  // pe_W2 16x16-frag: 32x32, [nt=2][512]
    const int nt = t / 512, li = t % 512;
    const int l = li >> 3, e = li & 7;
    const int k = ((l >> 4) << 3) + e;
    const int n = nt * 16 + (l & 15);
    WEP[t] = f2bf(pe_W2[k * 32 + n]);
    return;
  }
  t -= 1024;
  if (t < 3584) {  // stacked head W2 16x16-frag: 224x16, [ks=7][512]
    const int ks = t / 512, li = t % 512;
    const int l = li >> 3, e = li & 7;
    const int k = ks * 32 + ((l >> 4) << 3) + e;
    const int j = l & 15;
    float v = 0.0f;
    if (j == 0 && k < 64) v = prho_W2[k];
    else if (j == 1 && k >= 64 && k < 128) v = pen_W2[k - 64];
    else if (j == 2 && k >= 128 && k < 192) v = pmu_W2[(k - 128) * 2 + 0];
    else if (j == 3 && k >= 128 && k < 192) v = pmu_W2[(k - 128) * 2 + 1];
    else if (j == 4 && k >= 192 && k < 224) v = pv_W2[k - 192];
    WOP[t] = f2bf(v);
    return;
  }
  t -= 3584;
  if (t < 16) {  // head output biases
    HB2[t] = (t == 0) ? prho_b2[0]
           : (t == 1) ? pen_b2[0]
           : (t == 2) ? pmu_b2[0]
           : (t == 3) ? pmu_b2[1]
           : (t == 4) ? pv_b2[0] : 0.0f;
  }
}

// ---------------- Kernel 2: per-edge fused MFMA pipeline, 32 edges / block ----------------
struct EdgeArgs {
  const float *node_u, *edge_attr, *mean_mom, *std_mom, *edge_mem;
  const int* eidx;
  const float *pe_W1, *pe_b1, *pe_b2;
  const float *pm_b1, *pm_b2;
  const float *ln_g, *ln_b;
  const unsigned short* h;   // bf16
  const short *W1P, *W2P, *WHP, *WEP, *WOP;
  const float *HB, *HB2;
  float* out;
};

#define SMS 328   // msg bf16 row stride (656 B)
#define H1S 136   // h1 bf16 row stride (272 B)
#define MSR 72    // m bf16 row stride (144 B)
#define ZST 240   // z bf16 row stride (480 B, 16B-aligned)
#define EPS 40    // eps-hidden bf16 row stride (80 B)

#define OFF_A   0
#define OFF_MQ  8704
#define OFF_AM  15360
#define OFF_H1  20992
#define OFF_SC  29696
#define OFF_SC2 30720
#define OFF_IDX 31744
#define SMEM_BYTES 32000

#define MFMA16(a, b, c) __builtin_amdgcn_mfma_f32_16x16x32_bf16((a), (b), (c), 0, 0, 0)
#define MFMA32(a, b, c) __builtin_amdgcn_mfma_f32_32x32x16_bf16((a), (b), (c), 0, 0, 0)

__global__ __launch_bounds__(256, 5) void edge_kernel(EdgeArgs A) {
  __shared__ __align__(16) char smem[SMEM_BYTES];
  short* aA = (short*)(smem + OFF_A);
  short* aMq = (short*)(smem + OFF_MQ);
  short* aM = (short*)(smem + OFF_AM);
  short* aZ = (short*)(smem + OFF_A);
  short* aH1 = (short*)(smem + OFF_H1);
  short* epsB = (short*)(smem + OFF_H1);
  float* sSc = (float*)(smem + OFF_SC);
  float* sSc2 = (float*)(smem + OFF_SC2);
  int* sIdx = (int*)(smem + OFF_IDX);
  float* sSums = (float*)(smem + OFF_IDX);

  const int tid = threadIdx.x;
  const int e0 = blockIdx.x * 32;
  const int lane = tid & 63;
  const int wv = tid >> 6;
  const int l15 = lane & 15, g = lane >> 4;
  const int l31 = lane & 31, hi = lane >> 5;
  const int mt = wv & 1, nh = wv >> 1;

  // ---- S0a (tid<32) || S0b (all threads): independent work, one barrier
  if (tid < 32) {
    const int e = e0 + tid;
    const int s = A.eidx[e];
    const int d = A.eidx[NE + e];
    sIdx[tid] = s;
    sIdx[32 + tid] = d;
    const float dx = A.edge_attr[e * 3 + 0];
    const float dy = A.edge_attr[e * 3 + 1];
    const float r = A.edge_attr[e * 3 + 2];
    const float inv = 1.0f / (r + 1e-12f);
    const float n0 = dx * inv, n1 = dy * inv;  // t = (-n1, n0)
    const float* us = A.node_u + (size_t)s * 5;
    const float* ud = A.node_u + (size_t)d * 5;
    const float sm0 = A.std_mom[0], sm1 = A.std_mom[1];
    const float mm0 = A.mean_mom[0], mm1 = A.mean_mom[1];
    const float rs0 = fmaf(us[3], sm0, mm0), rs1 = fmaf(us[4], sm1, mm1);
    const float rd0 = fmaf(ud[3], sm0, mm0), rd1 = fmaf(ud[4], sm1, mm1);
    const float isc = 1.0f / (sqrtf(sm0 * sm0 + sm1 * sm1) + 1e-8f);
    unsigned* vp = (unsigned*)(aA + tid * SMS + 288);
    vp[0] = pack2((rs0 * n0 + rs1 * n1) * isc, (-rs0 * n1 + rs1 * n0) * isc);
    vp[1] = pack2((rd0 * n0 + rd1 * n1) * isc, (-rd0 * n1 + rd1 * n0) * isc);
    unsigned* zp = (unsigned*)(aA + tid * SMS + 292);
#pragma unroll
    for (int z = 0; z < 14; ++z) zp[z] = 0u;  // zero K-pad cols 292..319
    float* st = &sSc[tid * 8];
    st[0] = n0; st[1] = n1; st[2] = r;
    st[3] = ud[0] - us[0];
    st[4] = ud[1] - us[1];
    st[5] = ud[3] - us[3];
    st[6] = ud[4] - us[4];
  }
  {  // S0b: eps hidden (1 -> 32, gelu) -> epsB bf16 [32][40]; reads r directly
    const int i = tid & 31, eg = tid >> 5;
    const float w1 = A.pe_W1[i], b1 = A.pe_b1[i];
#pragma unroll
    for (int p = 0; p < 4; ++p) {
      const int el = eg * 4 + p;
      const float rv = A.edge_attr[(e0 + el) * 3 + 2];
      epsB[el * EPS + i] = f2bf(gelu_f(fmaf(rv, w1, b1)));
    }
  }
  __syncthreads();

  // ---- S0c: eps out via MFMA (M=32,K=32,N=32) -> msg cols [256..288)
  {
    const bf16x8 a = *(const bf16x8*)((const char*)epsB + (mt * 16 + l15) * (EPS * 2) + g * 16);
    const bf16x8 b = *(const bf16x8*)(A.WEP + nh * 512 + lane * 8);
    f32x4 acc = {0.f, 0.f, 0.f, 0.f};
    acc = MFMA16(a, b, acc);
    const int col = 256 + nh * 16 + l15;
    const float bb = A.pe_b2[nh * 16 + l15];
#pragma unroll
    for (int rg = 0; rg < 4; ++rg)
      aA[(mt * 16 + g * 4 + rg) * SMS + col] = f2bf(acc[rg] + bb);
  }
  // ---- S0d: h gathers (bf16) -> msg cols [0..256)
  {
    const int c = tid & 31, eg = tid >> 5;
#pragma unroll
    for (int p = 0; p < 4; ++p) {
      const int el = eg * 4 + p;
      const unsigned us_raw = ((const unsigned*)(A.h + (size_t)sIdx[el] * 64))[c];
      const unsigned ud_raw = ((const unsigned*)(A.h + (size_t)sIdx[32 + el] * 64))[c];
      unsigned* rp = (unsigned*)((char*)aA + el * (SMS * 2));
      rp[c] = us_raw;
      rp[32 + c] = ud_raw;
      const float s0 = bf2f_lo(us_raw), s1 = bf2f_hi(us_raw);
      const float d0 = bf2f_lo(ud_raw), d1 = bf2f_hi(ud_raw);
      rp[64 + c] = pack2(s0 + d0, s1 + d1);
      const float q0 = s0 - d0, q1 = s1 - d1;
      rp[96 + c] = pack2(q0 * q0, q1 * q1);
    }
  }
  __syncthreads();

  // ---- E2: layer1 via 32x32x16 MFMA (M=32, K=320, N=128; wave = 32-col tile)
  {
    const char* arow = (const char*)aA + l31 * (SMS * 2) + hi * 16;
    const short* BW = A.W1P + wv * 20 * 512 + lane * 8;
    f32x16 acc = {0.f, 0.f, 0.f, 0.f, 0.f, 0.f, 0.f, 0.f,
                  0.f, 0.f, 0.f, 0.f, 0.f, 0.f, 0.f, 0.f};
    for (int ks = 0; ks < 20; ++ks) {
      const bf16x8 a = *(const bf16x8*)(arow + ks * 32);
      const bf16x8 b = *(const bf16x8*)(BW + ks * 512);
      acc = MFMA32(a, b, acc);
    }
    const int col = wv * 32 + l31;
    const float bb = A.pm_b1[col];
#pragma unroll
    for (int reg = 0; reg < 16; ++reg) {
      const int row = (reg & 3) + 8 * (reg >> 2) + 4 * hi;
      aH1[row * H1S + col] = f2bf(gelu_f(acc[reg] + bb));
    }
  }
  __syncthreads();

  // ---- E3: layer2 16x16 MFMA (K=128, N=64) + bias + edge_memory -> aM (x) + aMq (x^2)
  {
    const char* arow = (const char*)aH1 + (mt * 16 + l15) * (H1S * 2) + g * 16;
    const short* BW = A.W2P + nh * 2 * 4 * 512 + lane * 8;
    f32x4 ac0 = {0.f, 0.f, 0.f, 0.f}, ac1 = ac0;
    for (int ks = 0; ks < 4; ++ks) {
      const bf16x8 a = *(const bf16x8*)(arow + ks * 64);
      const bf16x8 b0 = *(const bf16x8*)(BW + (0 * 4 + ks) * 512);
      const bf16x8 b1 = *(const bf16x8*)(BW + (1 * 4 + ks) * 512);
      ac0 = MFMA16(a, b0, ac0);
      ac1 = MFMA16(a, b1, ac1);
    }
    const int rb = mt * 16 + g * 4;
#define EPI2(j, accv) { \
    const int col = (nh * 2 + (j)) * 16 + l15; \
    const float bb = A.pm_b2[col]; \
    _Pragma("unroll") \
    for (int rg = 0; rg < 4; ++rg) { \
      const int row = rb + rg; \
      const float x = accv[rg] + bb + A.edge_mem[(size_t)(e0 + row) * 64 + col]; \
      const unsigned pk = pack2(x, x * x); \
      aM[row * MSR + col] = (short)pk; \
      aMq[row * MSR + col] = (short)(pk >> 16); \
    } \
  }
    EPI2(0, ac0) EPI2(1, ac1)
#undef EPI2
  }
  __syncthreads();

  // ---- LN sums via MFMA: wave (mt, q): C = A . ones, A = x or x^2
  {
    const int q = wv >> 1;
    const short* src = q ? aMq : aM;
    const short ONE = (short)0x3F80;
    const bf16x8 bones = {ONE, ONE, ONE, ONE, ONE, ONE, ONE, ONE};
    f32x4 acc = {0.f, 0.f, 0.f, 0.f};
#pragma unroll
    for (int ks = 0; ks < 2; ++ks) {
      const bf16x8 a = *(const bf16x8*)((const char*)src + (mt * 16 + l15) * (MSR * 2) + ks * 64 + g * 16);
      acc = MFMA16(a, bones, acc);
    }
    if (l15 == 0) {
#pragma unroll
      for (int rg = 0; rg < 4; ++rg)
        sSums[q * 32 + mt * 16 + g * 4 + rg] = acc[rg];
    }
  }
  __syncthreads();

  // ---- LN normalize (elementwise, in-place on aM) + m f32 output
  {
    const float lg = A.ln_g[lane], lb = A.ln_b[lane];
    float* out_m = A.out + (size_t)10 * NE;
#pragma unroll
    for (int p = 0; p < 8; ++p) {
      const int r = p * 4 + wv;
      const float x = bf2f(aM[r * MSR + lane]);
      const float mean = sSums[r] * (1.0f / 64.0f);
      const float var = fmaxf(sSums[32 + r] * (1.0f / 64.0f) - mean * mean, 0.0f);
      const float rstd = rsqrtf(var + 1e-5f);
      const float y = fmaf((x - mean) * rstd, lg, lb);
      aM[r * MSR + lane] = f2bf(y);
      out_m[(size_t)(e0 + r) * 64 + lane] = y;
    }
  }
  __syncthreads();

  // ---- E4: head hidden via 32x32x16 MFMA (M=32, K=64, N=224; wave tiles {wv, wv+4})
  {
    const char* arow = (const char*)aM + l31 * (MSR * 2) + hi * 16;
    bf16x8 af0 = *(const bf16x8*)(arow);
    bf16x8 af1 = *(const bf16x8*)(arow + 32);
    bf16x8 af2 = *(const bf16x8*)(arow + 64);
    bf16x8 af3 = *(const bf16x8*)(arow + 96);
    for (int nt = wv; nt < 7; nt += 4) {
      const short* BW = A.WHP + nt * 4 * 512 + lane * 8;
      f32x16 acc = {0.f, 0.f, 0.f, 0.f, 0.f, 0.f, 0.f, 0.f,
                    0.f, 0.f, 0.f, 0.f, 0.f, 0.f, 0.f, 0.f};
      acc = MFMA32(af0, *(const bf16x8*)(BW + 0 * 512), acc);
      acc = MFMA32(af1, *(const bf16x8*)(BW + 1 * 512), acc);
      acc = MFMA32(af2, *(const bf16x8*)(BW + 2 * 512), acc);
      acc = MFMA32(af3, *(const bf16x8*)(BW + 3 * 512), acc);
      const int col = nt * 32 + l31;
      const float bb = A.HB[col];
#pragma unroll
      for (int reg = 0; reg < 16; ++reg) {
        const int row = (reg & 3) + 8 * (reg >> 2) + 4 * hi;
        aZ[row * ZST + col] = f2bf(gelu_f(acc[reg] + bb));
      }
    }
  }
  __syncthreads();

  // ---- E5: head outputs via MFMA (M=32, K=224, N=16; cols 0..4 valid)
  if (wv < 2) {
    f32x4 acc = {0.f, 0.f, 0.f, 0.f};
    for (int ks = 0; ks < 7; ++ks) {
      const bf16x8 a = *(const bf16x8*)((const char*)aZ + (wv * 16 + l15) * (ZST * 2) + ks * 64 + g * 16);
      const bf16x8 b = *(const bf16x8*)(A.WOP + ks * 512 + lane * 8);
      acc = MFMA16(a, b, acc);
    }
    if (l15 < 5) {
      const float bb = A.HB2[l15];
#pragma unroll
      for (int rg = 0; rg < 4; ++rg)
        sSc2[(wv * 16 + g * 4 + rg) * 8 + l15] = acc[rg] + bb;
    }
  }
  __syncthreads();

  // ---- E5b: flux epilogue
  if (tid < 32) {
    const int e = tid;
    const float* st = &sSc[e * 8];
    const float n0 = st[0], n1 = st[1], r = st[2];
    const float du0 = st[3], du1 = st[4], du3 = st[5], du4 = st[6];
    const float arho = sSc2[e * 8 + 0], aen = sSc2[e * 8 + 1];
    const float amu0 = sSc2[e * 8 + 2], amu1 = sSc2[e * 8 + 3];
    const float av = sSc2[e * 8 + 4];
    const float alpha = __builtin_amdgcn_rcpf(1.0f + __builtin_amdgcn_exp2f(-1.4426950408f * av));
    const size_t ge = (size_t)(e0 + e);
    float* out = A.out;
    const float c0 = arho - alpha * du0;
    out[ge * 2 + 0] = c0 * n0;
    out[ge * 2 + 1] = c0 * n1;
    const float c1 = aen - alpha * du1;
    out[(size_t)2 * NE + ge * 2 + 0] = c1 * n0;
    out[(size_t)2 * NE + ge * 2 + 1] = c1 * n1;
    out[(size_t)4 * NE + ge * 2 + 0] = amu0 * n0 - amu1 * n1 - alpha * du3;
    out[(size_t)4 * NE + ge * 2 + 1] = amu0 * n1 + amu1 * n0 - alpha * du4;
    out[(size_t)6 * NE + ge * 2 + 0] = n0;
    out[(size_t)6 * NE + ge * 2 + 1] = n1;
    out[(size_t)8 * NE + ge] = r;
    out[(size_t)9 * NE + ge] = alpha;
  }
}

extern "C" void kernel_launch(void* const* d_in, const int* in_sizes, int n_in,
                              void* d_out, int out_size, void* d_ws, size_t ws_size,
                              hipStream_t stream) {
  const float* node_u = (const float*)d_in[0];
  const float* pn_W1 = (const float*)d_in[6];
  const float* pn_b1 = (const float*)d_in[7];
  const float* pn_W2 = (const float*)d_in[8];
  const float* pn_b2 = (const float*)d_in[9];
  const float* ip_W = (const float*)d_in[10];
  const float* ip_b = (const float*)d_in[11];

  char* ws = (char*)d_ws;
  unsigned short* h = (unsigned short*)ws;        // 12,800,000 B
  short* W1P = (short*)(ws + 12800000);           // 81,920 B
  short* W2P = (short*)(ws + 12881920);           // 16,384 B
  short* WHP = (short*)(ws + 12898304);           // 28,672 B
  float* HB  = (float*)(ws + 12926976);           // 896 B
  short* WEP = (short*)(ws + 12927872);           // 2,048 B
  short* WOP = (short*)(ws + 12929920);           // 7,168 B
  float* HB2 = (float*)(ws + 12937088);           // 64 B

  EdgeArgs A;
  A.node_u = node_u;
  A.edge_attr = (const float*)d_in[1];
  A.mean_mom = (const float*)d_in[2];
  A.std_mom = (const float*)d_in[3];
  A.edge_mem = (const float*)d_in[4];
  A.eidx = (const int*)d_in[5];
  A.pe_W1 = (const float*)d_in[12];
  A.pe_b1 = (const float*)d_in[13];
  A.pe_b2 = (const float*)d_in[15];
  A.pm_b1 = (const float*)d_in[17];
  A.pm_b2 = (const float*)d_in[19];
  A.ln_g = (const float*)d_in[36];
  A.ln_b = (const float*)d_in[37];
  A.h = h;
  A.W1P = W1P;
  A.W2P = W2P;
  A.WHP = WHP;
  A.WEP = WEP;
  A.WOP = WOP;
  A.HB = HB;
  A.HB2 = HB2;
  A.out = (float*)d_out;

  prep_kernel<<<267, 256, 0, stream>>>(
      (const float*)d_in[16], (const float*)d_in[18],
      (const float*)d_in[20], (const float*)d_in[24],
      (const float*)d_in[28], (const float*)d_in[32],
      (const float*)d_in[21], (const float*)d_in[25],
      (const float*)d_in[29], (const float*)d_in[33],
      (const float*)d_in[14],
      (const float*)d_in[22], (const float*)d_in[26],
      (const float*)d_in[30], (const float*)d_in[34],
      (const float*)d_in[23], (const float*)d_in[27],
      (const float*)d_in[31], (const float*)d_in[35],
      W1P, W2P, WHP, HB, WEP, WOP, HB2);
  node_h_kernel<<<NN / 4, 256, 0, stream>>>(node_u, pn_W1, pn_b1, pn_W2, pn_b2,
                                            ip_W, ip_b, h);
  edge_kernel<<<NE / 32, 256, 0, stream>>>(A);
}

// Round 7
// 215.639 us; speedup vs baseline: 1.3302x; 1.2265x over previous
//
#include <hip/hip_runtime.h>
#include <math.h>

#define NN 100000
#define NE 500000

typedef short bf16x8 __attribute__((ext_vector_type(8)));
typedef float f32x4 __attribute__((ext_vector_type(4)));
typedef float f32x16 __attribute__((ext_vector_type(16)));

// fast tanh-approx gelu (exp2-based): |err| <= ~3e-3 vs exact erf-gelu.
__device__ __forceinline__ float gelu_f(float x) {
  const float t = x * x;
  const float p = fmaf(t, 0.10294325f, 2.3022084f);
  const float E = __builtin_amdgcn_exp2f(x * p);
  const float r = __builtin_amdgcn_rcpf(E + 1.0f);
  return fmaf(-x, r, x);
}
// HW packed f32->bf16 (RNE), gfx950: v_cvt_pk_bf16_f32
__device__ __forceinline__ unsigned cvtpk(float lo, float hi) {
  unsigned r;
  asm("v_cvt_pk_bf16_f32 %0, %1, %2" : "=v"(r) : "v"(lo), "v"(hi));
  return r;
}
__device__ __forceinline__ short f2bf(float x) { return (short)cvtpk(x, x); }
__device__ __forceinline__ unsigned pack2(float a, float b) { return cvtpk(a, b); }
__device__ __forceinline__ float bf2f(short s) {
  unsigned u = ((unsigned)(unsigned short)s) << 16;
  return __builtin_bit_cast(float, u);
}
__device__ __forceinline__ float bf2f_lo(unsigned w) {
  return __builtin_bit_cast(float, w << 16);
}
__device__ __forceinline__ float bf2f_hi(unsigned w) {
  return __builtin_bit_cast(float, w & 0xFFFF0000u);
}

#define MFMA16(a, b, c) __builtin_amdgcn_mfma_f32_16x16x32_bf16((a), (b), (c), 0, 0, 0)
#define MFMA32(a, b, c) __builtin_amdgcn_mfma_f32_32x32x16_bf16((a), (b), (c), 0, 0, 0)

// ---------------- Kernel 1: per-node h via MFMA (64 nodes/block) ----------------
// h = gelu(u@pnW1 + b1) @ pnW2 + b2 + u@ipW + ipb
__global__ __launch_bounds__(256) void node_h_kernel(
    const float* __restrict__ node_u,
    const float* __restrict__ b1, const float* __restrict__ b2,
    const float* __restrict__ ipb,
    const short* __restrict__ W1NP, const short* __restrict__ IPNP,
    const short* __restrict__ W2NP,
    unsigned short* __restrict__ h) {
  __shared__ float sU[64 * 5];
  __shared__ short sG[64 * 72];
  const int tid = threadIdx.x;
  const int lane = tid & 63;
  const int wv = tid >> 6;
  const int l31 = lane & 31, hi = lane >> 5;
  const int mt = wv & 1, nh = wv >> 1;
  const int n0 = blockIdx.x * 64;
  const int nrem = NN - n0;

  {  // stage u
    const int cnt = (nrem < 64 ? nrem : 64) * 5;
    for (int t = tid; t < cnt; t += 256) sU[t] = node_u[(size_t)n0 * 5 + t];
  }
  __syncthreads();

  // phase1: layer1 pre-act (gelu -> sG) and ip (kept in regs) via MFMA, K=5 pad 16
  const int row_node = mt * 32 + l31;
  const int col = nh * 32 + l31;
  bf16x8 au;
#pragma unroll
  for (int e = 0; e < 8; ++e)
    au[e] = (hi == 0 && e < 5) ? f2bf(sU[row_node * 5 + e]) : (short)0;
  f32x16 acc1, accip;
  const float b1v = b1[col];
  const float ipv = ipb[col] + b2[col];
#pragma unroll
  for (int reg = 0; reg < 16; ++reg) { acc1[reg] = b1v; accip[reg] = ipv; }
  acc1 = MFMA32(au, *(const bf16x8*)(W1NP + nh * 512 + lane * 8), acc1);
  accip = MFMA32(au, *(const bf16x8*)(IPNP + nh * 512 + lane * 8), accip);
#pragma unroll
  for (int reg = 0; reg < 16; ++reg) {
    const int r = mt * 32 + (reg & 3) + 8 * (reg >> 2) + 4 * hi;
    sG[r * 72 + col] = f2bf(gelu_f(acc1[reg]));
  }
  __syncthreads();

  // phase2: h = g @ W2 + ip
  {
    const char* arow = (const char*)sG + row_node * 144 + hi * 16;
    const short* BW = W2NP + nh * 4 * 512 + lane * 8;
    f32x16 acc = accip;
#pragma unroll
    for (int ks = 0; ks < 4; ++ks)
      acc = MFMA32(*(const bf16x8*)(arow + ks * 32),
                   *(const bf16x8*)(BW + ks * 512), acc);
#pragma unroll
    for (int reg = 0; reg < 16; ++reg) {
      const int r = mt * 32 + (reg & 3) + 8 * (reg >> 2) + 4 * hi;
      const int node = n0 + r;
      if (node < NN) h[(size_t)node * 64 + col] = (unsigned short)f2bf(acc[reg]);
    }
  }
}

// ---------------- Kernel 0: weight repack + algebraic folds ----------------
// 16x16 frag block = 512 bf16: k = ks*32 + 8*(l>>4) + e, n = nt*16 + (l&15).
// 32x32 frag block = 512 bf16: k = ks*16 + 8*(l>>5) + e, n = nt*32 + (l&31).
// Folded W1' (240x128): rows [0,64)=hs: W1[k]+W1[128+k]; [64,128)=hd: W1[k]+W1[64+k];
// [128,192)=sq: W1[64+k]; [192,224)=hid: pe_W2 @ W1[256:288); [224,228)=vel: W1[64+k].
// B1F = pm_b1 + pe_b2 @ W1[256:288).
__global__ __launch_bounds__(256) void prep_kernel(
    const float* __restrict__ pm_W1, const float* __restrict__ pm_b1,
    const float* __restrict__ pm_W2,
    const float* __restrict__ prho_W1, const float* __restrict__ pen_W1,
    const float* __restrict__ pmu_W1, const float* __restrict__ pv_W1,
    const float* __restrict__ prho_b1, const float* __restrict__ pen_b1,
    const float* __restrict__ pmu_b1, const float* __restrict__ pv_b1,
    const float* __restrict__ pe_W2, const float* __restrict__ pe_b2,
    const float* __restrict__ prho_W2, const float* __restrict__ pen_W2,
    const float* __restrict__ pmu_W2, const float* __restrict__ pv_W2,
    const float* __restrict__ prho_b2, const float* __restrict__ pen_b2,
    const float* __restrict__ pmu_b2, const float* __restrict__ pv_b2,
    const float* __restrict__ pn_W1, const float* __restrict__ pn_W2,
    const float* __restrict__ ip_W,
    short* __restrict__ W1P, short* __restrict__ W2P, short* __restrict__ WHP,
    float* __restrict__ HB, short* __restrict__ WOP, float* __restrict__ HB2,
    float* __restrict__ B1F, short* __restrict__ W1NP, short* __restrict__ IPNP,
    short* __restrict__ W2NP) {
  int t = blockIdx.x * 256 + threadIdx.x;
  if (t < 30720) {  // folded W1': 240x128, 32x32 frag [nt=4][ks=15][512]
    const int nt = t / 7680, rem = t % 7680;
    const int ks = rem / 512, li = rem % 512;
    const int l = li >> 3, e = li & 7;
    const int k = ks * 16 + ((l >> 5) << 3) + e;
    const int n = nt * 32 + (l & 31);
    float v = 0.0f;
    if (k < 64) v = pm_W1[k * 128 + n] + pm_W1[(128 + k) * 128 + n];
    else if (k < 128) v = pm_W1[k * 128 + n] + pm_W1[(64 + k) * 128 + n];
    else if (k < 192) v = pm_W1[(64 + k) * 128 + n];
    else if (k < 224) {
      const int i = k - 192;
      for (int j = 0; j < 32; ++j) v += pe_W2[i * 32 + j] * pm_W1[(256 + j) * 128 + n];
    } else if (k < 228) v = pm_W1[(64 + k) * 128 + n];
    W1P[t] = f2bf(v);
    return;
  }
  t -= 30720;
  if (t < 8192) {  // pm_W2 16x16-frag: 128x64, [nt=4][ks=4][512]
    const int nt = t / 2048, rem = t % 2048;
    const int ks = rem / 512, li = rem % 512;
    const int l = li >> 3, e = li & 7;
    const int k = ks * 32 + ((l >> 4) << 3) + e;
    const int n = nt * 16 + (l & 15);
    W2P[t] = f2bf(pm_W2[k * 64 + n]);
    return;
  }
  t -= 8192;
  if (t < 14336) {  // heads W1 concat 32x32-frag: 64x224, [nt=7][ks=4][512]
    const int nt = t / 2048, rem = t % 2048;
    const int ks = rem / 512, li = rem % 512;
    const int l = li >> 3, e = li & 7;
    const int k = ks * 16 + ((l >> 5) << 3) + e;
    const int col = nt * 32 + (l & 31);
    float v;
    if (col < 64) v = prho_W1[k * 64 + col];
    else if (col < 128) v = pen_W1[k * 64 + (col - 64)];
    else if (col < 192) v = pmu_W1[k * 64 + (col - 128)];
    else v = pv_W1[k * 32 + (col - 192)];
    WHP[t] = f2bf(v);
    return;
  }
  t -= 14336;
  if (t < 224) {  // head hidden biases concat (f32)
    HB[t] = (t < 64) ? prho_b1[t]
          : (t < 128) ? pen_b1[t - 64]
          : (t < 192) ? pmu_b1[t - 128]
          : pv_b1[t - 192];
    return;
  }
  t -= 224;
  if (t < 3584) {  // stacked head W2 16x16-frag: 224x16, [ks=7][512]
    const int ks = t / 512, li = t % 512;
    const int l = li >> 3, e = li & 7;
    const int k = ks * 32 + ((l >> 4) << 3) + e;
    const int j = l & 15;
    float v = 0.0f;
    if (j == 0 && k < 64) v = prho_W2[k];
    else if (j == 1 && k >= 64 && k < 128) v = pen_W2[k - 64];
    else if (j == 2 && k >= 128 && k < 192) v = pmu_W2[(k - 128) * 2 + 0];
    else if (j == 3 && k >= 128 && k < 192) v = pmu_W2[(k - 128) * 2 + 1];
    else if (j == 4 && k >= 192 && k < 224) v = pv_W2[k - 192];
    WOP[t] = f2bf(v);
    return;
  }
  t -= 3584;
  if (t < 16) {  // head output biases
    HB2[t] = (t == 0) ? prho_b2[0]
           : (t == 1) ? pen_b2[0]
           : (t == 2) ? pmu_b2[0]
           : (t == 3) ? pmu_b2[1]
           : (t == 4) ? pv_b2[0] : 0.0f;
    return;
  }
  t -= 16;
  if (t < 128) {  // folded layer1 bias (f32)
    float v = pm_b1[t];
    for (int j = 0; j < 32; ++j) v += pe_b2[j] * pm_W1[(256 + j) * 128 + t];
    B1F[t] = v;
    return;
  }
  t -= 128;
  if (t < 1024) {  // pn_W1 32x32-frag (K=5 pad 16): [nt=2][512]
    const int nt = t / 512, li = t % 512;
    const int l = li >> 3, e = li & 7;
    const int k = ((l >> 5) << 3) + e;
    const int n = nt * 32 + (l & 31);
    W1NP[t] = (k < 5) ? f2bf(pn_W1[k * 64 + n]) : (short)0;
    return;
  }
  t -= 1024;
  if (t < 1024) {  // ip_W 32x32-frag (K=5 pad 16): [nt=2][512]
    const int nt = t / 512, li = t % 512;
    const int l = li >> 3, e = li & 7;
    const int k = ((l >> 5) << 3) + e;
    const int n = nt * 32 + (l & 31);
    IPNP[t] = (k < 5) ? f2bf(ip_W[k * 64 + n]) : (short)0;
    return;
  }
  t -= 1024;
  if (t < 4096) {  // pn_W2 32x32-frag: 64x64, [nt=2][ks=4][512]
    const int nt = t / 2048, rem = t % 2048;
    const int ks = rem / 512, li = rem % 512;
    const int l = li >> 3, e = li & 7;
    const int k = ks * 16 + ((l >> 5) << 3) + e;
    const int n = nt * 32 + (l & 31);
    W2NP[t] = f2bf(pn_W2[k * 64 + n]);
  }
}

// ---------------- Kernel 2: per-edge fused MFMA pipeline, 32 edges / block ----------------
struct EdgeArgs {
  const float *node_u, *edge_attr, *mean_mom, *std_mom, *edge_mem;
  const int* eidx;
  const float *pe_W1, *pe_b1;
  const float *B1F, *pm_b2;
  const float *ln_g, *ln_b;
  const unsigned short* h;   // bf16
  const short *W1P, *W2P, *WHP, *WOP;
  const float *HB, *HB2;
  float* out;
};

#define SMS 248   // msg bf16 row stride (496 B; 496/16=31 odd -> conflict-free b128)
#define H1S 136   // h1 bf16 row stride (272 B)
#define MSR 72    // m bf16 row stride (144 B)
#define ZST 248   // z bf16 row stride (496 B)

// LDS map (31744 B -> 5 blocks/CU):
//  [0, 15872): msg bf16 [32][248]  (S0..E2);  overlay: aZ bf16 [32][248] (E4..E5)
//  [15872, 20480): aM bf16 [32][72] (E3 -> E4, LN in place)
//  [20480, 29184): h1 bf16 [32][136] (E2 -> E3)
//  [29184, 30208): sSc  f32 [32][8]
//  [30208, 31232): sSc2 f32 [32][8]
//  [31232, 31744): sPart float2 [32][2]  (LN partial sums)
#define OFF_A    0
#define OFF_AM   15872
#define OFF_H1   20480
#define OFF_SC   29184
#define OFF_SC2  30208
#define OFF_PART 31232
#define SMEM_BYTES 31744

__global__ __launch_bounds__(256, 5) void edge_kernel(EdgeArgs A) {
  __shared__ __align__(16) char smem[SMEM_BYTES];
  short* aA = (short*)(smem + OFF_A);
  short* aZ = (short*)(smem + OFF_A);
  short* aM = (short*)(smem + OFF_AM);
  short* aH1 = (short*)(smem + OFF_H1);
  float* sSc = (float*)(smem + OFF_SC);
  float* sSc2 = (float*)(smem + OFF_SC2);
  float2* sPart = (float2*)(smem + OFF_PART);

  const int tid = threadIdx.x;
  const int e0 = blockIdx.x * 32;
  const int lane = tid & 63;
  const int wv = tid >> 6;
  const int l15 = lane & 15, g = lane >> 4;
  const int l31 = lane & 31, hi = lane >> 5;
  const int mt = wv & 1, nh = wv >> 1;

  // ---- S0a (tid<32) || S0b || S0d: one phase, disjoint writes
  if (tid < 32) {
    const int e = e0 + tid;
    const int s = A.eidx[e];
    const int d = A.eidx[NE + e];
    const float dx = A.edge_attr[e * 3 + 0];
    const float dy = A.edge_attr[e * 3 + 1];
    const float r = A.edge_attr[e * 3 + 2];
    const float inv = 1.0f / (r + 1e-12f);
    const float n0 = dx * inv, n1 = dy * inv;  // t = (-n1, n0)
    const float* us = A.node_u + (size_t)s * 5;
    const float* ud = A.node_u + (size_t)d * 5;
    const float sm0 = A.std_mom[0], sm1 = A.std_mom[1];
    const float mm0 = A.mean_mom[0], mm1 = A.mean_mom[1];
    const float rs0 = fmaf(us[3], sm0, mm0), rs1 = fmaf(us[4], sm1, mm1);
    const float rd0 = fmaf(ud[3], sm0, mm0), rd1 = fmaf(ud[4], sm1, mm1);
    const float isc = 1.0f / (sqrtf(sm0 * sm0 + sm1 * sm1) + 1e-8f);
    unsigned* vp = (unsigned*)(aA + tid * SMS + 224);  // vel cols 224..228
    vp[0] = pack2((rs0 * n0 + rs1 * n1) * isc, (-rs0 * n1 + rs1 * n0) * isc);
    vp[1] = pack2((rd0 * n0 + rd1 * n1) * isc, (-rd0 * n1 + rd1 * n0) * isc);
    unsigned* zp = (unsigned*)(aA + tid * SMS + 228);  // zero pad 228..240
#pragma unroll
    for (int z = 0; z < 6; ++z) zp[z] = 0u;
    float* st = &sSc[tid * 8];
    st[0] = n0; st[1] = n1; st[2] = r;
    st[3] = ud[0] - us[0];
    st[4] = ud[1] - us[1];
    st[5] = ud[3] - us[3];
    st[6] = ud[4] - us[4];
  }
  {  // S0b: eps hidden (1 -> 32, gelu) -> msg cols [192..224)
    const int i = tid & 31, eg = tid >> 5;
    const float w1 = A.pe_W1[i], b1 = A.pe_b1[i];
#pragma unroll
    for (int p = 0; p < 4; ++p) {
      const int el = eg * 4 + p;
      const float rv = A.edge_attr[(e0 + el) * 3 + 2];
      aA[el * SMS + 192 + i] = f2bf(gelu_f(fmaf(rv, w1, b1)));
    }
  }
  {  // S0d: h gathers -> msg cols [0..192): hs | hd | (hs-hd)^2
    const int c = tid & 31, eg = tid >> 5;
#pragma unroll
    for (int p = 0; p < 4; ++p) {
      const int el = eg * 4 + p;
      const int s = A.eidx[e0 + el];
      const int d = A.eidx[NE + e0 + el];
      const unsigned us_raw = ((const unsigned*)(A.h + (size_t)s * 64))[c];
      const unsigned ud_raw = ((const unsigned*)(A.h + (size_t)d * 64))[c];
      unsigned* rp = (unsigned*)((char*)aA + el * (SMS * 2));
      rp[c] = us_raw;
      rp[32 + c] = ud_raw;
      const float s0 = bf2f_lo(us_raw), s1 = bf2f_hi(us_raw);
      const float d0 = bf2f_lo(ud_raw), d1 = bf2f_hi(ud_raw);
      const float q0 = s0 - d0, q1 = s1 - d1;
      rp[64 + c] = pack2(q0 * q0, q1 * q1);
    }
  }
  __syncthreads();

  // ---- E2: layer1 via 32x32x16 MFMA (M=32, K=240, N=128)
  {
    const char* arow = (const char*)aA + l31 * (SMS * 2) + hi * 16;
    const short* BW = A.W1P + wv * 15 * 512 + lane * 8;
    f32x16 acc = {0.f, 0.f, 0.f, 0.f, 0.f, 0.f, 0.f, 0.f,
                  0.f, 0.f, 0.f, 0.f, 0.f, 0.f, 0.f, 0.f};
    for (int ks = 0; ks < 15; ++ks) {
      acc = MFMA32(*(const bf16x8*)(arow + ks * 32),
                   *(const bf16x8*)(BW + ks * 512), acc);
    }
    const int col = wv * 32 + l31;
    const float bb = A.B1F[col];
#pragma unroll
    for (int reg = 0; reg < 16; ++reg) {
      const int row = (reg & 3) + 8 * (reg >> 2) + 4 * hi;
      aH1[row * H1S + col] = f2bf(gelu_f(acc[reg] + bb));
    }
  }
  __syncthreads();

  // ---- E3: layer2 16x16 MFMA (K=128, N=64) + bias + edge_memory -> aM + LN partials
  {
    const char* arow = (const char*)aH1 + (mt * 16 + l15) * (H1S * 2) + g * 16;
    const short* BW = A.W2P + nh * 2 * 4 * 512 + lane * 8;
    f32x4 ac0 = {0.f, 0.f, 0.f, 0.f}, ac1 = ac0;
    for (int ks = 0; ks < 4; ++ks) {
      const bf16x8 a = *(const bf16x8*)(arow + ks * 64);
      ac0 = MFMA16(a, *(const bf16x8*)(BW + (0 * 4 + ks) * 512), ac0);
      ac1 = MFMA16(a, *(const bf16x8*)(BW + (1 * 4 + ks) * 512), ac1);
    }
    const int rb = mt * 16 + g * 4;
    const int c0 = (nh * 2 + 0) * 16 + l15, c1 = (nh * 2 + 1) * 16 + l15;
    const float bb0 = A.pm_b2[c0], bb1 = A.pm_b2[c1];
#pragma unroll
    for (int rg = 0; rg < 4; ++rg) {
      const int row = rb + rg;
      const float x0 = ac0[rg] + bb0 + A.edge_mem[(size_t)(e0 + row) * 64 + c0];
      const float x1 = ac1[rg] + bb1 + A.edge_mem[(size_t)(e0 + row) * 64 + c1];
      const unsigned pk = pack2(x0, x1);
      aM[row * MSR + c0] = (short)pk;
      aM[row * MSR + c1] = (short)(pk >> 16);
      float sx = x0 + x1;
      float sq = fmaf(x0, x0, x1 * x1);
#pragma unroll
      for (int m = 1; m < 16; m <<= 1) {
        sx += __shfl_xor(sx, m, 64);
        sq += __shfl_xor(sq, m, 64);
      }
      if (l15 == 0) sPart[row * 2 + nh] = make_float2(sx, sq);
    }
  }
  __syncthreads();

  // ---- LN normalize (elementwise, in-place on aM) + m f32 output
  {
    const float lg = A.ln_g[lane], lb = A.ln_b[lane];
    float* out_m = A.out + (size_t)10 * NE;
#pragma unroll
    for (int p = 0; p < 8; ++p) {
      const int r = p * 4 + wv;
      const float x = bf2f(aM[r * MSR + lane]);
      const float2 pa = sPart[r * 2 + 0], pb = sPart[r * 2 + 1];
      const float mean = (pa.x + pb.x) * (1.0f / 64.0f);
      const float var = fmaxf((pa.y + pb.y) * (1.0f / 64.0f) - mean * mean, 0.0f);
      const float rstd = rsqrtf(var + 1e-5f);
      const float y = fmaf((x - mean) * rstd, lg, lb);
      aM[r * MSR + lane] = f2bf(y);
      out_m[(size_t)(e0 + r) * 64 + lane] = y;
    }
  }
  __syncthreads();

  // ---- E4: head hidden via 32x32x16 MFMA (M=32, K=64, N=224) -> z (overlay msg)
  {
    const char* arow = (const char*)aM + l31 * (MSR * 2) + hi * 16;
    bf16x8 af0 = *(const bf16x8*)(arow);
    bf16x8 af1 = *(const bf16x8*)(arow + 32);
    bf16x8 af2 = *(const bf16x8*)(arow + 64);
    bf16x8 af3 = *(const bf16x8*)(arow + 96);
    for (int nt = wv; nt < 7; nt += 4) {
      const short* BW = A.WHP + nt * 4 * 512 + lane * 8;
      f32x16 acc = {0.f, 0.f, 0.f, 0.f, 0.f, 0.f, 0.f, 0.f,
                    0.f, 0.f, 0.f, 0.f, 0.f, 0.f, 0.f, 0.f};
      acc = MFMA32(af0, *(const bf16x8*)(BW + 0 * 512), acc);
      acc = MFMA32(af1, *(const bf16x8*)(BW + 1 * 512), acc);
      acc = MFMA32(af2, *(const bf16x8*)(BW + 2 * 512), acc);
      acc = MFMA32(af3, *(const bf16x8*)(BW + 3 * 512), acc);
      const int col = nt * 32 + l31;
      const float bb = A.HB[col];
#pragma unroll
      for (int reg = 0; reg < 16; ++reg) {
        const int row = (reg & 3) + 8 * (reg >> 2) + 4 * hi;
        aZ[row * ZST + col] = f2bf(gelu_f(acc[reg] + bb));
      }
    }
  }
  __syncthreads();

  // ---- E5: head outputs via MFMA (M=32, K=224, N=16; cols 0..4) + fused epilogue
  if (wv < 2) {
    f32x4 acc = {0.f, 0.f, 0.f, 0.f};
    for (int ks = 0; ks < 7; ++ks) {
      const bf16x8 a = *(const bf16x8*)((const char*)aZ + (wv * 16 + l15) * (ZST * 2) + ks * 64 + g * 16);
      const bf16x8 b = *(const bf16x8*)(A.WOP + ks * 512 + lane * 8);
      acc = MFMA16(a, b, acc);
    }
    if (l15 < 5) {
      const float bb = A.HB2[l15];
#pragma unroll
      for (int rg = 0; rg < 4; ++rg)
        sSc2[(wv * 16 + g * 4 + rg) * 8 + l15] = acc[rg] + bb;
    }
    asm volatile("s_waitcnt lgkmcnt(0)" ::: "memory");
    __builtin_amdgcn_sched_barrier(0);
    if (lane < 16) {  // same wave wrote all 16 of its edges' head values
      const int e = wv * 16 + lane;
      const float* st = &sSc[e * 8];
      const float n0 = st[0], n1 = st[1], r = st[2];
      const float du0 = st[3], du1 = st[4], du3 = st[5], du4 = st[6];
      const float arho = sSc2[e * 8 + 0], aen = sSc2[e * 8 + 1];
      const float amu0 = sSc2[e * 8 + 2], amu1 = sSc2[e * 8 + 3];
      const float av = sSc2[e * 8 + 4];
      const float alpha = __builtin_amdgcn_rcpf(1.0f + __builtin_amdgcn_exp2f(-1.4426950408f * av));
      const size_t ge = (size_t)(e0 + e);
      float* out = A.out;
      const float c0 = arho - alpha * du0;
      out[ge * 2 + 0] = c0 * n0;
      out[ge * 2 + 1] = c0 * n1;
      const float c1 = aen - alpha * du1;
      out[(size_t)2 * NE + ge * 2 + 0] = c1 * n0;
      out[(size_t)2 * NE + ge * 2 + 1] = c1 * n1;
      out[(size_t)4 * NE + ge * 2 + 0] = amu0 * n0 - amu1 * n1 - alpha * du3;
      out[(size_t)4 * NE + ge * 2 + 1] = amu0 * n1 + amu1 * n0 - alpha * du4;
      out[(size_t)6 * NE + ge * 2 + 0] = n0;
      out[(size_t)6 * NE + ge * 2 + 1] = n1;
      out[(size_t)8 * NE + ge] = r;
      out[(size_t)9 * NE + ge] = alpha;
    }
  }
}

extern "C" void kernel_launch(void* const* d_in, const int* in_sizes, int n_in,
                              void* d_out, int out_size, void* d_ws, size_t ws_size,
                              hipStream_t stream) {
  char* ws = (char*)d_ws;
  unsigned short* h = (unsigned short*)ws;         // 12,800,000 B
  short* W1P  = (short*)(ws + 12800000);           // 61,440 B
  short* W2P  = (short*)(ws + 12861440);           // 16,384 B
  short* WHP  = (short*)(ws + 12877824);           // 28,672 B
  float* HB   = (float*)(ws + 12906496);           // 896 B
  short* WOP  = (short*)(ws + 12907392);           // 7,168 B
  float* HB2  = (float*)(ws + 12914560);           // 64 B
  float* B1F  = (float*)(ws + 12914624);           // 512 B
  short* W1NP = (short*)(ws + 12915136);           // 2,048 B
  short* IPNP = (short*)(ws + 12917184);           // 2,048 B
  short* W2NP = (short*)(ws + 12919232);           // 8,192 B

  EdgeArgs A;
  A.node_u = (const float*)d_in[0];
  A.edge_attr = (const float*)d_in[1];
  A.mean_mom = (const float*)d_in[2];
  A.std_mom = (const float*)d_in[3];
  A.edge_mem = (const float*)d_in[4];
  A.eidx = (const int*)d_in[5];
  A.pe_W1 = (const float*)d_in[12];
  A.pe_b1 = (const float*)d_in[13];
  A.B1F = B1F;
  A.pm_b2 = (const float*)d_in[19];
  A.ln_g = (const float*)d_in[36];
  A.ln_b = (const float*)d_in[37];
  A.h = h;
  A.W1P = W1P;
  A.W2P = W2P;
  A.WHP = WHP;
  A.WOP = WOP;
  A.HB = HB;
  A.HB2 = HB2;
  A.out = (float*)d_out;

  prep_kernel<<<248, 256, 0, stream>>>(
      (const float*)d_in[16], (const float*)d_in[17], (const float*)d_in[18],
      (const float*)d_in[20], (const float*)d_in[24],
      (const float*)d_in[28], (const float*)d_in[32],
      (const float*)d_in[21], (const float*)d_in[25],
      (const float*)d_in[29], (const float*)d_in[33],
      (const float*)d_in[14], (const float*)d_in[15],
      (const float*)d_in[22], (const float*)d_in[26],
      (const float*)d_in[30], (const float*)d_in[34],
      (const float*)d_in[23], (const float*)d_in[27],
      (const float*)d_in[31], (const float*)d_in[35],
      (const float*)d_in[6], (const float*)d_in[8], (const float*)d_in[10],
      W1P, W2P, WHP, HB, WOP, HB2, B1F, W1NP, IPNP, W2NP);
  node_h_kernel<<<(NN + 63) / 64, 256, 0, stream>>>(
      (const float*)d_in[0], (const float*)d_in[7], (const float*)d_in[9],
      (const float*)d_in[11], W1NP, IPNP, W2NP, h);
  edge_kernel<<<NE / 32, 256, 0, stream>>>(A);
}

// Round 8
// 202.266 us; speedup vs baseline: 1.4182x; 1.0661x over previous
//
#include <hip/hip_runtime.h>
#include <math.h>

#define NN 100000
#define NE 500000

typedef short bf16x8 __attribute__((ext_vector_type(8)));
typedef float f32x4 __attribute__((ext_vector_type(4)));
typedef float f32x16 __attribute__((ext_vector_type(16)));

// fast tanh-approx gelu (exp2-based): |err| <= ~3e-3 vs exact erf-gelu.
__device__ __forceinline__ float gelu_f(float x) {
  const float t = x * x;
  const float p = fmaf(t, 0.10294325f, 2.3022084f);
  const float E = __builtin_amdgcn_exp2f(x * p);
  const float r = __builtin_amdgcn_rcpf(E + 1.0f);
  return fmaf(-x, r, x);
}
// HW packed f32->bf16 (RNE), gfx950: v_cvt_pk_bf16_f32
__device__ __forceinline__ unsigned cvtpk(float lo, float hi) {
  unsigned r;
  asm("v_cvt_pk_bf16_f32 %0, %1, %2" : "=v"(r) : "v"(lo), "v"(hi));
  return r;
}
__device__ __forceinline__ short f2bf(float x) { return (short)cvtpk(x, x); }
__device__ __forceinline__ unsigned pack2(float a, float b) { return cvtpk(a, b); }
__device__ __forceinline__ float bf2f(short s) {
  unsigned u = ((unsigned)(unsigned short)s) << 16;
  return __builtin_bit_cast(float, u);
}
__device__ __forceinline__ float bf2f_lo(unsigned w) {
  return __builtin_bit_cast(float, w << 16);
}
__device__ __forceinline__ float bf2f_hi(unsigned w) {
  return __builtin_bit_cast(float, w & 0xFFFF0000u);
}

#define MFMA16(a, b, c) __builtin_amdgcn_mfma_f32_16x16x32_bf16((a), (b), (c), 0, 0, 0)
#define MFMA32(a, b, c) __builtin_amdgcn_mfma_f32_32x32x16_bf16((a), (b), (c), 0, 0, 0)

// ---------------- Kernel 1: per-node h via MFMA (64 nodes/block) ----------------
__global__ __launch_bounds__(256) void node_h_kernel(
    const float* __restrict__ node_u,
    const float* __restrict__ b1, const float* __restrict__ b2,
    const float* __restrict__ ipb,
    const short* __restrict__ W1NP, const short* __restrict__ IPNP,
    const short* __restrict__ W2NP,
    unsigned short* __restrict__ h) {
  __shared__ float sU[64 * 5];
  __shared__ short sG[64 * 72];
  const int tid = threadIdx.x;
  const int lane = tid & 63;
  const int wv = tid >> 6;
  const int l31 = lane & 31, hi = lane >> 5;
  const int mt = wv & 1, nh = wv >> 1;
  const int n0 = blockIdx.x * 64;
  const int nrem = NN - n0;

  {  // stage u
    const int cnt = (nrem < 64 ? nrem : 64) * 5;
    for (int t = tid; t < cnt; t += 256) sU[t] = node_u[(size_t)n0 * 5 + t];
  }
  __syncthreads();

  const int row_node = mt * 32 + l31;
  const int col = nh * 32 + l31;
  bf16x8 au;
#pragma unroll
  for (int e = 0; e < 8; ++e)
    au[e] = (hi == 0 && e < 5) ? f2bf(sU[row_node * 5 + e]) : (short)0;
  f32x16 acc1, accip;
  const float b1v = b1[col];
  const float ipv = ipb[col] + b2[col];
#pragma unroll
  for (int reg = 0; reg < 16; ++reg) { acc1[reg] = b1v; accip[reg] = ipv; }
  acc1 = MFMA32(au, *(const bf16x8*)(W1NP + nh * 512 + lane * 8), acc1);
  accip = MFMA32(au, *(const bf16x8*)(IPNP + nh * 512 + lane * 8), accip);
#pragma unroll
  for (int reg = 0; reg < 16; ++reg) {
    const int r = mt * 32 + (reg & 3) + 8 * (reg >> 2) + 4 * hi;
    sG[r * 72 + col] = f2bf(gelu_f(acc1[reg]));
  }
  __syncthreads();

  {
    const char* arow = (const char*)sG + row_node * 144 + hi * 16;
    const short* BW = W2NP + nh * 4 * 512 + lane * 8;
    f32x16 acc = accip;
#pragma unroll
    for (int ks = 0; ks < 4; ++ks)
      acc = MFMA32(*(const bf16x8*)(arow + ks * 32),
                   *(const bf16x8*)(BW + ks * 512), acc);
#pragma unroll
    for (int reg = 0; reg < 16; ++reg) {
      const int r = mt * 32 + (reg & 3) + 8 * (reg >> 2) + 4 * hi;
      const int node = n0 + r;
      if (node < NN) h[(size_t)node * 64 + col] = (unsigned short)f2bf(acc[reg]);
    }
  }
}

// ---------------- Kernel 0: weight repack + algebraic folds ----------------
// 16x16 frag block = 512 bf16: k = ks*32 + 8*(l>>4) + e, n = nt*16 + (l&15).
// 32x32 frag block = 512 bf16: k = ks*16 + 8*(l>>5) + e, n = nt*32 + (l&31).
__global__ __launch_bounds__(256) void prep_kernel(
    const float* __restrict__ pm_W1, const float* __restrict__ pm_b1,
    const float* __restrict__ pm_W2,
    const float* __restrict__ prho_W1, const float* __restrict__ pen_W1,
    const float* __restrict__ pmu_W1, const float* __restrict__ pv_W1,
    const float* __restrict__ prho_b1, const float* __restrict__ pen_b1,
    const float* __restrict__ pmu_b1, const float* __restrict__ pv_b1,
    const float* __restrict__ pe_W2, const float* __restrict__ pe_b2,
    const float* __restrict__ prho_W2, const float* __restrict__ pen_W2,
    const float* __restrict__ pmu_W2, const float* __restrict__ pv_W2,
    const float* __restrict__ prho_b2, const float* __restrict__ pen_b2,
    const float* __restrict__ pmu_b2, const float* __restrict__ pv_b2,
    const float* __restrict__ pn_W1, const float* __restrict__ pn_W2,
    const float* __restrict__ ip_W,
    short* __restrict__ W1P, short* __restrict__ W2P, short* __restrict__ WHP,
    float* __restrict__ HB, short* __restrict__ WOP, float* __restrict__ HB2,
    float* __restrict__ B1F, short* __restrict__ W1NP, short* __restrict__ IPNP,
    short* __restrict__ W2NP) {
  int t = blockIdx.x * 256 + threadIdx.x;
  if (t < 30720) {  // folded W1': 240x128, 32x32 frag [nt=4][ks=15][512]
    const int nt = t / 7680, rem = t % 7680;
    const int ks = rem / 512, li = rem % 512;
    const int l = li >> 3, e = li & 7;
    const int k = ks * 16 + ((l >> 5) << 3) + e;
    const int n = nt * 32 + (l & 31);
    float v = 0.0f;
    if (k < 64) v = pm_W1[k * 128 + n] + pm_W1[(128 + k) * 128 + n];
    else if (k < 128) v = pm_W1[k * 128 + n] + pm_W1[(64 + k) * 128 + n];
    else if (k < 192) v = pm_W1[(64 + k) * 128 + n];
    else if (k < 224) {
      const int i = k - 192;
      for (int j = 0; j < 32; ++j) v += pe_W2[i * 32 + j] * pm_W1[(256 + j) * 128 + n];
    } else if (k < 228) v = pm_W1[(64 + k) * 128 + n];
    W1P[t] = f2bf(v);
    return;
  }
  t -= 30720;
  if (t < 8192) {  // pm_W2 16x16-frag: 128x64, [nt=4][ks=4][512]
    const int nt = t / 2048, rem = t % 2048;
    const int ks = rem / 512, li = rem % 512;
    const int l = li >> 3, e = li & 7;
    const int k = ks * 32 + ((l >> 4) << 3) + e;
    const int n = nt * 16 + (l & 15);
    W2P[t] = f2bf(pm_W2[k * 64 + n]);
    return;
  }
  t -= 8192;
  if (t < 14336) {  // heads W1 concat 32x32-frag: 64x224, [nt=7][ks=4][512]
    const int nt = t / 2048, rem = t % 2048;
    const int ks = rem / 512, li = rem % 512;
    const int l = li >> 3, e = li & 7;
    const int k = ks * 16 + ((l >> 5) << 3) + e;
    const int col = nt * 32 + (l & 31);
    float v;
    if (col < 64) v = prho_W1[k * 64 + col];
    else if (col < 128) v = pen_W1[k * 64 + (col - 64)];
    else if (col < 192) v = pmu_W1[k * 64 + (col - 128)];
    else v = pv_W1[k * 32 + (col - 192)];
    WHP[t] = f2bf(v);
    return;
  }
  t -= 14336;
  if (t < 224) {  // head hidden biases concat (f32)
    HB[t] = (t < 64) ? prho_b1[t]
          : (t < 128) ? pen_b1[t - 64]
          : (t < 192) ? pmu_b1[t - 128]
          : pv_b1[t - 192];
    return;
  }
  t -= 224;
  if (t < 3584) {  // stacked head W2 16x16-frag: 224x16, [ks=7][512]
    const int ks = t / 512, li = t % 512;
    const int l = li >> 3, e = li & 7;
    const int k = ks * 32 + ((l >> 4) << 3) + e;
    const int j = l & 15;
    float v = 0.0f;
    if (j == 0 && k < 64) v = prho_W2[k];
    else if (j == 1 && k >= 64 && k < 128) v = pen_W2[k - 64];
    else if (j == 2 && k >= 128 && k < 192) v = pmu_W2[(k - 128) * 2 + 0];
    else if (j == 3 && k >= 128 && k < 192) v = pmu_W2[(k - 128) * 2 + 1];
    else if (j == 4 && k >= 192 && k < 224) v = pv_W2[k - 192];
    WOP[t] = f2bf(v);
    return;
  }
  t -= 3584;
  if (t < 16) {  // head output biases
    HB2[t] = (t == 0) ? prho_b2[0]
           : (t == 1) ? pen_b2[0]
           : (t == 2) ? pmu_b2[0]
           : (t == 3) ? pmu_b2[1]
           : (t == 4) ? pv_b2[0] : 0.0f;
    return;
  }
  t -= 16;
  if (t < 128) {  // folded layer1 bias (f32)
    float v = pm_b1[t];
    for (int j = 0; j < 32; ++j) v += pe_b2[j] * pm_W1[(256 + j) * 128 + t];
    B1F[t] = v;
    return;
  }
  t -= 128;
  if (t < 1024) {  // pn_W1 32x32-frag (K=5 pad 16): [nt=2][512]
    const int nt = t / 512, li = t % 512;
    const int l = li >> 3, e = li & 7;
    const int k = ((l >> 5) << 3) + e;
    const int n = nt * 32 + (l & 31);
    W1NP[t] = (k < 5) ? f2bf(pn_W1[k * 64 + n]) : (short)0;
    return;
  }
  t -= 1024;
  if (t < 1024) {  // ip_W 32x32-frag (K=5 pad 16): [nt=2][512]
    const int nt = t / 512, li = t % 512;
    const int l = li >> 3, e = li & 7;
    const int k = ((l >> 5) << 3) + e;
    const int n = nt * 32 + (l & 31);
    IPNP[t] = (k < 5) ? f2bf(ip_W[k * 64 + n]) : (short)0;
    return;
  }
  t -= 1024;
  if (t < 4096) {  // pn_W2 32x32-frag: 64x64, [nt=2][ks=4][512]
    const int nt = t / 2048, rem = t % 2048;
    const int ks = rem / 512, li = rem % 512;
    const int l = li >> 3, e = li & 7;
    const int k = ks * 16 + ((l >> 5) << 3) + e;
    const int n = nt * 32 + (l & 31);
    W2NP[t] = f2bf(pn_W2[k * 64 + n]);
  }
}

// ---------------- Kernel 2: per-edge fused MFMA pipeline, 32 edges / block ----------------
struct EdgeArgs {
  const float *node_u, *edge_attr, *mean_mom, *std_mom, *edge_mem;
  const int* eidx;
  const float *pe_W1, *pe_b1;
  const float *B1F, *pm_b2;
  const float *ln_g, *ln_b;
  const unsigned short* h;   // bf16
  const short *W1P, *W2P, *WHP, *WOP;
  const float *HB, *HB2;
  float* out;
};

#define SMS 248   // msg bf16 row stride (496 B)
#define H1S 136   // h1 bf16 row stride (272 B)
#define MSR 72    // m bf16 row stride (144 B)
#define ZST 248   // z bf16 row stride (496 B)

// LDS map (25,088 B -> 6 blocks/CU):
//  [0, 15872): msg bf16 [32][248]  (S0..E2)
//      overlay: h1 bf16 [32][136]  (written AFTER E2 barrier from regs; E2->E3)
//      overlay: aZ bf16 [32][248]  (E4 -> E5)
//  [15872, 20480): aM bf16 [32][72] (E3 -> E4, LN in place)
//  [20480, 22528): sSc  f32 [32][8]
//  [22528, 24576): sSc2 f32 [32][8]
//  [24576, 25088): sPart float2 [32][2]  (LN partial sums)
#define OFF_A    0
#define OFF_AM   15872
#define OFF_SC   20480
#define OFF_SC2  22528
#define OFF_PART 24576
#define SMEM_BYTES 25088

__global__ __launch_bounds__(256, 6) void edge_kernel(EdgeArgs A) {
  __shared__ __align__(16) char smem[SMEM_BYTES];
  short* aA = (short*)(smem + OFF_A);
  short* aZ = (short*)(smem + OFF_A);
  short* aH1 = (short*)(smem + OFF_A);   // overlays msg after E2
  short* aM = (short*)(smem + OFF_AM);
  float* sSc = (float*)(smem + OFF_SC);
  float* sSc2 = (float*)(smem + OFF_SC2);
  float2* sPart = (float2*)(smem + OFF_PART);

  const int tid = threadIdx.x;
  const int e0 = blockIdx.x * 32;
  const int lane = tid & 63;
  const int wv = tid >> 6;
  const int l15 = lane & 15, g = lane >> 4;
  const int l31 = lane & 31, hi = lane >> 5;
  const int mt = wv & 1, nh = wv >> 1;

  // ---- S0a (tid<32) || S0b || S0d: one phase, disjoint writes
  if (tid < 32) {
    const int e = e0 + tid;
    const int s = A.eidx[e];
    const int d = A.eidx[NE + e];
    const float dx = A.edge_attr[e * 3 + 0];
    const float dy = A.edge_attr[e * 3 + 1];
    const float r = A.edge_attr[e * 3 + 2];
    const float inv = 1.0f / (r + 1e-12f);
    const float n0 = dx * inv, n1 = dy * inv;  // t = (-n1, n0)
    const float* us = A.node_u + (size_t)s * 5;
    const float* ud = A.node_u + (size_t)d * 5;
    const float sm0 = A.std_mom[0], sm1 = A.std_mom[1];
    const float mm0 = A.mean_mom[0], mm1 = A.mean_mom[1];
    const float rs0 = fmaf(us[3], sm0, mm0), rs1 = fmaf(us[4], sm1, mm1);
    const float rd0 = fmaf(ud[3], sm0, mm0), rd1 = fmaf(ud[4], sm1, mm1);
    const float isc = 1.0f / (sqrtf(sm0 * sm0 + sm1 * sm1) + 1e-8f);
    unsigned* vp = (unsigned*)(aA + tid * SMS + 224);  // vel cols 224..228
    vp[0] = pack2((rs0 * n0 + rs1 * n1) * isc, (-rs0 * n1 + rs1 * n0) * isc);
    vp[1] = pack2((rd0 * n0 + rd1 * n1) * isc, (-rd0 * n1 + rd1 * n0) * isc);
    unsigned* zp = (unsigned*)(aA + tid * SMS + 228);  // zero pad 228..240
#pragma unroll
    for (int z = 0; z < 6; ++z) zp[z] = 0u;
    float* st = &sSc[tid * 8];
    st[0] = n0; st[1] = n1; st[2] = r;
    st[3] = ud[0] - us[0];
    st[4] = ud[1] - us[1];
    st[5] = ud[3] - us[3];
    st[6] = ud[4] - us[4];
  }
  {  // S0b: eps hidden (1 -> 32, gelu) -> msg cols [192..224)
    const int i = tid & 31, eg = tid >> 5;
    const float w1 = A.pe_W1[i], b1 = A.pe_b1[i];
#pragma unroll
    for (int p = 0; p < 4; ++p) {
      const int el = eg * 4 + p;
      const float rv = A.edge_attr[(e0 + el) * 3 + 2];
      aA[el * SMS + 192 + i] = f2bf(gelu_f(fmaf(rv, w1, b1)));
    }
  }
  {  // S0d: h gathers -> msg cols [0..192): hs | hd | (hs-hd)^2
    const int c = tid & 31, eg = tid >> 5;
#pragma unroll
    for (int p = 0; p < 4; ++p) {
      const int el = eg * 4 + p;
      const int s = A.eidx[e0 + el];
      const int d = A.eidx[NE + e0 + el];
      const unsigned us_raw = ((const unsigned*)(A.h + (size_t)s * 64))[c];
      const unsigned ud_raw = ((const unsigned*)(A.h + (size_t)d * 64))[c];
      unsigned* rp = (unsigned*)((char*)aA + el * (SMS * 2));
      rp[c] = us_raw;
      rp[32 + c] = ud_raw;
      const float s0 = bf2f_lo(us_raw), s1 = bf2f_hi(us_raw);
      const float d0 = bf2f_lo(ud_raw), d1 = bf2f_hi(ud_raw);
      const float q0 = s0 - d0, q1 = s1 - d1;
      rp[64 + c] = pack2(q0 * q0, q1 * q1);
    }
  }
  __syncthreads();

  // ---- E2: layer1 via 32x32x16 MFMA (M=32, K=240, N=128); results kept in regs
  unsigned h1pk[8];
  {
    const char* arow = (const char*)aA + l31 * (SMS * 2) + hi * 16;
    const short* BW = A.W1P + wv * 15 * 512 + lane * 8;
    f32x16 acc = {0.f, 0.f, 0.f, 0.f, 0.f, 0.f, 0.f, 0.f,
                  0.f, 0.f, 0.f, 0.f, 0.f, 0.f, 0.f, 0.f};
    for (int ks = 0; ks < 15; ++ks) {
      acc = MFMA32(*(const bf16x8*)(arow + ks * 32),
                   *(const bf16x8*)(BW + ks * 512), acc);
    }
    const float bb = A.B1F[wv * 32 + l31];
#pragma unroll
    for (int r8 = 0; r8 < 8; ++r8)
      h1pk[r8] = pack2(gelu_f(acc[2 * r8] + bb), gelu_f(acc[2 * r8 + 1] + bb));
  }
  __syncthreads();   // msg now dead; h1 overlays it

  {  // write h1 from regs into overlay region
    const int col = wv * 32 + l31;
#pragma unroll
    for (int r8 = 0; r8 < 8; ++r8) {
      const int reg = 2 * r8;
      const int row = (reg & 3) + 8 * (reg >> 2) + 4 * hi;
      aH1[row * H1S + col] = (short)h1pk[r8];
      aH1[(row + 1) * H1S + col] = (short)(h1pk[r8] >> 16);
    }
  }
  __syncthreads();

  // ---- E3: layer2 16x16 MFMA (K=128, N=64) + bias + edge_memory -> aM + LN partials
  {
    const char* arow = (const char*)aH1 + (mt * 16 + l15) * (H1S * 2) + g * 16;
    const short* BW = A.W2P + nh * 2 * 4 * 512 + lane * 8;
    f32x4 ac0 = {0.f, 0.f, 0.f, 0.f}, ac1 = ac0;
    for (int ks = 0; ks < 4; ++ks) {
      const bf16x8 a = *(const bf16x8*)(arow + ks * 64);
      ac0 = MFMA16(a, *(const bf16x8*)(BW + (0 * 4 + ks) * 512), ac0);
      ac1 = MFMA16(a, *(const bf16x8*)(BW + (1 * 4 + ks) * 512), ac1);
    }
    const int rb = mt * 16 + g * 4;
    const int c0 = (nh * 2 + 0) * 16 + l15, c1 = (nh * 2 + 1) * 16 + l15;
    const float bb0 = A.pm_b2[c0], bb1 = A.pm_b2[c1];
#pragma unroll
    for (int rg = 0; rg < 4; ++rg) {
      const int row = rb + rg;
      const float x0 = ac0[rg] + bb0 + A.edge_mem[(size_t)(e0 + row) * 64 + c0];
      const float x1 = ac1[rg] + bb1 + A.edge_mem[(size_t)(e0 + row) * 64 + c1];
      const unsigned pk = pack2(x0, x1);
      aM[row * MSR + c0] = (short)pk;
      aM[row * MSR + c1] = (short)(pk >> 16);
      float sx = x0 + x1;
      float sq = fmaf(x0, x0, x1 * x1);
#pragma unroll
      for (int m = 1; m < 16; m <<= 1) {
        sx += __shfl_xor(sx, m, 64);
        sq += __shfl_xor(sq, m, 64);
      }
      if (l15 == 0) sPart[row * 2 + nh] = make_float2(sx, sq);
    }
  }
  __syncthreads();

  // ---- LN normalize (elementwise, in-place on aM) + m f32 output
  {
    const float lg = A.ln_g[lane], lb = A.ln_b[lane];
    float* out_m = A.out + (size_t)10 * NE;
#pragma unroll
    for (int p = 0; p < 8; ++p) {
      const int r = p * 4 + wv;
      const float x = bf2f(aM[r * MSR + lane]);
      const float2 pa = sPart[r * 2 + 0], pb = sPart[r * 2 + 1];
      const float mean = (pa.x + pb.x) * (1.0f / 64.0f);
      const float var = fmaxf((pa.y + pb.y) * (1.0f / 64.0f) - mean * mean, 0.0f);
      const float rstd = rsqrtf(var + 1e-5f);
      const float y = fmaf((x - mean) * rstd, lg, lb);
      aM[r * MSR + lane] = f2bf(y);
      out_m[(size_t)(e0 + r) * 64 + lane] = y;
    }
  }
  __syncthreads();

  // ---- E4: head hidden via 32x32x16 MFMA (M=32, K=64, N=224) -> z (overlay msg)
  {
    const char* arow = (const char*)aM + l31 * (MSR * 2) + hi * 16;
    bf16x8 af0 = *(const bf16x8*)(arow);
    bf16x8 af1 = *(const bf16x8*)(arow + 32);
    bf16x8 af2 = *(const bf16x8*)(arow + 64);
    bf16x8 af3 = *(const bf16x8*)(arow + 96);
    for (int nt = wv; nt < 7; nt += 4) {
      const short* BW = A.WHP + nt * 4 * 512 + lane * 8;
      f32x16 acc = {0.f, 0.f, 0.f, 0.f, 0.f, 0.f, 0.f, 0.f,
                    0.f, 0.f, 0.f, 0.f, 0.f, 0.f, 0.f, 0.f};
      acc = MFMA32(af0, *(const bf16x8*)(BW + 0 * 512), acc);
      acc = MFMA32(af1, *(const bf16x8*)(BW + 1 * 512), acc);
      acc = MFMA32(af2, *(const bf16x8*)(BW + 2 * 512), acc);
      acc = MFMA32(af3, *(const bf16x8*)(BW + 3 * 512), acc);
      const int col = nt * 32 + l31;
      const float bb = A.HB[col];
#pragma unroll
      for (int reg = 0; reg < 16; ++reg) {
        const int row = (reg & 3) + 8 * (reg >> 2) + 4 * hi;
        aZ[row * ZST + col] = f2bf(gelu_f(acc[reg] + bb));
      }
    }
  }
  __syncthreads();

  // ---- E5: head outputs via MFMA (M=32, K=224, N=16; cols 0..4) + fused epilogue
  if (wv < 2) {
    f32x4 acc = {0.f, 0.f, 0.f, 0.f};
    for (int ks = 0; ks < 7; ++ks) {
      const bf16x8 a = *(const bf16x8*)((const char*)aZ + (wv * 16 + l15) * (ZST * 2) + ks * 64 + g * 16);
      const bf16x8 b = *(const bf16x8*)(A.WOP + ks * 512 + lane * 8);
      acc = MFMA16(a, b, acc);
    }
    if (l15 < 5) {
      const float bb = A.HB2[l15];
#pragma unroll
      for (int rg = 0; rg < 4; ++rg)
        sSc2[(wv * 16 + g * 4 + rg) * 8 + l15] = acc[rg] + bb;
    }
    asm volatile("s_waitcnt lgkmcnt(0)" ::: "memory");
    __builtin_amdgcn_sched_barrier(0);
    if (lane < 16) {  // same wave wrote all 16 of its edges' head values
      const int e = wv * 16 + lane;
      const float* st = &sSc[e * 8];
      const float n0 = st[0], n1 = st[1], r = st[2];
      const float du0 = st[3], du1 = st[4], du3 = st[5], du4 = st[6];
      const float arho = sSc2[e * 8 + 0], aen = sSc2[e * 8 + 1];
      const float amu0 = sSc2[e * 8 + 2], amu1 = sSc2[e * 8 + 3];
      const float av = sSc2[e * 8 + 4];
      const float alpha = __builtin_amdgcn_rcpf(1.0f + __builtin_amdgcn_exp2f(-1.4426950408f * av));
      const size_t ge = (size_t)(e0 + e);
      float* out = A.out;
      const float c0 = arho - alpha * du0;
      out[ge * 2 + 0] = c0 * n0;
      out[ge * 2 + 1] = c0 * n1;
      const float c1 = aen - alpha * du1;
      out[(size_t)2 * NE + ge * 2 + 0] = c1 * n0;
      out[(size_t)2 * NE + ge * 2 + 1] = c1 * n1;
      out[(size_t)4 * NE + ge * 2 + 0] = amu0 * n0 - amu1 * n1 - alpha * du3;
      out[(size_t)4 * NE + ge * 2 + 1] = amu0 * n1 + amu1 * n0 - alpha * du4;
      out[(size_t)6 * NE + ge * 2 + 0] = n0;
      out[(size_t)6 * NE + ge * 2 + 1] = n1;
      out[(size_t)8 * NE + ge] = r;
      out[(size_t)9 * NE + ge] = alpha;
    }
  }
}

extern "C" void kernel_launch(void* const* d_in, const int* in_sizes, int n_in,
                              void* d_out, int out_size, void* d_ws, size_t ws_size,
                              hipStream_t stream) {
  char* ws = (char*)d_ws;
  unsigned short* h = (unsigned short*)ws;         // 12,800,000 B
  short* W1P  = (short*)(ws + 12800000);           // 61,440 B
  short* W2P  = (short*)(ws + 12861440);           // 16,384 B
  short* WHP  = (short*)(ws + 12877824);           // 28,672 B
  float* HB   = (float*)(ws + 12906496);           // 896 B
  short* WOP  = (short*)(ws + 12907392);           // 7,168 B
  float* HB2  = (float*)(ws + 12914560);           // 64 B
  float* B1F  = (float*)(ws + 12914624);           // 512 B
  short* W1NP = (short*)(ws + 12915136);           // 2,048 B
  short* IPNP = (short*)(ws + 12917184);           // 2,048 B
  short* W2NP = (short*)(ws + 12919232);           // 8,192 B

  EdgeArgs A;
  A.node_u = (const float*)d_in[0];
  A.edge_attr = (const float*)d_in[1];
  A.mean_mom = (const float*)d_in[2];
  A.std_mom = (const float*)d_in[3];
  A.edge_mem = (const float*)d_in[4];
  A.eidx = (const int*)d_in[5];
  A.pe_W1 = (const float*)d_in[12];
  A.pe_b1 = (const float*)d_in[13];
  A.B1F = B1F;
  A.pm_b2 = (const float*)d_in[19];
  A.ln_g = (const float*)d_in[36];
  A.ln_b = (const float*)d_in[37];
  A.h = h;
  A.W1P = W1P;
  A.W2P = W2P;
  A.WHP = WHP;
  A.WOP = WOP;
  A.HB = HB;
  A.HB2 = HB2;
  A.out = (float*)d_out;

  prep_kernel<<<248, 256, 0, stream>>>(
      (const float*)d_in[16], (const float*)d_in[17], (const float*)d_in[18],
      (const float*)d_in[20], (const float*)d_in[24],
      (const float*)d_in[28], (const float*)d_in[32],
      (const float*)d_in[21], (const float*)d_in[25],
      (const float*)d_in[29], (const float*)d_in[33],
      (const float*)d_in[14], (const float*)d_in[15],
      (const float*)d_in[22], (const float*)d_in[26],
      (const float*)d_in[30], (const float*)d_in[34],
      (const float*)d_in[23], (const float*)d_in[27],
      (const float*)d_in[31], (const float*)d_in[35],
      (const float*)d_in[6], (const float*)d_in[8], (const float*)d_in[10],
      W1P, W2P, WHP, HB, WOP, HB2, B1F, W1NP, IPNP, W2NP);
  node_h_kernel<<<(NN + 63) / 64, 256, 0, stream>>>(
      (const float*)d_in[0], (const float*)d_in[7], (const float*)d_in[9],
      (const float*)d_in[11], W1NP, IPNP, W2NP, h);
  edge_kernel<<<NE / 32, 256, 0, stream>>>(A);
}

// Round 9
// 190.463 us; speedup vs baseline: 1.5060x; 1.0620x over previous
//
#include <hip/hip_runtime.h>
#include <math.h>

#define NN 100000
#define NE 500000

typedef short bf16x8 __attribute__((ext_vector_type(8)));
typedef float f32x4 __attribute__((ext_vector_type(4)));
typedef float f32x16 __attribute__((ext_vector_type(16)));

// fast tanh-approx gelu (exp2-based): |err| <= ~3e-3 vs exact erf-gelu.
__device__ __forceinline__ float gelu_f(float x) {
  const float t = x * x;
  const float p = fmaf(t, 0.10294325f, 2.3022084f);
  const float E = __builtin_amdgcn_exp2f(x * p);
  const float r = __builtin_amdgcn_rcpf(E + 1.0f);
  return fmaf(-x, r, x);
}
// HW packed f32->bf16 (RNE), gfx950: v_cvt_pk_bf16_f32
__device__ __forceinline__ unsigned cvtpk(float lo, float hi) {
  unsigned r;
  asm("v_cvt_pk_bf16_f32 %0, %1, %2" : "=v"(r) : "v"(lo), "v"(hi));
  return r;
}
__device__ __forceinline__ short f2bf(float x) { return (short)cvtpk(x, x); }
__device__ __forceinline__ unsigned pack2(float a, float b) { return cvtpk(a, b); }
__device__ __forceinline__ float bf2f(short s) {
  unsigned u = ((unsigned)(unsigned short)s) << 16;
  return __builtin_bit_cast(float, u);
}
__device__ __forceinline__ float bf2f_lo(unsigned w) {
  return __builtin_bit_cast(float, w << 16);
}
__device__ __forceinline__ float bf2f_hi(unsigned w) {
  return __builtin_bit_cast(float, w & 0xFFFF0000u);
}

#define MFMA16(a, b, c) __builtin_amdgcn_mfma_f32_16x16x32_bf16((a), (b), (c), 0, 0, 0)
#define MFMA32(a, b, c) __builtin_amdgcn_mfma_f32_32x32x16_bf16((a), (b), (c), 0, 0, 0)

// ---------------- Kernel 1: per-node h via MFMA (64 nodes/block) ----------------
__global__ __launch_bounds__(256) void node_h_kernel(
    const float* __restrict__ node_u,
    const float* __restrict__ b1, const float* __restrict__ b2,
    const float* __restrict__ ipb,
    const short* __restrict__ W1NP, const short* __restrict__ IPNP,
    const short* __restrict__ W2NP,
    unsigned short* __restrict__ h) {
  __shared__ float sU[64 * 5];
  __shared__ short sG[64 * 72];
  const int tid = threadIdx.x;
  const int lane = tid & 63;
  const int wv = tid >> 6;
  const int l31 = lane & 31, hi = lane >> 5;
  const int mt = wv & 1, nh = wv >> 1;
  const int n0 = blockIdx.x * 64;
  const int nrem = NN - n0;

  {  // stage u
    const int cnt = (nrem < 64 ? nrem : 64) * 5;
    for (int t = tid; t < cnt; t += 256) sU[t] = node_u[(size_t)n0 * 5 + t];
  }
  __syncthreads();

  const int row_node = mt * 32 + l31;
  const int col = nh * 32 + l31;
  bf16x8 au;
#pragma unroll
  for (int e = 0; e < 8; ++e)
    au[e] = (hi == 0 && e < 5) ? f2bf(sU[row_node * 5 + e]) : (short)0;
  f32x16 acc1, accip;
  const float b1v = b1[col];
  const float ipv = ipb[col] + b2[col];
#pragma unroll
  for (int reg = 0; reg < 16; ++reg) { acc1[reg] = b1v; accip[reg] = ipv; }
  acc1 = MFMA32(au, *(const bf16x8*)(W1NP + nh * 512 + lane * 8), acc1);
  accip = MFMA32(au, *(const bf16x8*)(IPNP + nh * 512 + lane * 8), accip);
#pragma unroll
  for (int reg = 0; reg < 16; ++reg) {
    const int r = mt * 32 + (reg & 3) + 8 * (reg >> 2) + 4 * hi;
    sG[r * 72 + col] = f2bf(gelu_f(acc1[reg]));
  }
  __syncthreads();

  {
    const char* arow = (const char*)sG + row_node * 144 + hi * 16;
    const short* BW = W2NP + nh * 4 * 512 + lane * 8;
    f32x16 acc = accip;
#pragma unroll
    for (int ks = 0; ks < 4; ++ks)
      acc = MFMA32(*(const bf16x8*)(arow + ks * 32),
                   *(const bf16x8*)(BW + ks * 512), acc);
#pragma unroll
    for (int reg = 0; reg < 16; ++reg) {
      const int r = mt * 32 + (reg & 3) + 8 * (reg >> 2) + 4 * hi;
      const int node = n0 + r;
      if (node < NN) h[(size_t)node * 64 + col] = (unsigned short)f2bf(acc[reg]);
    }
  }
}

// ---------------- Kernel 0: weight repack + algebraic folds ----------------
// 16x16 frag block = 512 bf16: k = ks*32 + 8*(l>>4) + e, n = nt*16 + (l&15).
// 32x32 frag block = 512 bf16: k = ks*16 + 8*(l>>5) + e, n = nt*32 + (l&31).
__global__ __launch_bounds__(256) void prep_kernel(
    const float* __restrict__ pm_W1, const float* __restrict__ pm_b1,
    const float* __restrict__ pm_W2,
    const float* __restrict__ prho_W1, const float* __restrict__ pen_W1,
    const float* __restrict__ pmu_W1, const float* __restrict__ pv_W1,
    const float* __restrict__ prho_b1, const float* __restrict__ pen_b1,
    const float* __restrict__ pmu_b1, const float* __restrict__ pv_b1,
    const float* __restrict__ pe_W2, const float* __restrict__ pe_b2,
    const float* __restrict__ prho_W2, const float* __restrict__ pen_W2,
    const float* __restrict__ pmu_W2, const float* __restrict__ pv_W2,
    const float* __restrict__ prho_b2, const float* __restrict__ pen_b2,
    const float* __restrict__ pmu_b2, const float* __restrict__ pv_b2,
    const float* __restrict__ pn_W1, const float* __restrict__ pn_W2,
    const float* __restrict__ ip_W,
    short* __restrict__ W1P, short* __restrict__ W2P, short* __restrict__ WHP,
    float* __restrict__ HB, short* __restrict__ WOP, float* __restrict__ HB2,
    float* __restrict__ B1F, short* __restrict__ W1NP, short* __restrict__ IPNP,
    short* __restrict__ W2NP) {
  int t = blockIdx.x * 256 + threadIdx.x;
  if (t < 30720) {  // folded W1': 240x128, 32x32 frag [nt=4][ks=15][512]
    const int nt = t / 7680, rem = t % 7680;
    const int ks = rem / 512, li = rem % 512;
    const int l = li >> 3, e = li & 7;
    const int k = ks * 16 + ((l >> 5) << 3) + e;
    const int n = nt * 32 + (l & 31);
    float v = 0.0f;
    if (k < 64) v = pm_W1[k * 128 + n] + pm_W1[(128 + k) * 128 + n];
    else if (k < 128) v = pm_W1[k * 128 + n] + pm_W1[(64 + k) * 128 + n];
    else if (k < 192) v = pm_W1[(64 + k) * 128 + n];
    else if (k < 224) {
      const int i = k - 192;
      for (int j = 0; j < 32; ++j) v += pe_W2[i * 32 + j] * pm_W1[(256 + j) * 128 + n];
    } else if (k < 228) v = pm_W1[(64 + k) * 128 + n];
    W1P[t] = f2bf(v);
    return;
  }
  t -= 30720;
  if (t < 8192) {  // pm_W2 16x16-frag: 128x64, [nt=4][ks=4][512]
    const int nt = t / 2048, rem = t % 2048;
    const int ks = rem / 512, li = rem % 512;
    const int l = li >> 3, e = li & 7;
    const int k = ks * 32 + ((l >> 4) << 3) + e;
    const int n = nt * 16 + (l & 15);
    W2P[t] = f2bf(pm_W2[k * 64 + n]);
    return;
  }
  t -= 8192;
  if (t < 14336) {  // heads W1 concat 32x32-frag: 64x224, [nt=7][ks=4][512]
    const int nt = t / 2048, rem = t % 2048;
    const int ks = rem / 512, li = rem % 512;
    const int l = li >> 3, e = li & 7;
    const int k = ks * 16 + ((l >> 5) << 3) + e;
    const int col = nt * 32 + (l & 31);
    float v;
    if (col < 64) v = prho_W1[k * 64 + col];
    else if (col < 128) v = pen_W1[k * 64 + (col - 64)];
    else if (col < 192) v = pmu_W1[k * 64 + (col - 128)];
    else v = pv_W1[k * 32 + (col - 192)];
    WHP[t] = f2bf(v);
    return;
  }
  t -= 14336;
  if (t < 224) {  // head hidden biases concat (f32)
    HB[t] = (t < 64) ? prho_b1[t]
          : (t < 128) ? pen_b1[t - 64]
          : (t < 192) ? pmu_b1[t - 128]
          : pv_b1[t - 192];
    return;
  }
  t -= 224;
  if (t < 3584) {  // stacked head W2 16x16-frag: 224x16, [ks=7][512]
    const int ks = t / 512, li = t % 512;
    const int l = li >> 3, e = li & 7;
    const int k = ks * 32 + ((l >> 4) << 3) + e;
    const int j = l & 15;
    float v = 0.0f;
    if (j == 0 && k < 64) v = prho_W2[k];
    else if (j == 1 && k >= 64 && k < 128) v = pen_W2[k - 64];
    else if (j == 2 && k >= 128 && k < 192) v = pmu_W2[(k - 128) * 2 + 0];
    else if (j == 3 && k >= 128 && k < 192) v = pmu_W2[(k - 128) * 2 + 1];
    else if (j == 4 && k >= 192 && k < 224) v = pv_W2[k - 192];
    WOP[t] = f2bf(v);
    return;
  }
  t -= 3584;
  if (t < 16) {  // head output biases
    HB2[t] = (t == 0) ? prho_b2[0]
           : (t == 1) ? pen_b2[0]
           : (t == 2) ? pmu_b2[0]
           : (t == 3) ? pmu_b2[1]
           : (t == 4) ? pv_b2[0] : 0.0f;
    return;
  }
  t -= 16;
  if (t < 128) {  // folded layer1 bias (f32)
    float v = pm_b1[t];
    for (int j = 0; j < 32; ++j) v += pe_b2[j] * pm_W1[(256 + j) * 128 + t];
    B1F[t] = v;
    return;
  }
  t -= 128;
  if (t < 1024) {  // pn_W1 32x32-frag (K=5 pad 16): [nt=2][512]
    const int nt = t / 512, li = t % 512;
    const int l = li >> 3, e = li & 7;
    const int k = ((l >> 5) << 3) + e;
    const int n = nt * 32 + (l & 31);
    W1NP[t] = (k < 5) ? f2bf(pn_W1[k * 64 + n]) : (short)0;
    return;
  }
  t -= 1024;
  if (t < 1024) {  // ip_W 32x32-frag (K=5 pad 16): [nt=2][512]
    const int nt = t / 512, li = t % 512;
    const int l = li >> 3, e = li & 7;
    const int k = ((l >> 5) << 3) + e;
    const int n = nt * 32 + (l & 31);
    IPNP[t] = (k < 5) ? f2bf(ip_W[k * 64 + n]) : (short)0;
    return;
  }
  t -= 1024;
  if (t < 4096) {  // pn_W2 32x32-frag: 64x64, [nt=2][ks=4][512]
    const int nt = t / 2048, rem = t % 2048;
    const int ks = rem / 512, li = rem % 512;
    const int l = li >> 3, e = li & 7;
    const int k = ks * 16 + ((l >> 5) << 3) + e;
    const int n = nt * 32 + (l & 31);
    W2NP[t] = f2bf(pn_W2[k * 64 + n]);
  }
}

// ---------------- Kernel 2: per-edge fused MFMA pipeline, 32 edges / block ----------------
struct EdgeArgs {
  const float *node_u, *edge_attr, *mean_mom, *std_mom, *edge_mem;
  const int* eidx;
  const float *pe_W1, *pe_b1;
  const float *B1F, *pm_b2;
  const float *ln_g, *ln_b;
  const unsigned short* h;   // bf16
  const short *W1P, *W2P, *WHP, *WOP;
  const float *HB, *HB2;
  float* out;
};

#define SMS 248   // msg bf16 row stride (496 B)
#define H1S 136   // h1 bf16 row stride (272 B)
#define MSR 72    // m bf16 row stride (144 B)
#define ZST 248   // z bf16 row stride (496 B)

// LDS map (25,088 B -> 6 blocks/CU):
//  [0, 15872): msg bf16 [32][248]  (S0..E2)
//      overlay: h1 bf16 [32][136]  (written AFTER E2 barrier from regs; E2->E3)
//      overlay: aZ bf16 [32][248]  (E4 -> E5)
//  [15872, 20480): aM bf16 [32][72] (E3 -> E4/E5-mstore, LN in place)
//  [20480, 22528): sSc  f32 [32][8]
//  [22528, 24576): sSc2 f32 [32][8]
//  [24576, 25088): sPart float2 [32][2]  (LN partial sums)
#define OFF_A    0
#define OFF_AM   15872
#define OFF_SC   20480
#define OFF_SC2  22528
#define OFF_PART 24576
#define SMEM_BYTES 25088

__global__ __launch_bounds__(256, 6) void edge_kernel(EdgeArgs A) {
  __shared__ __align__(16) char smem[SMEM_BYTES];
  short* aA = (short*)(smem + OFF_A);
  short* aZ = (short*)(smem + OFF_A);
  short* aH1 = (short*)(smem + OFF_A);   // overlays msg after E2
  short* aM = (short*)(smem + OFF_AM);
  float* sSc = (float*)(smem + OFF_SC);
  float* sSc2 = (float*)(smem + OFF_SC2);
  float2* sPart = (float2*)(smem + OFF_PART);

  const int tid = threadIdx.x;
  const int e0 = blockIdx.x * 32;
  const int lane = tid & 63;
  const int wv = tid >> 6;
  const int l15 = lane & 15, g = lane >> 4;
  const int l31 = lane & 31, hi = lane >> 5;
  const int mt = wv & 1, nh = wv >> 1;

  // ---- S0a (tid<32) || S0b || S0d: one phase, disjoint writes
  if (tid < 32) {
    const int e = e0 + tid;
    const int s = A.eidx[e];
    const int d = A.eidx[NE + e];
    const float dx = A.edge_attr[e * 3 + 0];
    const float dy = A.edge_attr[e * 3 + 1];
    const float r = A.edge_attr[e * 3 + 2];
    const float inv = 1.0f / (r + 1e-12f);
    const float n0 = dx * inv, n1 = dy * inv;  // t = (-n1, n0)
    const float* us = A.node_u + (size_t)s * 5;
    const float* ud = A.node_u + (size_t)d * 5;
    const float sm0 = A.std_mom[0], sm1 = A.std_mom[1];
    const float mm0 = A.mean_mom[0], mm1 = A.mean_mom[1];
    const float rs0 = fmaf(us[3], sm0, mm0), rs1 = fmaf(us[4], sm1, mm1);
    const float rd0 = fmaf(ud[3], sm0, mm0), rd1 = fmaf(ud[4], sm1, mm1);
    const float isc = 1.0f / (sqrtf(sm0 * sm0 + sm1 * sm1) + 1e-8f);
    unsigned* vp = (unsigned*)(aA + tid * SMS + 224);  // vel cols 224..228
    vp[0] = pack2((rs0 * n0 + rs1 * n1) * isc, (-rs0 * n1 + rs1 * n0) * isc);
    vp[1] = pack2((rd0 * n0 + rd1 * n1) * isc, (-rd0 * n1 + rd1 * n0) * isc);
    unsigned* zp = (unsigned*)(aA + tid * SMS + 228);  // zero pad 228..240
#pragma unroll
    for (int z = 0; z < 6; ++z) zp[z] = 0u;
    float* st = &sSc[tid * 8];
    st[0] = n0; st[1] = n1; st[2] = r;
    st[3] = ud[0] - us[0];
    st[4] = ud[1] - us[1];
    st[5] = ud[3] - us[3];
    st[6] = ud[4] - us[4];
  }
  {  // S0b: eps hidden (1 -> 32, gelu) -> msg cols [192..224)
    const int i = tid & 31, eg = tid >> 5;
    const float w1 = A.pe_W1[i], b1 = A.pe_b1[i];
#pragma unroll
    for (int p = 0; p < 4; ++p) {
      const int el = eg * 4 + p;
      const float rv = A.edge_attr[(e0 + el) * 3 + 2];
      aA[el * SMS + 192 + i] = f2bf(gelu_f(fmaf(rv, w1, b1)));
    }
  }
  {  // S0d: h gathers -> msg cols [0..192): hs | hd | (hs-hd)^2  (batched loads)
    const int c = tid & 31, eg = tid >> 5;
    int si[4], di[4];
#pragma unroll
    for (int p = 0; p < 4; ++p) {
      si[p] = A.eidx[e0 + eg * 4 + p];
      di[p] = A.eidx[NE + e0 + eg * 4 + p];
    }
    unsigned usr[4], udr[4];
#pragma unroll
    for (int p = 0; p < 4; ++p) {
      usr[p] = ((const unsigned*)(A.h + (size_t)si[p] * 64))[c];
      udr[p] = ((const unsigned*)(A.h + (size_t)di[p] * 64))[c];
    }
#pragma unroll
    for (int p = 0; p < 4; ++p) {
      const int el = eg * 4 + p;
      unsigned* rp = (unsigned*)((char*)aA + el * (SMS * 2));
      rp[c] = usr[p];
      rp[32 + c] = udr[p];
      const float s0 = bf2f_lo(usr[p]), s1 = bf2f_hi(usr[p]);
      const float d0 = bf2f_lo(udr[p]), d1 = bf2f_hi(udr[p]);
      const float q0 = s0 - d0, q1 = s1 - d1;
      rp[64 + c] = pack2(q0 * q0, q1 * q1);
    }
  }
  __syncthreads();

  // ---- E2: layer1 via 32x32x16 MFMA (M=32, K=240, N=128); results kept in regs
  unsigned h1pk[8];
  {
    const char* arow = (const char*)aA + l31 * (SMS * 2) + hi * 16;
    const short* BW = A.W1P + wv * 15 * 512 + lane * 8;
    f32x16 acc = {0.f, 0.f, 0.f, 0.f, 0.f, 0.f, 0.f, 0.f,
                  0.f, 0.f, 0.f, 0.f, 0.f, 0.f, 0.f, 0.f};
    for (int ks = 0; ks < 15; ++ks) {
      acc = MFMA32(*(const bf16x8*)(arow + ks * 32),
                   *(const bf16x8*)(BW + ks * 512), acc);
    }
    const float bb = A.B1F[wv * 32 + l31];
#pragma unroll
    for (int r8 = 0; r8 < 8; ++r8)
      h1pk[r8] = pack2(gelu_f(acc[2 * r8] + bb), gelu_f(acc[2 * r8 + 1] + bb));
  }
  __syncthreads();   // msg now dead; h1 overlays it

  {  // write h1 from regs into overlay region
    const int col = wv * 32 + l31;
#pragma unroll
    for (int r8 = 0; r8 < 8; ++r8) {
      const int reg = 2 * r8;
      const int row = (reg & 3) + 8 * (reg >> 2) + 4 * hi;
      aH1[row * H1S + col] = (short)h1pk[r8];
      aH1[(row + 1) * H1S + col] = (short)(h1pk[r8] >> 16);
    }
  }
  __syncthreads();

  // ---- E3: layer2 16x16 MFMA (K=128, N=64) + bias + edge_memory -> aM + LN partials
  {
    const int rb = mt * 16 + g * 4;
    const int c0 = (nh * 2 + 0) * 16 + l15, c1 = (nh * 2 + 1) * 16 + l15;
    float em0[4], em1[4];
#pragma unroll
    for (int rg = 0; rg < 4; ++rg) {   // issue global loads early
      em0[rg] = A.edge_mem[(size_t)(e0 + rb + rg) * 64 + c0];
      em1[rg] = A.edge_mem[(size_t)(e0 + rb + rg) * 64 + c1];
    }
    const char* arow = (const char*)aH1 + (mt * 16 + l15) * (H1S * 2) + g * 16;
    const short* BW = A.W2P + nh * 2 * 4 * 512 + lane * 8;
    f32x4 ac0 = {0.f, 0.f, 0.f, 0.f}, ac1 = ac0;
    for (int ks = 0; ks < 4; ++ks) {
      const bf16x8 a = *(const bf16x8*)(arow + ks * 64);
      ac0 = MFMA16(a, *(const bf16x8*)(BW + (0 * 4 + ks) * 512), ac0);
      ac1 = MFMA16(a, *(const bf16x8*)(BW + (1 * 4 + ks) * 512), ac1);
    }
    const float bb0 = A.pm_b2[c0], bb1 = A.pm_b2[c1];
#pragma unroll
    for (int rg = 0; rg < 4; ++rg) {
      const int row = rb + rg;
      const float x0 = ac0[rg] + bb0 + em0[rg];
      const float x1 = ac1[rg] + bb1 + em1[rg];
      const unsigned pk = pack2(x0, x1);
      aM[row * MSR + c0] = (short)pk;
      aM[row * MSR + c1] = (short)(pk >> 16);
      float sx = x0 + x1;
      float sq = fmaf(x0, x0, x1 * x1);
#pragma unroll
      for (int m = 1; m < 16; m <<= 1) {
        sx += __shfl_xor(sx, m, 64);
        sq += __shfl_xor(sq, m, 64);
      }
      if (l15 == 0) sPart[row * 2 + nh] = make_float2(sx, sq);
    }
  }
  __syncthreads();

  // ---- LN normalize (elementwise, in-place on aM; m global store deferred to E5 phase)
  {
    const float lg = A.ln_g[lane], lb = A.ln_b[lane];
#pragma unroll
    for (int p = 0; p < 8; ++p) {
      const int r = p * 4 + wv;
      const float x = bf2f(aM[r * MSR + lane]);
      const float2 pa = sPart[r * 2 + 0], pb = sPart[r * 2 + 1];
      const float mean = (pa.x + pb.x) * (1.0f / 64.0f);
      const float var = fmaxf((pa.y + pb.y) * (1.0f / 64.0f) - mean * mean, 0.0f);
      const float rstd = rsqrtf(var + 1e-5f);
      const float y = fmaf((x - mean) * rstd, lg, lb);
      aM[r * MSR + lane] = f2bf(y);
    }
  }
  __syncthreads();

  // ---- E4: head hidden via 32x32x16 MFMA (M=32, K=64, N=224) -> z (overlay msg)
  {
    const char* arow = (const char*)aM + l31 * (MSR * 2) + hi * 16;
    bf16x8 af0 = *(const bf16x8*)(arow);
    bf16x8 af1 = *(const bf16x8*)(arow + 32);
    bf16x8 af2 = *(const bf16x8*)(arow + 64);
    bf16x8 af3 = *(const bf16x8*)(arow + 96);
    for (int nt = wv; nt < 7; nt += 4) {
      const short* BW = A.WHP + nt * 4 * 512 + lane * 8;
      f32x16 acc = {0.f, 0.f, 0.f, 0.f, 0.f, 0.f, 0.f, 0.f,
                    0.f, 0.f, 0.f, 0.f, 0.f, 0.f, 0.f, 0.f};
      acc = MFMA32(af0, *(const bf16x8*)(BW + 0 * 512), acc);
      acc = MFMA32(af1, *(const bf16x8*)(BW + 1 * 512), acc);
      acc = MFMA32(af2, *(const bf16x8*)(BW + 2 * 512), acc);
      acc = MFMA32(af3, *(const bf16x8*)(BW + 3 * 512), acc);
      const int col = nt * 32 + l31;
      const float bb = A.HB[col];
#pragma unroll
      for (int reg = 0; reg < 16; ++reg) {
        const int row = (reg & 3) + 8 * (reg >> 2) + 4 * hi;
        aZ[row * ZST + col] = f2bf(gelu_f(acc[reg] + bb));
      }
    }
  }
  __syncthreads();

  // ---- E5 (waves 0,1): head outputs via MFMA + fused flux epilogue
  // ---- waves 2,3 (concurrent): store m output (bf16 aM -> f32 global)
  if (wv < 2) {
    f32x4 acc = {0.f, 0.f, 0.f, 0.f};
    for (int ks = 0; ks < 7; ++ks) {
      const bf16x8 a = *(const bf16x8*)((const char*)aZ + (wv * 16 + l15) * (ZST * 2) + ks * 64 + g * 16);
      const bf16x8 b = *(const bf16x8*)(A.WOP + ks * 512 + lane * 8);
      acc = MFMA16(a, b, acc);
    }
    if (l15 < 5) {
      const float bb = A.HB2[l15];
#pragma unroll
      for (int rg = 0; rg < 4; ++rg)
        sSc2[(wv * 16 + g * 4 + rg) * 8 + l15] = acc[rg] + bb;
    }
    asm volatile("s_waitcnt lgkmcnt(0)" ::: "memory");
    __builtin_amdgcn_sched_barrier(0);
    if (lane < 16) {  // same wave wrote all 16 of its edges' head values
      const int e = wv * 16 + lane;
      const float* st = &sSc[e * 8];
      const float n0 = st[0], n1 = st[1], r = st[2];
      const float du0 = st[3], du1 = st[4], du3 = st[5], du4 = st[6];
      const float arho = sSc2[e * 8 + 0], aen = sSc2[e * 8 + 1];
      const float amu0 = sSc2[e * 8 + 2], amu1 = sSc2[e * 8 + 3];
      const float av = sSc2[e * 8 + 4];
      const float alpha = __builtin_amdgcn_rcpf(1.0f + __builtin_amdgcn_exp2f(-1.4426950408f * av));
      const size_t ge = (size_t)(e0 + e);
      float* out = A.out;
      const float c0 = arho - alpha * du0;
      out[ge * 2 + 0] = c0 * n0;
      out[ge * 2 + 1] = c0 * n1;
      const float c1 = aen - alpha * du1;
      out[(size_t)2 * NE + ge * 2 + 0] = c1 * n0;
      out[(size_t)2 * NE + ge * 2 + 1] = c1 * n1;
      out[(size_t)4 * NE + ge * 2 + 0] = amu0 * n0 - amu1 * n1 - alpha * du3;
      out[(size_t)4 * NE + ge * 2 + 1] = amu0 * n1 + amu1 * n0 - alpha * du4;
      out[(size_t)6 * NE + ge * 2 + 0] = n0;
      out[(size_t)6 * NE + ge * 2 + 1] = n1;
      out[(size_t)8 * NE + ge] = r;
      out[(size_t)9 * NE + ge] = alpha;
    }
  } else {
    float* out_m = A.out + (size_t)10 * NE;
    const int rbase = (wv - 2) * 16;
#pragma unroll
    for (int rr = 0; rr < 16; ++rr) {
      const int row = rbase + rr;
      out_m[(size_t)(e0 + row) * 64 + lane] = bf2f(aM[row * MSR + lane]);
    }
  }
}

extern "C" void kernel_launch(void* const* d_in, const int* in_sizes, int n_in,
                              void* d_out, int out_size, void* d_ws, size_t ws_size,
                              hipStream_t stream) {
  char* ws = (char*)d_ws;
  unsigned short* h = (unsigned short*)ws;         // 12,800,000 B
  short* W1P  = (short*)(ws + 12800000);           // 61,440 B
  short* W2P  = (short*)(ws + 12861440);           // 16,384 B
  short* WHP  = (short*)(ws + 12877824);           // 28,672 B
  float* HB   = (float*)(ws + 12906496);           // 896 B
  short* WOP  = (short*)(ws + 12907392);           // 7,168 B
  float* HB2  = (float*)(ws + 12914560);           // 64 B
  float* B1F  = (float*)(ws + 12914624);           // 512 B
  short* W1NP = (short*)(ws + 12915136);           // 2,048 B
  short* IPNP = (short*)(ws + 12917184);           // 2,048 B
  short* W2NP = (short*)(ws + 12919232);           // 8,192 B

  EdgeArgs A;
  A.node_u = (const float*)d_in[0];
  A.edge_attr = (const float*)d_in[1];
  A.mean_mom = (const float*)d_in[2];
  A.std_mom = (const float*)d_in[3];
  A.edge_mem = (const float*)d_in[4];
  A.eidx = (const int*)d_in[5];
  A.pe_W1 = (const float*)d_in[12];
  A.pe_b1 = (const float*)d_in[13];
  A.B1F = B1F;
  A.pm_b2 = (const float*)d_in[19];
  A.ln_g = (const float*)d_in[36];
  A.ln_b = (const float*)d_in[37];
  A.h = h;
  A.W1P = W1P;
  A.W2P = W2P;
  A.WHP = WHP;
  A.WOP = WOP;
  A.HB = HB;
  A.HB2 = HB2;
  A.out = (float*)d_out;

  prep_kernel<<<248, 256, 0, stream>>>(
      (const float*)d_in[16], (const float*)d_in[17], (const float*)d_in[18],
      (const float*)d_in[20], (const float*)d_in[24],
      (const float*)d_in[28], (const float*)d_in[32],
      (const float*)d_in[21], (const float*)d_in[25],
      (const float*)d_in[29], (const float*)d_in[33],
      (const float*)d_in[14], (const float*)d_in[15],
      (const float*)d_in[22], (const float*)d_in[26],
      (const float*)d_in[30], (const float*)d_in[34],
      (const float*)d_in[23], (const float*)d_in[27],
      (const float*)d_in[31], (const float*)d_in[35],
      (const float*)d_in[6], (const float*)d_in[8], (const float*)d_in[10],
      W1P, W2P, WHP, HB, WOP, HB2, B1F, W1NP, IPNP, W2NP);
  node_h_kernel<<<(NN + 63) / 64, 256, 0, stream>>>(
      (const float*)d_in[0], (const float*)d_in[7], (const float*)d_in[9],
      (const float*)d_in[11], W1NP, IPNP, W2NP, h);
  edge_kernel<<<NE / 32, 256, 0, stream>>>(A);
}

// Round 11
// 184.953 us; speedup vs baseline: 1.5509x; 1.0298x over previous
//
#include <hip/hip_runtime.h>
#include <math.h>

#define NN 100000
#define NE 500000

typedef short bf16x8 __attribute__((ext_vector_type(8)));
typedef float f32x4 __attribute__((ext_vector_type(4)));
typedef float f32x16 __attribute__((ext_vector_type(16)));

// fast tanh-approx gelu (exp2-based): |err| <= ~3e-3 vs exact erf-gelu.
__device__ __forceinline__ float gelu_f(float x) {
  const float t = x * x;
  const float p = fmaf(t, 0.10294325f, 2.3022084f);
  const float E = __builtin_amdgcn_exp2f(x * p);
  const float r = __builtin_amdgcn_rcpf(E + 1.0f);
  return fmaf(-x, r, x);
}
// HW packed f32->bf16 (RNE), gfx950: v_cvt_pk_bf16_f32
__device__ __forceinline__ unsigned cvtpk(float lo, float hi) {
  unsigned r;
  asm("v_cvt_pk_bf16_f32 %0, %1, %2" : "=v"(r) : "v"(lo), "v"(hi));
  return r;
}
__device__ __forceinline__ short f2bf(float x) { return (short)cvtpk(x, x); }
__device__ __forceinline__ unsigned pack2(float a, float b) { return cvtpk(a, b); }
__device__ __forceinline__ float bf2f(short s) {
  unsigned u = ((unsigned)(unsigned short)s) << 16;
  return __builtin_bit_cast(float, u);
}
__device__ __forceinline__ float bf2f_lo(unsigned w) {
  return __builtin_bit_cast(float, w << 16);
}
__device__ __forceinline__ float bf2f_hi(unsigned w) {
  return __builtin_bit_cast(float, w & 0xFFFF0000u);
}

#define MFMA16(a, b, c) __builtin_amdgcn_mfma_f32_16x16x32_bf16((a), (b), (c), 0, 0, 0)
#define MFMA32(a, b, c) __builtin_amdgcn_mfma_f32_32x32x16_bf16((a), (b), (c), 0, 0, 0)

// ---------------- Kernel 1: per-node h via MFMA (64 nodes/block) ----------------
__global__ __launch_bounds__(256) void node_h_kernel(
    const float* __restrict__ node_u,
    const float* __restrict__ b1, const float* __restrict__ b2,
    const float* __restrict__ ipb,
    const short* __restrict__ W1NP, const short* __restrict__ IPNP,
    const short* __restrict__ W2NP,
    unsigned short* __restrict__ h) {
  __shared__ float sU[64 * 5];
  __shared__ short sG[64 * 72];
  const int tid = threadIdx.x;
  const int lane = tid & 63;
  const int wv = tid >> 6;
  const int l31 = lane & 31, hi = lane >> 5;
  const int mt = wv & 1, nh = wv >> 1;
  const int n0 = blockIdx.x * 64;
  const int nrem = NN - n0;

  {  // stage u
    const int cnt = (nrem < 64 ? nrem : 64) * 5;
    for (int t = tid; t < cnt; t += 256) sU[t] = node_u[(size_t)n0 * 5 + t];
  }
  __syncthreads();

  const int row_node = mt * 32 + l31;
  const int col = nh * 32 + l31;
  bf16x8 au;
#pragma unroll
  for (int e = 0; e < 8; ++e)
    au[e] = (hi == 0 && e < 5) ? f2bf(sU[row_node * 5 + e]) : (short)0;
  f32x16 acc1, accip;
  const float b1v = b1[col];
  const float ipv = ipb[col] + b2[col];
#pragma unroll
  for (int reg = 0; reg < 16; ++reg) { acc1[reg] = b1v; accip[reg] = ipv; }
  acc1 = MFMA32(au, *(const bf16x8*)(W1NP + nh * 512 + lane * 8), acc1);
  accip = MFMA32(au, *(const bf16x8*)(IPNP + nh * 512 + lane * 8), accip);
#pragma unroll
  for (int reg = 0; reg < 16; ++reg) {
    const int r = mt * 32 + (reg & 3) + 8 * (reg >> 2) + 4 * hi;
    sG[r * 72 + col] = f2bf(gelu_f(acc1[reg]));
  }
  __syncthreads();

  {
    const char* arow = (const char*)sG + row_node * 144 + hi * 16;
    const short* BW = W2NP + nh * 4 * 512 + lane * 8;
    f32x16 acc = accip;
#pragma unroll
    for (int ks = 0; ks < 4; ++ks)
      acc = MFMA32(*(const bf16x8*)(arow + ks * 32),
                   *(const bf16x8*)(BW + ks * 512), acc);
#pragma unroll
    for (int reg = 0; reg < 16; ++reg) {
      const int r = mt * 32 + (reg & 3) + 8 * (reg >> 2) + 4 * hi;
      const int node = n0 + r;
      if (node < NN) h[(size_t)node * 64 + col] = (unsigned short)f2bf(acc[reg]);
    }
  }
}

// ---------------- Kernel 0: weight repack + algebraic folds ----------------
// 16x16 frag block = 512 bf16: k = ks*32 + 8*(l>>4) + e, n = nt*16 + (l&15).
// 32x32 frag block = 512 bf16: k = ks*16 + 8*(l>>5) + e, n = nt*32 + (l&31).
__global__ __launch_bounds__(256) void prep_kernel(
    const float* __restrict__ pm_W1, const float* __restrict__ pm_b1,
    const float* __restrict__ pm_W2,
    const float* __restrict__ prho_W1, const float* __restrict__ pen_W1,
    const float* __restrict__ pmu_W1, const float* __restrict__ pv_W1,
    const float* __restrict__ prho_b1, const float* __restrict__ pen_b1,
    const float* __restrict__ pmu_b1, const float* __restrict__ pv_b1,
    const float* __restrict__ pe_W2, const float* __restrict__ pe_b2,
    const float* __restrict__ prho_W2, const float* __restrict__ pen_W2,
    const float* __restrict__ pmu_W2, const float* __restrict__ pv_W2,
    const float* __restrict__ prho_b2, const float* __restrict__ pen_b2,
    const float* __restrict__ pmu_b2, const float* __restrict__ pv_b2,
    const float* __restrict__ pn_W1, const float* __restrict__ pn_W2,
    const float* __restrict__ ip_W,
    short* __restrict__ W1P, short* __restrict__ W2P, short* __restrict__ WHP,
    float* __restrict__ HB, short* __restrict__ WOP, float* __restrict__ HB2,
    float* __restrict__ B1F, short* __restrict__ W1NP, short* __restrict__ IPNP,
    short* __restrict__ W2NP) {
  int t = blockIdx.x * 256 + threadIdx.x;
  if (t < 30720) {  // folded W1': 240x128, 32x32 frag [nt=4][ks=15][512]
    const int nt = t / 7680, rem = t % 7680;
    const int ks = rem / 512, li = rem % 512;
    const int l = li >> 3, e = li & 7;
    const int k = ks * 16 + ((l >> 5) << 3) + e;
    const int n = nt * 32 + (l & 31);
    float v = 0.0f;
    if (k < 64) v = pm_W1[k * 128 + n] + pm_W1[(128 + k) * 128 + n];
    else if (k < 128) v = pm_W1[k * 128 + n] + pm_W1[(64 + k) * 128 + n];
    else if (k < 192) v = pm_W1[(64 + k) * 128 + n];
    else if (k < 224) {
      const int i = k - 192;
      for (int j = 0; j < 32; ++j) v += pe_W2[i * 32 + j] * pm_W1[(256 + j) * 128 + n];
    } else if (k < 228) v = pm_W1[(64 + k) * 128 + n];
    W1P[t] = f2bf(v);
    return;
  }
  t -= 30720;
  if (t < 8192) {  // pm_W2 16x16-frag: 128x64, [nt=4][ks=4][512]
    const int nt = t / 2048, rem = t % 2048;
    const int ks = rem / 512, li = rem % 512;
    const int l = li >> 3, e = li & 7;
    const int k = ks * 32 + ((l >> 4) << 3) + e;
    const int n = nt * 16 + (l & 15);
    W2P[t] = f2bf(pm_W2[k * 64 + n]);
    return;
  }
  t -= 8192;
  if (t < 14336) {  // heads W1 concat 32x32-frag: 64x224, [nt=7][ks=4][512]
    const int nt = t / 2048, rem = t % 2048;
    const int ks = rem / 512, li = rem % 512;
    const int l = li >> 3, e = li & 7;
    const int k = ks * 16 + ((l >> 5) << 3) + e;
    const int col = nt * 32 + (l & 31);
    float v;
    if (col < 64) v = prho_W1[k * 64 + col];
    else if (col < 128) v = pen_W1[k * 64 + (col - 64)];
    else if (col < 192) v = pmu_W1[k * 64 + (col - 128)];
    else v = pv_W1[k * 32 + (col - 192)];
    WHP[t] = f2bf(v);
    return;
  }
  t -= 14336;
  if (t < 224) {  // head hidden biases concat (f32)
    HB[t] = (t < 64) ? prho_b1[t]
          : (t < 128) ? pen_b1[t - 64]
          : (t < 192) ? pmu_b1[t - 128]
          : pv_b1[t - 192];
    return;
  }
  t -= 224;
  if (t < 3584) {  // stacked head W2 16x16-frag: 224x16, [ks=7][512]
    const int ks = t / 512, li = t % 512;
    const int l = li >> 3, e = li & 7;
    const int k = ks * 32 + ((l >> 4) << 3) + e;
    const int j = l & 15;
    float v = 0.0f;
    if (j == 0 && k < 64) v = prho_W2[k];
    else if (j == 1 && k >= 64 && k < 128) v = pen_W2[k - 64];
    else if (j == 2 && k >= 128 && k < 192) v = pmu_W2[(k - 128) * 2 + 0];
    else if (j == 3 && k >= 128 && k < 192) v = pmu_W2[(k - 128) * 2 + 1];
    else if (j == 4 && k >= 192 && k < 224) v = pv_W2[k - 192];
    WOP[t] = f2bf(v);
    return;
  }
  t -= 3584;
  if (t < 16) {  // head output biases
    HB2[t] = (t == 0) ? prho_b2[0]
           : (t == 1) ? pen_b2[0]
           : (t == 2) ? pmu_b2[0]
           : (t == 3) ? pmu_b2[1]
           : (t == 4) ? pv_b2[0] : 0.0f;
    return;
  }
  t -= 16;
  if (t < 128) {  // folded layer1 bias (f32)
    float v = pm_b1[t];
    for (int j = 0; j < 32; ++j) v += pe_b2[j] * pm_W1[(256 + j) * 128 + t];
    B1F[t] = v;
    return;
  }
  t -= 128;
  if (t < 1024) {  // pn_W1 32x32-frag (K=5 pad 16): [nt=2][512]
    const int nt = t / 512, li = t % 512;
    const int l = li >> 3, e = li & 7;
    const int k = ((l >> 5) << 3) + e;
    const int n = nt * 32 + (l & 31);
    W1NP[t] = (k < 5) ? f2bf(pn_W1[k * 64 + n]) : (short)0;
    return;
  }
  t -= 1024;
  if (t < 1024) {  // ip_W 32x32-frag (K=5 pad 16): [nt=2][512]
    const int nt = t / 512, li = t % 512;
    const int l = li >> 3, e = li & 7;
    const int k = ((l >> 5) << 3) + e;
    const int n = nt * 32 + (l & 31);
    IPNP[t] = (k < 5) ? f2bf(ip_W[k * 64 + n]) : (short)0;
    return;
  }
  t -= 1024;
  if (t < 4096) {  // pn_W2 32x32-frag: 64x64, [nt=2][ks=4][512]
    const int nt = t / 2048, rem = t % 2048;
    const int ks = rem / 512, li = rem % 512;
    const int l = li >> 3, e = li & 7;
    const int k = ks * 16 + ((l >> 5) << 3) + e;
    const int n = nt * 32 + (l & 31);
    W2NP[t] = f2bf(pn_W2[k * 64 + n]);
  }
}

// ---------------- Kernel 2: per-edge fused MFMA pipeline, 32 edges / block ----------------
struct EdgeArgs {
  const float *node_u, *edge_attr, *mean_mom, *std_mom, *edge_mem;
  const int* eidx;
  const float *pe_W1, *pe_b1;
  const float *B1F, *pm_b2;
  const float *ln_g, *ln_b;
  const unsigned short* h;   // bf16
  const short *W1P, *W2P, *WHP, *WOP;
  const float *HB, *HB2;
  float* out;
};

#define SMS 248   // msg bf16 row stride (496 B)
#define H1S 136   // h1 bf16 row stride (272 B)
#define MSR 72    // m bf16 row stride (144 B)
#define ZST 248   // z bf16 row stride (496 B)

// LDS map (23,040 B -> 7 blocks/CU: 7*23040 = 161,280 <= 163,840):
//  [0, 15872): msg bf16 [32][248]  (S0..E2)
//      overlay: h1 bf16 [32][136]  (written AFTER E2 barrier from regs; E2->E3)
//      overlay: aZ bf16 [32][248]  (E4 -> E5)
//  [15872, 20480): aM bf16 [32][72] (E3 -> E4/E5-mstore, LN in place)
//  [20480, 21504): sSc  f32 [32][8]
//  [21504, 22528): sSc2 f32 [32][8]
//  [22528, 23040): sPart float2 [32][2]  (LN partial sums)
#define OFF_A    0
#define OFF_AM   15872
#define OFF_SC   20480
#define OFF_SC2  21504
#define OFF_PART 22528
#define SMEM_BYTES 23040

__global__ __launch_bounds__(256, 7) void edge_kernel(EdgeArgs A) {
  __shared__ __align__(16) char smem[SMEM_BYTES];
  short* aA = (short*)(smem + OFF_A);
  short* aZ = (short*)(smem + OFF_A);
  short* aH1 = (short*)(smem + OFF_A);   // overlays msg after E2
  short* aM = (short*)(smem + OFF_AM);
  float* sSc = (float*)(smem + OFF_SC);
  float* sSc2 = (float*)(smem + OFF_SC2);
  float2* sPart = (float2*)(smem + OFF_PART);

  const int tid = threadIdx.x;
  const int e0 = blockIdx.x * 32;
  const int lane = tid & 63;
  const int wv = tid >> 6;
  const int l15 = lane & 15, g = lane >> 4;
  const int l31 = lane & 31, hi = lane >> 5;
  const int mt = wv & 1, nh = wv >> 1;

  // ---- S0a (tid<32) || S0b || S0d: one phase, disjoint writes
  if (tid < 32) {
    const int e = e0 + tid;
    const int s = A.eidx[e];
    const int d = A.eidx[NE + e];
    const float dx = A.edge_attr[e * 3 + 0];
    const float dy = A.edge_attr[e * 3 + 1];
    const float r = A.edge_attr[e * 3 + 2];
    const float inv = 1.0f / (r + 1e-12f);
    const float n0 = dx * inv, n1 = dy * inv;  // t = (-n1, n0)
    const float* us = A.node_u + (size_t)s * 5;
    const float* ud = A.node_u + (size_t)d * 5;
    const float sm0 = A.std_mom[0], sm1 = A.std_mom[1];
    const float mm0 = A.mean_mom[0], mm1 = A.mean_mom[1];
    const float rs0 = fmaf(us[3], sm0, mm0), rs1 = fmaf(us[4], sm1, mm1);
    const float rd0 = fmaf(ud[3], sm0, mm0), rd1 = fmaf(ud[4], sm1, mm1);
    const float isc = 1.0f / (sqrtf(sm0 * sm0 + sm1 * sm1) + 1e-8f);
    unsigned* vp = (unsigned*)(aA + tid * SMS + 224);  // vel cols 224..228
    vp[0] = pack2((rs0 * n0 + rs1 * n1) * isc, (-rs0 * n1 + rs1 * n0) * isc);
    vp[1] = pack2((rd0 * n0 + rd1 * n1) * isc, (-rd0 * n1 + rd1 * n0) * isc);
    unsigned* zp = (unsigned*)(aA + tid * SMS + 228);  // zero pad 228..240
#pragma unroll
    for (int z = 0; z < 6; ++z) zp[z] = 0u;
    float* st = &sSc[tid * 8];
    st[0] = n0; st[1] = n1; st[2] = r;
    st[3] = ud[0] - us[0];
    st[4] = ud[1] - us[1];
    st[5] = ud[3] - us[3];
    st[6] = ud[4] - us[4];
  }
  {  // S0b: eps hidden (1 -> 32, gelu) -> msg cols [192..224)
    const int i = tid & 31, eg = tid >> 5;
    const float w1 = A.pe_W1[i], b1 = A.pe_b1[i];
#pragma unroll
    for (int p = 0; p < 4; ++p) {
      const int el = eg * 4 + p;
      const float rv = A.edge_attr[(e0 + el) * 3 + 2];
      aA[el * SMS + 192 + i] = f2bf(gelu_f(fmaf(rv, w1, b1)));
    }
  }
  {  // S0d: h gathers -> msg cols [0..192): hs | hd | (hs-hd)^2  (batched loads)
    const int c = tid & 31, eg = tid >> 5;
    int si[4], di[4];
#pragma unroll
    for (int p = 0; p < 4; ++p) {
      si[p] = A.eidx[e0 + eg * 4 + p];
      di[p] = A.eidx[NE + e0 + eg * 4 + p];
    }
    unsigned usr[4], udr[4];
#pragma unroll
    for (int p = 0; p < 4; ++p) {
      usr[p] = ((const unsigned*)(A.h + (size_t)si[p] * 64))[c];
      udr[p] = ((const unsigned*)(A.h + (size_t)di[p] * 64))[c];
    }
#pragma unroll
    for (int p = 0; p < 4; ++p) {
      const int el = eg * 4 + p;
      unsigned* rp = (unsigned*)((char*)aA + el * (SMS * 2));
      rp[c] = usr[p];
      rp[32 + c] = udr[p];
      const float s0 = bf2f_lo(usr[p]), s1 = bf2f_hi(usr[p]);
      const float d0 = bf2f_lo(udr[p]), d1 = bf2f_hi(udr[p]);
      const float q0 = s0 - d0, q1 = s1 - d1;
      rp[64 + c] = pack2(q0 * q0, q1 * q1);
    }
  }
  __syncthreads();

  // ---- E2: layer1 via 32x32x16 MFMA (M=32, K=240, N=128); results kept in regs
  unsigned h1pk[8];
  {
    const char* arow = (const char*)aA + l31 * (SMS * 2) + hi * 16;
    const short* BW = A.W1P + wv * 15 * 512 + lane * 8;
    f32x16 acc = {0.f, 0.f, 0.f, 0.f, 0.f, 0.f, 0.f, 0.f,
                  0.f, 0.f, 0.f, 0.f, 0.f, 0.f, 0.f, 0.f};
    for (int ks = 0; ks < 15; ++ks) {
      acc = MFMA32(*(const bf16x8*)(arow + ks * 32),
                   *(const bf16x8*)(BW + ks * 512), acc);
    }
    const float bb = A.B1F[wv * 32 + l31];
#pragma unroll
    for (int r8 = 0; r8 < 8; ++r8)
      h1pk[r8] = pack2(gelu_f(acc[2 * r8] + bb), gelu_f(acc[2 * r8 + 1] + bb));
  }
  __syncthreads();   // msg now dead; h1 overlays it

  {  // write h1 from regs into overlay region
    const int col = wv * 32 + l31;
#pragma unroll
    for (int r8 = 0; r8 < 8; ++r8) {
      const int reg = 2 * r8;
      const int row = (reg & 3) + 8 * (reg >> 2) + 4 * hi;
      aH1[row * H1S + col] = (short)h1pk[r8];
      aH1[(row + 1) * H1S + col] = (short)(h1pk[r8] >> 16);
    }
  }
  __syncthreads();

  // ---- E3: layer2 16x16 MFMA (K=128, N=64) + bias + edge_memory -> aM + LN partials
  {
    const int rb = mt * 16 + g * 4;
    const int c0 = (nh * 2 + 0) * 16 + l15, c1 = (nh * 2 + 1) * 16 + l15;
    float em0[4], em1[4];
#pragma unroll
    for (int rg = 0; rg < 4; ++rg) {   // issue global loads early
      em0[rg] = A.edge_mem[(size_t)(e0 + rb + rg) * 64 + c0];
      em1[rg] = A.edge_mem[(size_t)(e0 + rb + rg) * 64 + c1];
    }
    const char* arow = (const char*)aH1 + (mt * 16 + l15) * (H1S * 2) + g * 16;
    const short* BW = A.W2P + nh * 2 * 4 * 512 + lane * 8;
    f32x4 ac0 = {0.f, 0.f, 0.f, 0.f}, ac1 = ac0;
    for (int ks = 0; ks < 4; ++ks) {
      const bf16x8 a = *(const bf16x8*)(arow + ks * 64);
      ac0 = MFMA16(a, *(const bf16x8*)(BW + (0 * 4 + ks) * 512), ac0);
      ac1 = MFMA16(a, *(const bf16x8*)(BW + (1 * 4 + ks) * 512), ac1);
    }
    const float bb0 = A.pm_b2[c0], bb1 = A.pm_b2[c1];
#pragma unroll
    for (int rg = 0; rg < 4; ++rg) {
      const int row = rb + rg;
      const float x0 = ac0[rg] + bb0 + em0[rg];
      const float x1 = ac1[rg] + bb1 + em1[rg];
      const unsigned pk = pack2(x0, x1);
      aM[row * MSR + c0] = (short)pk;
      aM[row * MSR + c1] = (short)(pk >> 16);
      float sx = x0 + x1;
      float sq = fmaf(x0, x0, x1 * x1);
#pragma unroll
      for (int m = 1; m < 16; m <<= 1) {
        sx += __shfl_xor(sx, m, 64);
        sq += __shfl_xor(sq, m, 64);
      }
      if (l15 == 0) sPart[row * 2 + nh] = make_float2(sx, sq);
    }
  }
  __syncthreads();

  // ---- LN normalize (elementwise, in-place on aM; m global store deferred to E5 phase)
  {
    const float lg = A.ln_g[lane], lb = A.ln_b[lane];
#pragma unroll
    for (int p = 0; p < 8; ++p) {
      const int r = p * 4 + wv;
      const float x = bf2f(aM[r * MSR + lane]);
      const float2 pa = sPart[r * 2 + 0], pb = sPart[r * 2 + 1];
      const float mean = (pa.x + pb.x) * (1.0f / 64.0f);
      const float var = fmaxf((pa.y + pb.y) * (1.0f / 64.0f) - mean * mean, 0.0f);
      const float rstd = rsqrtf(var + 1e-5f);
      const float y = fmaf((x - mean) * rstd, lg, lb);
      aM[r * MSR + lane] = f2bf(y);
    }
  }
  __syncthreads();

  // ---- E4: head hidden via 32x32x16 MFMA (M=32, K=64, N=224) -> z (overlay msg)
  {
    const char* arow = (const char*)aM + l31 * (MSR * 2) + hi * 16;
    bf16x8 af0 = *(const bf16x8*)(arow);
    bf16x8 af1 = *(const bf16x8*)(arow + 32);
    bf16x8 af2 = *(const bf16x8*)(arow + 64);
    bf16x8 af3 = *(const bf16x8*)(arow + 96);
    for (int nt = wv; nt < 7; nt += 4) {
      const short* BW = A.WHP + nt * 4 * 512 + lane * 8;
      f32x16 acc = {0.f, 0.f, 0.f, 0.f, 0.f, 0.f, 0.f, 0.f,
                    0.f, 0.f, 0.f, 0.f, 0.f, 0.f, 0.f, 0.f};
      acc = MFMA32(af0, *(const bf16x8*)(BW + 0 * 512), acc);
      acc = MFMA32(af1, *(const bf16x8*)(BW + 1 * 512), acc);
      acc = MFMA32(af2, *(const bf16x8*)(BW + 2 * 512), acc);
      acc = MFMA32(af3, *(const bf16x8*)(BW + 3 * 512), acc);
      const int col = nt * 32 + l31;
      const float bb = A.HB[col];
#pragma unroll
      for (int i = 0; i < 8; ++i) {
        const int reg = 2 * i;
        const int row = (reg & 3) + 8 * (reg >> 2) + 4 * hi;
        const unsigned pk = pack2(gelu_f(acc[reg] + bb), gelu_f(acc[reg + 1] + bb));
        aZ[row * ZST + col] = (short)pk;
        aZ[(row + 1) * ZST + col] = (short)(pk >> 16);
      }
    }
  }
  __syncthreads();

  // ---- E5 (waves 0,1): head outputs via MFMA + fused flux epilogue
  // ---- waves 2,3 (concurrent): store m output (bf16 aM -> f32 global)
  if (wv < 2) {
    f32x4 acc = {0.f, 0.f, 0.f, 0.f};
    for (int ks = 0; ks < 7; ++ks) {
      const bf16x8 a = *(const bf16x8*)((const char*)aZ + (wv * 16 + l15) * (ZST * 2) + ks * 64 + g * 16);
      const bf16x8 b = *(const bf16x8*)(A.WOP + ks * 512 + lane * 8);
      acc = MFMA16(a, b, acc);
    }
    if (l15 < 5) {
      const float bb = A.HB2[l15];
#pragma unroll
      for (int rg = 0; rg < 4; ++rg)
        sSc2[(wv * 16 + g * 4 + rg) * 8 + l15] = acc[rg] + bb;
    }
    asm volatile("s_waitcnt lgkmcnt(0)" ::: "memory");
    __builtin_amdgcn_sched_barrier(0);
    if (lane < 16) {  // same wave wrote all 16 of its edges' head values
      const int e = wv * 16 + lane;
      const float* st = &sSc[e * 8];
      const float n0 = st[0], n1 = st[1], r = st[2];
      const float du0 = st[3], du1 = st[4], du3 = st[5], du4 = st[6];
      const float arho = sSc2[e * 8 + 0], aen = sSc2[e * 8 + 1];
      const float amu0 = sSc2[e * 8 + 2], amu1 = sSc2[e * 8 + 3];
      const float av = sSc2[e * 8 + 4];
      const float alpha = __builtin_amdgcn_rcpf(1.0f + __builtin_amdgcn_exp2f(-1.4426950408f * av));
      const size_t ge = (size_t)(e0 + e);
      float* out = A.out;
      const float c0 = arho - alpha * du0;
      out[ge * 2 + 0] = c0 * n0;
      out[ge * 2 + 1] = c0 * n1;
      const float c1 = aen - alpha * du1;
      out[(size_t)2 * NE + ge * 2 + 0] = c1 * n0;
      out[(size_t)2 * NE + ge * 2 + 1] = c1 * n1;
      out[(size_t)4 * NE + ge * 2 + 0] = amu0 * n0 - amu1 * n1 - alpha * du3;
      out[(size_t)4 * NE + ge * 2 + 1] = amu0 * n1 + amu1 * n0 - alpha * du4;
      out[(size_t)6 * NE + ge * 2 + 0] = n0;
      out[(size_t)6 * NE + ge * 2 + 1] = n1;
      out[(size_t)8 * NE + ge] = r;
      out[(size_t)9 * NE + ge] = alpha;
    }
  } else {
    float* out_m = A.out + (size_t)10 * NE;
    const int rbase = (wv - 2) * 16;
#pragma unroll
    for (int rr = 0; rr < 16; ++rr) {
      const int row = rbase + rr;
      out_m[(size_t)(e0 + row) * 64 + lane] = bf2f(aM[row * MSR + lane]);
    }
  }
}

extern "C" void kernel_launch(void* const* d_in, const int* in_sizes, int n_in,
                              void* d_out, int out_size, void* d_ws, size_t ws_size,
                              hipStream_t stream) {
  char* ws = (char*)d_ws;
  unsigned short* h = (unsigned short*)ws;         // 12,800,000 B
  short* W1P  = (short*)(ws + 12800000);           // 61,440 B
  short* W2P  = (short*)(ws + 12861440);           // 16,384 B
  short* WHP  = (short*)(ws + 12877824);           // 28,672 B
  float* HB   = (float*)(ws + 12906496);           // 896 B
  short* WOP  = (short*)(ws + 12907392);           // 7,168 B
  float* HB2  = (float*)(ws + 12914560);           // 64 B
  float* B1F  = (float*)(ws + 12914624);           // 512 B
  short* W1NP = (short*)(ws + 12915136);           // 2,048 B
  short* IPNP = (short*)(ws + 12917184);           // 2,048 B
  short* W2NP = (short*)(ws + 12919232);           // 8,192 B

  EdgeArgs A;
  A.node_u = (const float*)d_in[0];
  A.edge_attr = (const float*)d_in[1];
  A.mean_mom = (const float*)d_in[2];
  A.std_mom = (const float*)d_in[3];
  A.edge_mem = (const float*)d_in[4];
  A.eidx = (const int*)d_in[5];
  A.pe_W1 = (const float*)d_in[12];
  A.pe_b1 = (const float*)d_in[13];
  A.B1F = B1F;
  A.pm_b2 = (const float*)d_in[19];
  A.ln_g = (const float*)d_in[36];
  A.ln_b = (const float*)d_in[37];
  A.h = h;
  A.W1P = W1P;
  A.W2P = W2P;
  A.WHP = WHP;
  A.WOP = WOP;
  A.HB = HB;
  A.HB2 = HB2;
  A.out = (float*)d_out;

  prep_kernel<<<248, 256, 0, stream>>>(
      (const float*)d_in[16], (const float*)d_in[17], (const float*)d_in[18],
      (const float*)d_in[20], (const float*)d_in[24],
      (const float*)d_in[28], (const float*)d_in[32],
      (const float*)d_in[21], (const float*)d_in[25],
      (const float*)d_in[29], (const float*)d_in[33],
      (const float*)d_in[14], (const float*)d_in[15],
      (const float*)d_in[22], (const float*)d_in[26],
      (const float*)d_in[30], (const float*)d_in[34],
      (const float*)d_in[23], (const float*)d_in[27],
      (const float*)d_in[31], (const float*)d_in[35],
      (const float*)d_in[6], (const float*)d_in[8], (const float*)d_in[10],
      W1P, W2P, WHP, HB, WOP, HB2, B1F, W1NP, IPNP, W2NP);
  node_h_kernel<<<(NN + 63) / 64, 256, 0, stream>>>(
      (const float*)d_in[0], (const float*)d_in[7], (const float*)d_in[9],
      (const float*)d_in[11], W1NP, IPNP, W2NP, h);
  edge_kernel<<<NE / 32, 256, 0, stream>>>(A);
}

// Round 12
// 182.280 us; speedup vs baseline: 1.5736x; 1.0147x over previous
//
#include <hip/hip_runtime.h>
#include <math.h>

#define NN 100000
#define NE 500000

typedef short bf16x8 __attribute__((ext_vector_type(8)));
typedef float f32x4 __attribute__((ext_vector_type(4)));
typedef float f32x16 __attribute__((ext_vector_type(16)));

// fast tanh-approx gelu (exp2-based): |err| <= ~3e-3 vs exact erf-gelu.
__device__ __forceinline__ float gelu_f(float x) {
  const float t = x * x;
  const float p = fmaf(t, 0.10294325f, 2.3022084f);
  const float E = __builtin_amdgcn_exp2f(x * p);
  const float r = __builtin_amdgcn_rcpf(E + 1.0f);
  return fmaf(-x, r, x);
}
// HW packed f32->bf16 (RNE), gfx950: v_cvt_pk_bf16_f32
__device__ __forceinline__ unsigned cvtpk(float lo, float hi) {
  unsigned r;
  asm("v_cvt_pk_bf16_f32 %0, %1, %2" : "=v"(r) : "v"(lo), "v"(hi));
  return r;
}
__device__ __forceinline__ short f2bf(float x) { return (short)cvtpk(x, x); }
__device__ __forceinline__ unsigned pack2(float a, float b) { return cvtpk(a, b); }
__device__ __forceinline__ float bf2f(short s) {
  unsigned u = ((unsigned)(unsigned short)s) << 16;
  return __builtin_bit_cast(float, u);
}
__device__ __forceinline__ float bf2f_lo(unsigned w) {
  return __builtin_bit_cast(float, w << 16);
}
__device__ __forceinline__ float bf2f_hi(unsigned w) {
  return __builtin_bit_cast(float, w & 0xFFFF0000u);
}

#define MFMA16(a, b, c) __builtin_amdgcn_mfma_f32_16x16x32_bf16((a), (b), (c), 0, 0, 0)
#define MFMA32(a, b, c) __builtin_amdgcn_mfma_f32_32x32x16_bf16((a), (b), (c), 0, 0, 0)

// ---------------- Kernel 1: per-node h via MFMA (64 nodes/block) ----------------
__global__ __launch_bounds__(256) void node_h_kernel(
    const float* __restrict__ node_u,
    const float* __restrict__ b1, const float* __restrict__ b2,
    const float* __restrict__ ipb,
    const short* __restrict__ W1NP, const short* __restrict__ IPNP,
    const short* __restrict__ W2NP,
    unsigned short* __restrict__ h) {
  __shared__ float sU[64 * 5];
  __shared__ short sG[64 * 72];
  const int tid = threadIdx.x;
  const int lane = tid & 63;
  const int wv = tid >> 6;
  const int l31 = lane & 31, hi = lane >> 5;
  const int mt = wv & 1, nh = wv >> 1;
  const int n0 = blockIdx.x * 64;
  const int nrem = NN - n0;

  {  // stage u
    const int cnt = (nrem < 64 ? nrem : 64) * 5;
    for (int t = tid; t < cnt; t += 256) sU[t] = node_u[(size_t)n0 * 5 + t];
  }
  __syncthreads();

  const int row_node = mt * 32 + l31;
  const int col = nh * 32 + l31;
  bf16x8 au;
#pragma unroll
  for (int e = 0; e < 8; ++e)
    au[e] = (hi == 0 && e < 5) ? f2bf(sU[row_node * 5 + e]) : (short)0;
  f32x16 acc1, accip;
  const float b1v = b1[col];
  const float ipv = ipb[col] + b2[col];
#pragma unroll
  for (int reg = 0; reg < 16; ++reg) { acc1[reg] = b1v; accip[reg] = ipv; }
  acc1 = MFMA32(au, *(const bf16x8*)(W1NP + nh * 512 + lane * 8), acc1);
  accip = MFMA32(au, *(const bf16x8*)(IPNP + nh * 512 + lane * 8), accip);
#pragma unroll
  for (int reg = 0; reg < 16; ++reg) {
    const int r = mt * 32 + (reg & 3) + 8 * (reg >> 2) + 4 * hi;
    sG[r * 72 + col] = f2bf(gelu_f(acc1[reg]));
  }
  __syncthreads();

  {
    const char* arow = (const char*)sG + row_node * 144 + hi * 16;
    const short* BW = W2NP + nh * 4 * 512 + lane * 8;
    f32x16 acc = accip;
#pragma unroll
    for (int ks = 0; ks < 4; ++ks)
      acc = MFMA32(*(const bf16x8*)(arow + ks * 32),
                   *(const bf16x8*)(BW + ks * 512), acc);
#pragma unroll
    for (int reg = 0; reg < 16; ++reg) {
      const int r = mt * 32 + (reg & 3) + 8 * (reg >> 2) + 4 * hi;
      const int node = n0 + r;
      if (node < NN) h[(size_t)node * 64 + col] = (unsigned short)f2bf(acc[reg]);
    }
  }
}

// ---------------- Kernel 0: weight repack + algebraic folds ----------------
// 16x16 frag block = 512 bf16: k = ks*32 + 8*(l>>4) + e, n = nt*16 + (l&15).
// 32x32 frag block = 512 bf16: k = ks*16 + 8*(l>>5) + e, n = nt*32 + (l&31).
__global__ __launch_bounds__(256) void prep_kernel(
    const float* __restrict__ pm_W1, const float* __restrict__ pm_b1,
    const float* __restrict__ pm_W2,
    const float* __restrict__ prho_W1, const float* __restrict__ pen_W1,
    const float* __restrict__ pmu_W1, const float* __restrict__ pv_W1,
    const float* __restrict__ prho_b1, const float* __restrict__ pen_b1,
    const float* __restrict__ pmu_b1, const float* __restrict__ pv_b1,
    const float* __restrict__ pe_W2, const float* __restrict__ pe_b2,
    const float* __restrict__ prho_W2, const float* __restrict__ pen_W2,
    const float* __restrict__ pmu_W2, const float* __restrict__ pv_W2,
    const float* __restrict__ prho_b2, const float* __restrict__ pen_b2,
    const float* __restrict__ pmu_b2, const float* __restrict__ pv_b2,
    const float* __restrict__ pn_W1, const float* __restrict__ pn_W2,
    const float* __restrict__ ip_W,
    short* __restrict__ W1P, short* __restrict__ W2P, short* __restrict__ WHP,
    float* __restrict__ HB, short* __restrict__ WOP, float* __restrict__ HB2,
    float* __restrict__ B1F, short* __restrict__ W1NP, short* __restrict__ IPNP,
    short* __restrict__ W2NP) {
  int t = blockIdx.x * 256 + threadIdx.x;
  if (t < 30720) {  // folded W1': 240x128, 32x32 frag [nt=4][ks=15][512]
    const int nt = t / 7680, rem = t % 7680;
    const int ks = rem / 512, li = rem % 512;
    const int l = li >> 3, e = li & 7;
    const int k = ks * 16 + ((l >> 5) << 3) + e;
    const int n = nt * 32 + (l & 31);
    float v = 0.0f;
    if (k < 64) v = pm_W1[k * 128 + n] + pm_W1[(128 + k) * 128 + n];
    else if (k < 128) v = pm_W1[k * 128 + n] + pm_W1[(64 + k) * 128 + n];
    else if (k < 192) v = pm_W1[(64 + k) * 128 + n];
    else if (k < 224) {
      const int i = k - 192;
      for (int j = 0; j < 32; ++j) v += pe_W2[i * 32 + j] * pm_W1[(256 + j) * 128 + n];
    } else if (k < 228) v = pm_W1[(64 + k) * 128 + n];
    W1P[t] = f2bf(v);
    return;
  }
  t -= 30720;
  if (t < 8192) {  // pm_W2 16x16-frag: 128x64, [nt=4][ks=4][512]
    const int nt = t / 2048, rem = t % 2048;
    const int ks = rem / 512, li = rem % 512;
    const int l = li >> 3, e = li & 7;
    const int k = ks * 32 + ((l >> 4) << 3) + e;
    const int n = nt * 16 + (l & 15);
    W2P[t] = f2bf(pm_W2[k * 64 + n]);
    return;
  }
  t -= 8192;
  if (t < 14336) {  // heads W1 concat 32x32-frag: 64x224, [nt=7][ks=4][512]
    const int nt = t / 2048, rem = t % 2048;
    const int ks = rem / 512, li = rem % 512;
    const int l = li >> 3, e = li & 7;
    const int k = ks * 16 + ((l >> 5) << 3) + e;
    const int col = nt * 32 + (l & 31);
    float v;
    if (col < 64) v = prho_W1[k * 64 + col];
    else if (col < 128) v = pen_W1[k * 64 + (col - 64)];
    else if (col < 192) v = pmu_W1[k * 64 + (col - 128)];
    else v = pv_W1[k * 32 + (col - 192)];
    WHP[t] = f2bf(v);
    return;
  }
  t -= 14336;
  if (t < 224) {  // head hidden biases concat (f32)
    HB[t] = (t < 64) ? prho_b1[t]
          : (t < 128) ? pen_b1[t - 64]
          : (t < 192) ? pmu_b1[t - 128]
          : pv_b1[t - 192];
    return;
  }
  t -= 224;
  if (t < 3584) {  // stacked head W2 16x16-frag: 224x16, [ks=7][512]
    const int ks = t / 512, li = t % 512;
    const int l = li >> 3, e = li & 7;
    const int k = ks * 32 + ((l >> 4) << 3) + e;
    const int j = l & 15;
    float v = 0.0f;
    if (j == 0 && k < 64) v = prho_W2[k];
    else if (j == 1 && k >= 64 && k < 128) v = pen_W2[k - 64];
    else if (j == 2 && k >= 128 && k < 192) v = pmu_W2[(k - 128) * 2 + 0];
    else if (j == 3 && k >= 128 && k < 192) v = pmu_W2[(k - 128) * 2 + 1];
    else if (j == 4 && k >= 192 && k < 224) v = pv_W2[k - 192];
    WOP[t] = f2bf(v);
    return;
  }
  t -= 3584;
  if (t < 16) {  // head output biases
    HB2[t] = (t == 0) ? prho_b2[0]
           : (t == 1) ? pen_b2[0]
           : (t == 2) ? pmu_b2[0]
           : (t == 3) ? pmu_b2[1]
           : (t == 4) ? pv_b2[0] : 0.0f;
    return;
  }
  t -= 16;
  if (t < 128) {  // folded layer1 bias (f32)
    float v = pm_b1[t];
    for (int j = 0; j < 32; ++j) v += pe_b2[j] * pm_W1[(256 + j) * 128 + t];
    B1F[t] = v;
    return;
  }
  t -= 128;
  if (t < 1024) {  // pn_W1 32x32-frag (K=5 pad 16): [nt=2][512]
    const int nt = t / 512, li = t % 512;
    const int l = li >> 3, e = li & 7;
    const int k = ((l >> 5) << 3) + e;
    const int n = nt * 32 + (l & 31);
    W1NP[t] = (k < 5) ? f2bf(pn_W1[k * 64 + n]) : (short)0;
    return;
  }
  t -= 1024;
  if (t < 1024) {  // ip_W 32x32-frag (K=5 pad 16): [nt=2][512]
    const int nt = t / 512, li = t % 512;
    const int l = li >> 3, e = li & 7;
    const int k = ((l >> 5) << 3) + e;
    const int n = nt * 32 + (l & 31);
    IPNP[t] = (k < 5) ? f2bf(ip_W[k * 64 + n]) : (short)0;
    return;
  }
  t -= 1024;
  if (t < 4096) {  // pn_W2 32x32-frag: 64x64, [nt=2][ks=4][512]
    const int nt = t / 2048, rem = t % 2048;
    const int ks = rem / 512, li = rem % 512;
    const int l = li >> 3, e = li & 7;
    const int k = ks * 16 + ((l >> 5) << 3) + e;
    const int n = nt * 32 + (l & 31);
    W2NP[t] = f2bf(pn_W2[k * 64 + n]);
  }
}

// ---------------- Kernel 2: per-edge fused MFMA pipeline, 32 edges / block ----------------
struct EdgeArgs {
  const float *node_u, *edge_attr, *mean_mom, *std_mom, *edge_mem;
  const int* eidx;
  const float *pe_W1, *pe_b1;
  const float *B1F, *pm_b2;
  const float *ln_g, *ln_b;
  const unsigned short* h;   // bf16
  const short *W1P, *W2P, *WHP, *WOP;
  const float *HB, *HB2;
  float* out;
};

#define SMS 248   // msg bf16 row stride (496 B)
#define H1S 136   // h1 bf16 row stride (272 B)
#define MSR 72    // m bf16 row stride (144 B)
#define ZST 248   // z bf16 row stride (496 B; z uses cols 0..224, slack [448,496) B/row)

// LDS map (20,480 B -> 8 blocks/CU: 8*20480 = 163,840 = full pool):
//  [0, 15872): msg bf16 [32][248]  (S0..E2)
//      overlay: h1 bf16 [32][136]  (written AFTER E2 barrier from regs; E2->E3)
//      overlay: sPart float2[32][2] @ +8704 (E3->LN; h1 ends at 8704, dead by E4)
//      overlay: aZ bf16 [32][248]  (E4 -> E5); per-row slack [448,496) holds
//               sSc2: 5 f32 head results per edge @ row*496+448 (E5, same-wave)
//  [15872, 20480): aM bf16 [32][72] (E3 -> E4/E5-mstore, LN in place)
#define OFF_A    0
#define OFF_AM   15872
#define OFF_PART 8704
#define SMEM_BYTES 20480

__global__ __launch_bounds__(256, 8) void edge_kernel(EdgeArgs A) {
  __shared__ __align__(16) char smem[SMEM_BYTES];
  short* aA = (short*)(smem + OFF_A);
  short* aZ = (short*)(smem + OFF_A);
  short* aH1 = (short*)(smem + OFF_A);   // overlays msg after E2
  short* aM = (short*)(smem + OFF_AM);
  float2* sPart = (float2*)(smem + OFF_PART);

  const int tid = threadIdx.x;
  const int e0 = blockIdx.x * 32;
  const int lane = tid & 63;
  const int wv = tid >> 6;
  const int l15 = lane & 15, g = lane >> 4;
  const int l31 = lane & 31, hi = lane >> 5;
  const int mt = wv & 1, nh = wv >> 1;

  // ---- S0a (tid<32) || S0b || S0d: one phase, disjoint writes
  if (tid < 32) {
    const int e = e0 + tid;
    const int s = A.eidx[e];
    const int d = A.eidx[NE + e];
    const float dx = A.edge_attr[e * 3 + 0];
    const float dy = A.edge_attr[e * 3 + 1];
    const float r = A.edge_attr[e * 3 + 2];
    const float inv = 1.0f / (r + 1e-12f);
    const float n0 = dx * inv, n1 = dy * inv;  // t = (-n1, n0)
    const float* us = A.node_u + (size_t)s * 5;
    const float* ud = A.node_u + (size_t)d * 5;
    const float sm0 = A.std_mom[0], sm1 = A.std_mom[1];
    const float mm0 = A.mean_mom[0], mm1 = A.mean_mom[1];
    const float rs0 = fmaf(us[3], sm0, mm0), rs1 = fmaf(us[4], sm1, mm1);
    const float rd0 = fmaf(ud[3], sm0, mm0), rd1 = fmaf(ud[4], sm1, mm1);
    const float isc = 1.0f / (sqrtf(sm0 * sm0 + sm1 * sm1) + 1e-8f);
    unsigned* vp = (unsigned*)(aA + tid * SMS + 224);  // vel cols 224..228
    vp[0] = pack2((rs0 * n0 + rs1 * n1) * isc, (-rs0 * n1 + rs1 * n0) * isc);
    vp[1] = pack2((rd0 * n0 + rd1 * n1) * isc, (-rd0 * n1 + rd1 * n0) * isc);
    unsigned* zp = (unsigned*)(aA + tid * SMS + 228);  // zero pad 228..240
#pragma unroll
    for (int z = 0; z < 6; ++z) zp[z] = 0u;
  }
  {  // S0b: eps hidden (1 -> 32, gelu) -> msg cols [192..224)
    const int i = tid & 31, eg = tid >> 5;
    const float w1 = A.pe_W1[i], b1 = A.pe_b1[i];
#pragma unroll
    for (int p = 0; p < 4; ++p) {
      const int el = eg * 4 + p;
      const float rv = A.edge_attr[(e0 + el) * 3 + 2];
      aA[el * SMS + 192 + i] = f2bf(gelu_f(fmaf(rv, w1, b1)));
    }
  }
  {  // S0d: h gathers -> msg cols [0..192): hs | hd | (hs-hd)^2  (batched loads)
    const int c = tid & 31, eg = tid >> 5;
    int si[4], di[4];
#pragma unroll
    for (int p = 0; p < 4; ++p) {
      si[p] = A.eidx[e0 + eg * 4 + p];
      di[p] = A.eidx[NE + e0 + eg * 4 + p];
    }
    unsigned usr[4], udr[4];
#pragma unroll
    for (int p = 0; p < 4; ++p) {
      usr[p] = ((const unsigned*)(A.h + (size_t)si[p] * 64))[c];
      udr[p] = ((const unsigned*)(A.h + (size_t)di[p] * 64))[c];
    }
#pragma unroll
    for (int p = 0; p < 4; ++p) {
      const int el = eg * 4 + p;
      unsigned* rp = (unsigned*)((char*)aA + el * (SMS * 2));
      rp[c] = usr[p];
      rp[32 + c] = udr[p];
      const float s0 = bf2f_lo(usr[p]), s1 = bf2f_hi(usr[p]);
      const float d0 = bf2f_lo(udr[p]), d1 = bf2f_hi(udr[p]);
      const float q0 = s0 - d0, q1 = s1 - d1;
      rp[64 + c] = pack2(q0 * q0, q1 * q1);
    }
  }
  __syncthreads();

  // ---- E2: layer1 via 32x32x16 MFMA (M=32, K=240, N=128); results kept in regs
  unsigned h1pk[8];
  {
    const char* arow = (const char*)aA + l31 * (SMS * 2) + hi * 16;
    const short* BW = A.W1P + wv * 15 * 512 + lane * 8;
    f32x16 acc = {0.f, 0.f, 0.f, 0.f, 0.f, 0.f, 0.f, 0.f,
                  0.f, 0.f, 0.f, 0.f, 0.f, 0.f, 0.f, 0.f};
    for (int ks = 0; ks < 15; ++ks) {
      acc = MFMA32(*(const bf16x8*)(arow + ks * 32),
                   *(const bf16x8*)(BW + ks * 512), acc);
    }
    const float bb = A.B1F[wv * 32 + l31];
#pragma unroll
    for (int r8 = 0; r8 < 8; ++r8)
      h1pk[r8] = pack2(gelu_f(acc[2 * r8] + bb), gelu_f(acc[2 * r8 + 1] + bb));
  }
  __syncthreads();   // msg now dead; h1 overlays it

  {  // write h1 from regs into overlay region
    const int col = wv * 32 + l31;
#pragma unroll
    for (int r8 = 0; r8 < 8; ++r8) {
      const int reg = 2 * r8;
      const int row = (reg & 3) + 8 * (reg >> 2) + 4 * hi;
      aH1[row * H1S + col] = (short)h1pk[r8];
      aH1[(row + 1) * H1S + col] = (short)(h1pk[r8] >> 16);
    }
  }
  __syncthreads();

  // ---- E3: layer2 16x16 MFMA (K=128, N=64) + bias + edge_memory -> aM + LN partials
  {
    const int rb = mt * 16 + g * 4;
    const int c0 = (nh * 2 + 0) * 16 + l15, c1 = (nh * 2 + 1) * 16 + l15;
    float em0[4], em1[4];
#pragma unroll
    for (int rg = 0; rg < 4; ++rg) {   // issue global loads early
      em0[rg] = A.edge_mem[(size_t)(e0 + rb + rg) * 64 + c0];
      em1[rg] = A.edge_mem[(size_t)(e0 + rb + rg) * 64 + c1];
    }
    const char* arow = (const char*)aH1 + (mt * 16 + l15) * (H1S * 2) + g * 16;
    const short* BW = A.W2P + nh * 2 * 4 * 512 + lane * 8;
    f32x4 ac0 = {0.f, 0.f, 0.f, 0.f}, ac1 = ac0;
    for (int ks = 0; ks < 4; ++ks) {
      const bf16x8 a = *(const bf16x8*)(arow + ks * 64);
      ac0 = MFMA16(a, *(const bf16x8*)(BW + (0 * 4 + ks) * 512), ac0);
      ac1 = MFMA16(a, *(const bf16x8*)(BW + (1 * 4 + ks) * 512), ac1);
    }
    const float bb0 = A.pm_b2[c0], bb1 = A.pm_b2[c1];
#pragma unroll
    for (int rg = 0; rg < 4; ++rg) {
      const int row = rb + rg;
      const float x0 = ac0[rg] + bb0 + em0[rg];
      const float x1 = ac1[rg] + bb1 + em1[rg];
      const unsigned pk = pack2(x0, x1);
      aM[row * MSR + c0] = (short)pk;
      aM[row * MSR + c1] = (short)(pk >> 16);
      float sx = x0 + x1;
      float sq = fmaf(x0, x0, x1 * x1);
#pragma unroll
      for (int m = 1; m < 16; m <<= 1) {
        sx += __shfl_xor(sx, m, 64);
        sq += __shfl_xor(sq, m, 64);
      }
      if (l15 == 0) sPart[row * 2 + nh] = make_float2(sx, sq);
    }
  }
  __syncthreads();

  // ---- LN normalize (elementwise, in-place on aM; m global store deferred to E5 phase)
  {
    const float lg = A.ln_g[lane], lb = A.ln_b[lane];
#pragma unroll
    for (int p = 0; p < 8; ++p) {
      const int r = p * 4 + wv;
      const float x = bf2f(aM[r * MSR + lane]);
      const float2 pa = sPart[r * 2 + 0], pb = sPart[r * 2 + 1];
      const float mean = (pa.x + pb.x) * (1.0f / 64.0f);
      const float var = fmaxf((pa.y + pb.y) * (1.0f / 64.0f) - mean * mean, 0.0f);
      const float rstd = rsqrtf(var + 1e-5f);
      const float y = fmaf((x - mean) * rstd, lg, lb);
      aM[r * MSR + lane] = f2bf(y);
    }
  }
  __syncthreads();

  // ---- E4: head hidden via 32x32x16 MFMA (M=32, K=64, N=224) -> z (overlay msg)
  {
    const char* arow = (const char*)aM + l31 * (MSR * 2) + hi * 16;
    bf16x8 af0 = *(const bf16x8*)(arow);
    bf16x8 af1 = *(const bf16x8*)(arow + 32);
    bf16x8 af2 = *(const bf16x8*)(arow + 64);
    bf16x8 af3 = *(const bf16x8*)(arow + 96);
    for (int nt = wv; nt < 7; nt += 4) {
      const short* BW = A.WHP + nt * 4 * 512 + lane * 8;
      f32x16 acc = {0.f, 0.f, 0.f, 0.f, 0.f, 0.f, 0.f, 0.f,
                    0.f, 0.f, 0.f, 0.f, 0.f, 0.f, 0.f, 0.f};
      acc = MFMA32(af0, *(const bf16x8*)(BW + 0 * 512), acc);
      acc = MFMA32(af1, *(const bf16x8*)(BW + 1 * 512), acc);
      acc = MFMA32(af2, *(const bf16x8*)(BW + 2 * 512), acc);
      acc = MFMA32(af3, *(const bf16x8*)(BW + 3 * 512), acc);
      const int col = nt * 32 + l31;
      const float bb = A.HB[col];
#pragma unroll
      for (int i = 0; i < 8; ++i) {
        const int reg = 2 * i;
        const int row = (reg & 3) + 8 * (reg >> 2) + 4 * hi;
        const unsigned pk = pack2(gelu_f(acc[reg] + bb), gelu_f(acc[reg + 1] + bb));
        aZ[row * ZST + col] = (short)pk;
        aZ[(row + 1) * ZST + col] = (short)(pk >> 16);
      }
    }
  }
  __syncthreads();

  // ---- E5 (waves 0,1): head outputs via MFMA + fused flux epilogue
  // ---- waves 2,3 (concurrent): store m output (bf16 aM -> f32 global)
  if (wv < 2) {
    // issue geometry loads early (hidden under the MFMA loop)
    const int e = wv * 16 + l15;
    const size_t ge = (size_t)(e0 + e);
    int s = 0, d = 0;
    float dx = 0.f, dy = 0.f, rr = 0.f;
    float u0s = 0.f, u1s = 0.f, u3s = 0.f, u4s = 0.f;
    float u0d = 0.f, u1d = 0.f, u3d = 0.f, u4d = 0.f;
    if (lane < 16) {
      s = A.eidx[ge];
      d = A.eidx[NE + ge];
      dx = A.edge_attr[ge * 3 + 0];
      dy = A.edge_attr[ge * 3 + 1];
      rr = A.edge_attr[ge * 3 + 2];
      const float* us = A.node_u + (size_t)s * 5;
      const float* ud = A.node_u + (size_t)d * 5;
      u0s = us[0]; u1s = us[1]; u3s = us[3]; u4s = us[4];
      u0d = ud[0]; u1d = ud[1]; u3d = ud[3]; u4d = ud[4];
    }
    f32x4 acc = {0.f, 0.f, 0.f, 0.f};
    for (int ks = 0; ks < 7; ++ks) {
      const bf16x8 a = *(const bf16x8*)((const char*)aZ + (wv * 16 + l15) * (ZST * 2) + ks * 64 + g * 16);
      const bf16x8 b = *(const bf16x8*)(A.WOP + ks * 512 + lane * 8);
      acc = MFMA16(a, b, acc);
    }
    if (l15 < 5) {   // store head results into aZ row slack (same-wave rows only)
      const float bb = A.HB2[l15];
#pragma unroll
      for (int rg = 0; rg < 4; ++rg)
        *(float*)(smem + (size_t)(wv * 16 + g * 4 + rg) * 496 + 448 + l15 * 4) = acc[rg] + bb;
    }
    asm volatile("s_waitcnt lgkmcnt(0)" ::: "memory");
    __builtin_amdgcn_sched_barrier(0);
    if (lane < 16) {  // same wave wrote all 16 of its edges' head values
      const float inv = 1.0f / (rr + 1e-12f);
      const float n0 = dx * inv, n1 = dy * inv;
      const float du0 = u0d - u0s, du1 = u1d - u1s;
      const float du3 = u3d - u3s, du4 = u4d - u4s;
      const float* sc2 = (const float*)(smem + (size_t)e * 496 + 448);
      const float arho = sc2[0], aen = sc2[1];
      const float amu0 = sc2[2], amu1 = sc2[3];
      const float av = sc2[4];
      const float alpha = __builtin_amdgcn_rcpf(1.0f + __builtin_amdgcn_exp2f(-1.4426950408f * av));
      float* out = A.out;
      const float c0 = arho - alpha * du0;
      out[ge * 2 + 0] = c0 * n0;
      out[ge * 2 + 1] = c0 * n1;
      const float c1 = aen - alpha * du1;
      out[(size_t)2 * NE + ge * 2 + 0] = c1 * n0;
      out[(size_t)2 * NE + ge * 2 + 1] = c1 * n1;
      out[(size_t)4 * NE + ge * 2 + 0] = amu0 * n0 - amu1 * n1 - alpha * du3;
      out[(size_t)4 * NE + ge * 2 + 1] = amu0 * n1 + amu1 * n0 - alpha * du4;
      out[(size_t)6 * NE + ge * 2 + 0] = n0;
      out[(size_t)6 * NE + ge * 2 + 1] = n1;
      out[(size_t)8 * NE + ge] = rr;
      out[(size_t)9 * NE + ge] = alpha;
    }
  } else {
    float* out_m = A.out + (size_t)10 * NE;
    const int rbase = (wv - 2) * 16;
#pragma unroll
    for (int rr2 = 0; rr2 < 16; ++rr2) {
      const int row = rbase + rr2;
      out_m[(size_t)(e0 + row) * 64 + lane] = bf2f(aM[row * MSR + lane]);
    }
  }
}

extern "C" void kernel_launch(void* const* d_in, const int* in_sizes, int n_in,
                              void* d_out, int out_size, void* d_ws, size_t ws_size,
                              hipStream_t stream) {
  char* ws = (char*)d_ws;
  unsigned short* h = (unsigned short*)ws;         // 12,800,000 B
  short* W1P  = (short*)(ws + 12800000);           // 61,440 B
  short* W2P  = (short*)(ws + 12861440);           // 16,384 B
  short* WHP  = (short*)(ws + 12877824);           // 28,672 B
  float* HB   = (float*)(ws + 12906496);           // 896 B
  short* WOP  = (short*)(ws + 12907392);           // 7,168 B
  float* HB2  = (float*)(ws + 12914560);           // 64 B
  float* B1F  = (float*)(ws + 12914624);           // 512 B
  short* W1NP = (short*)(ws + 12915136);           // 2,048 B
  short* IPNP = (short*)(ws + 12917184);           // 2,048 B
  short* W2NP = (short*)(ws + 12919232);           // 8,192 B

  EdgeArgs A;
  A.node_u = (const float*)d_in[0];
  A.edge_attr = (const float*)d_in[1];
  A.mean_mom = (const float*)d_in[2];
  A.std_mom = (const float*)d_in[3];
  A.edge_mem = (const float*)d_in[4];
  A.eidx = (const int*)d_in[5];
  A.pe_W1 = (const float*)d_in[12];
  A.pe_b1 = (const float*)d_in[13];
  A.B1F = B1F;
  A.pm_b2 = (const float*)d_in[19];
  A.ln_g = (const float*)d_in[36];
  A.ln_b = (const float*)d_in[37];
  A.h = h;
  A.W1P = W1P;
  A.W2P = W2P;
  A.WHP = WHP;
  A.WOP = WOP;
  A.HB = HB;
  A.HB2 = HB2;
  A.out = (float*)d_out;

  prep_kernel<<<248, 256, 0, stream>>>(
      (const float*)d_in[16], (const float*)d_in[17], (const float*)d_in[18],
      (const float*)d_in[20], (const float*)d_in[24],
      (const float*)d_in[28], (const float*)d_in[32],
      (const float*)d_in[21], (const float*)d_in[25],
      (const float*)d_in[29], (const float*)d_in[33],
      (const float*)d_in[14], (const float*)d_in[15],
      (const float*)d_in[22], (const float*)d_in[26],
      (const float*)d_in[30], (const float*)d_in[34],
      (const float*)d_in[23], (const float*)d_in[27],
      (const float*)d_in[31], (const float*)d_in[35],
      (const float*)d_in[6], (const float*)d_in[8], (const float*)d_in[10],
      W1P, W2P, WHP, HB, WOP, HB2, B1F, W1NP, IPNP, W2NP);
  node_h_kernel<<<(NN + 63) / 64, 256, 0, stream>>>(
      (const float*)d_in[0], (const float*)d_in[7], (const float*)d_in[9],
      (const float*)d_in[11], W1NP, IPNP, W2NP, h);
  edge_kernel<<<NE / 32, 256, 0, stream>>>(A);
}